// Round 4
// baseline (1504.520 us; speedup 1.0000x reference)
//
#include <hip/hip_runtime.h>
#include <hip/hip_bf16.h>

// Model dims (fixed by the reference)
#define BATCH  4
#define SEQ    512
#define TOK    (BATCH*SEQ)     // 2048
#define HID    512
#define NHEAD  8
#define HEAD   64
#define FFDIM  2048
#define NLAYER 12
#define SPAN2  1024            // 2*SPAN
#define VOCAB  25
#define LNEPS  1e-7f
#define NEG_BIG -3.0e38f

typedef __attribute__((ext_vector_type(8))) short bf16x8;   // 8 bf16 = 4 VGPRs
typedef __attribute__((ext_vector_type(4))) float floatx4;

#define MFMA16(a, b, c) __builtin_amdgcn_mfma_f32_16x16x32_bf16((a), (b), (c), 0, 0, 0)

__device__ __forceinline__ float b2f(unsigned short u) {
    return __uint_as_float(((unsigned int)u) << 16);
}
__device__ __forceinline__ unsigned short f2b(float f) {
    __hip_bfloat16 h = __float2bfloat16(f);
    return *(unsigned short*)&h;
}

// ---------------- block reductions (blockDim = 256, 1-D) ----------------
__device__ __forceinline__ float block_reduce_sum(float v, float* red) {
    int tid = threadIdx.x;
    red[tid] = v; __syncthreads();
    for (int s = 128; s > 0; s >>= 1) { if (tid < s) red[tid] += red[tid + s]; __syncthreads(); }
    float r = red[0]; __syncthreads();
    return r;
}

// ---------------- embedding gather + LN + mask (writes fp32 h and bf16 hb) ----------------
__global__ void embed_ln_kernel(const int* __restrict__ x, const int* __restrict__ am,
                                const float* __restrict__ word_emb,
                                const float* __restrict__ g, const float* __restrict__ bb,
                                float* __restrict__ h, unsigned short* __restrict__ hb) {
    __shared__ float red[256];
    int t = blockIdx.x, tid = threadIdx.x;
    const float* we = word_emb + (size_t)x[t] * HID;
    float v1 = we[tid], v2 = we[tid + 256];
    float mean = block_reduce_sum(v1 + v2, red) * (1.0f / HID);
    float d1 = v1 - mean, d2 = v2 - mean;
    float var = block_reduce_sum(d1 * d1 + d2 * d2, red) * (1.0f / HID);
    float rstd = rsqrtf(var + LNEPS);
    float maskf = (float)am[t];
    size_t base = (size_t)t * HID;
    float o1 = (d1 * rstd * g[tid]       + bb[tid])       * maskf;
    float o2 = (d2 * rstd * g[tid + 256] + bb[tid + 256]) * maskf;
    h[base + tid] = o1;        h[base + tid + 256] = o2;
    hb[base + tid] = f2b(o1);  hb[base + tid + 256] = f2b(o2);
}

// ---------------- residual add + LN, single tmp (fallback path) ----------------
__global__ void add_ln_kernel(const float* __restrict__ tmp,
                              const float* __restrict__ g, const float* __restrict__ bb,
                              float* __restrict__ h, unsigned short* __restrict__ hb) {
    __shared__ float red[256];
    int t = blockIdx.x, tid = threadIdx.x;
    size_t base = (size_t)t * HID;
    float v1 = tmp[base + tid] + h[base + tid];
    float v2 = tmp[base + tid + 256] + h[base + tid + 256];
    float mean = block_reduce_sum(v1 + v2, red) * (1.0f / HID);
    float d1 = v1 - mean, d2 = v2 - mean;
    float var = block_reduce_sum(d1 * d1 + d2 * d2, red) * (1.0f / HID);
    float rstd = rsqrtf(var + LNEPS);
    float o1 = d1 * rstd * g[tid]       + bb[tid];
    float o2 = d2 * rstd * g[tid + 256] + bb[tid + 256];
    h[base + tid] = o1;        h[base + tid + 256] = o2;
    hb[base + tid] = f2b(o1);  hb[base + tid + 256] = f2b(o2);
}

// ---------------- residual add + LN, two split-K partials ----------------
__global__ void add_ln2_kernel(const float* __restrict__ t1a, const float* __restrict__ t1b,
                               const float* __restrict__ g, const float* __restrict__ bb,
                               float* __restrict__ h, unsigned short* __restrict__ hb) {
    __shared__ float red[256];
    int t = blockIdx.x, tid = threadIdx.x;
    size_t base = (size_t)t * HID;
    float v1 = t1a[base + tid] + t1b[base + tid] + h[base + tid];
    float v2 = t1a[base + tid + 256] + t1b[base + tid + 256] + h[base + tid + 256];
    float mean = block_reduce_sum(v1 + v2, red) * (1.0f / HID);
    float d1 = v1 - mean, d2 = v2 - mean;
    float var = block_reduce_sum(d1 * d1 + d2 * d2, red) * (1.0f / HID);
    float rstd = rsqrtf(var + LNEPS);
    float o1 = d1 * rstd * g[tid]       + bb[tid];
    float o2 = d2 * rstd * g[tid + 256] + bb[tid + 256];
    h[base + tid] = o1;        h[base + tid + 256] = o2;
    hb[base + tid] = f2b(o1);  hb[base + tid + 256] = f2b(o2);
}

// ---------------- fp32 -> bf16 convert (rel_emb, n multiple of 1024) ----------------
__global__ void cvt_rel_kernel(const float* __restrict__ in, unsigned short* __restrict__ out) {
    int i = (blockIdx.x * 256 + threadIdx.x) * 4;
    float4 v = *(const float4*)(in + i);
    out[i] = f2b(v.x); out[i+1] = f2b(v.y); out[i+2] = f2b(v.z); out[i+3] = f2b(v.w);
}

// ---------------- transpose+convert: W[K][N] fp32 -> Wt[N][K] bf16, blockIdx.z = layer ----------------
__global__ void tcvt_kernel(const float* __restrict__ in, unsigned short* __restrict__ out,
                            int K, int N) {
    __shared__ float tile[32][33];
    int l = blockIdx.z;
    const float* ip = in + (size_t)l * K * N;
    unsigned short* op = out + (size_t)l * K * N;
    int kb = blockIdx.y * 32, nb = blockIdx.x * 32;
    int tx = threadIdx.x, ty = threadIdx.y;   // block (32,8)
    #pragma unroll
    for (int i = 0; i < 32; i += 8) tile[ty + i][tx] = ip[(size_t)(kb + ty + i) * N + nb + tx];
    __syncthreads();
    #pragma unroll
    for (int i = 0; i < 32; i += 8) op[(size_t)(nb + ty + i) * K + kb + tx] = f2b(tile[tx][ty + i]);
}

// six [12][512][512] weight arrays in one launch; z = l*6 + w; out contiguous [w][l][512][512]
__global__ void tcvt6_kernel(const float* __restrict__ Wq, const float* __restrict__ Wk,
                             const float* __restrict__ Wv, const float* __restrict__ Wpk,
                             const float* __restrict__ Wpq, const float* __restrict__ Wo,
                             unsigned short* __restrict__ out) {
    __shared__ float tile[32][33];
    int z = blockIdx.z, l = z / 6, w = z - l * 6;
    const float* src = w == 0 ? Wq : w == 1 ? Wk : w == 2 ? Wv : w == 3 ? Wpk : w == 4 ? Wpq : Wo;
    const float* ip = src + (size_t)l * HID * HID;
    unsigned short* op = out + ((size_t)w * NLAYER + l) * HID * HID;
    int kb = blockIdx.y * 32, nb = blockIdx.x * 32;
    int tx = threadIdx.x, ty = threadIdx.y;
    #pragma unroll
    for (int i = 0; i < 32; i += 8) tile[ty + i][tx] = ip[(size_t)(kb + ty + i) * HID + nb + tx];
    __syncthreads();
    #pragma unroll
    for (int i = 0; i < 32; i += 8) op[(size_t)(nb + ty + i) * HID + kb + tx] = f2b(tile[tx][ty + i]);
}

// ---------------- V transpose for fallback path: vb[token][ch] -> vbt[(b,h),d][seq] ----------------
__global__ void vtr_kernel(const unsigned short* __restrict__ in, unsigned short* __restrict__ out) {
    __shared__ unsigned short tile[32][33];
    int tb = blockIdx.y * 32, cb = blockIdx.x * 32;   // token base, channel base
    int tx = threadIdx.x, ty = threadIdx.y;           // block (32,8)
    #pragma unroll
    for (int i = 0; i < 32; i += 8)
        tile[ty + i][tx] = in[(size_t)(tb + ty + i) * HID + cb + tx];
    __syncthreads();
    int bq = tb >> 9, sq = tb & 511;
    #pragma unroll
    for (int i = 0; i < 32; i += 8) {
        int c = cb + ty + i;
        out[((size_t)(bq * NHEAD + (c >> 6)) * HEAD + (c & 63)) * SEQ + sq + tx] = tile[tx][ty + i];
    }
}

// ---------------- shared 64x64 tile core: A[M][K] bf16 x Bt[N][K] bf16 ----------------
__device__ __forceinline__ void gemm_tile_bt(
    const unsigned short* __restrict__ A, const unsigned short* __restrict__ Bt,
    int row0, int col0, int K, int kbeg, int kend,
    floatx4 (&acc)[2][2], unsigned short (&As)[64][72], unsigned short (&Bs)[64][72]) {
    int tid = threadIdx.x;
    int lane = tid & 63, wid = tid >> 6;
    int wm = wid >> 1, wn = wid & 1;
    int m16 = lane & 15, quad = lane >> 4;
    int sr = tid >> 2, sc = (tid & 3) << 4;          // staging: row, 16 bf16 cols
    const unsigned short* Ag = A + (size_t)(row0 + sr) * K + sc;
    const unsigned short* Bg = Bt + (size_t)(col0 + sr) * K + sc;
    for (int k0 = kbeg; k0 < kend; k0 += 64) {
        uint4 av0 = *(const uint4*)(Ag + k0);
        uint4 av1 = *(const uint4*)(Ag + k0 + 8);
        uint4 bv0 = *(const uint4*)(Bg + k0);
        uint4 bv1 = *(const uint4*)(Bg + k0 + 8);
        *(uint4*)&As[sr][sc]     = av0;
        *(uint4*)&As[sr][sc + 8] = av1;
        *(uint4*)&Bs[sr][sc]     = bv0;
        *(uint4*)&Bs[sr][sc + 8] = bv1;
        __syncthreads();
        #pragma unroll
        for (int kk = 0; kk < 2; kk++) {
            bf16x8 a0 = *(const bf16x8*)&As[wm * 32 + m16][kk * 32 + quad * 8];
            bf16x8 a1 = *(const bf16x8*)&As[wm * 32 + 16 + m16][kk * 32 + quad * 8];
            bf16x8 b0 = *(const bf16x8*)&Bs[wn * 32 + m16][kk * 32 + quad * 8];
            bf16x8 b1 = *(const bf16x8*)&Bs[wn * 32 + 16 + m16][kk * 32 + quad * 8];
            acc[0][0] = MFMA16(a0, b0, acc[0][0]);
            acc[0][1] = MFMA16(a0, b1, acc[0][1]);
            acc[1][0] = MFMA16(a1, b0, acc[1][0]);
            acc[1][1] = MFMA16(a1, b1, acc[1][1]);
        }
        __syncthreads();
    }
}

// ---------------- generic bf16-weight GEMM, optional split-K over blockIdx.z ----------------
template<bool OUT_BF16, bool GELU, int SPLITK>
__global__ __launch_bounds__(256) void gemm_bt(
    const unsigned short* __restrict__ A, const unsigned short* __restrict__ Bt,
    const float* __restrict__ bias, void* __restrict__ Cp, int N, int K) {
    __shared__ unsigned short As[64][72], Bs[64][72];
    int row0 = blockIdx.y * 64, col0 = blockIdx.x * 64;
    int kseg = K / SPLITK;
    int kbeg = kseg * blockIdx.z, kend = kbeg + kseg;
    floatx4 acc[2][2];
    #pragma unroll
    for (int mi = 0; mi < 2; mi++)
        #pragma unroll
        for (int ni = 0; ni < 2; ni++) acc[mi][ni] = (floatx4){0.f, 0.f, 0.f, 0.f};
    gemm_tile_bt(A, Bt, row0, col0, K, kbeg, kend, acc, As, Bs);

    int tid = threadIdx.x, lane = tid & 63, wid = tid >> 6;
    int wm = wid >> 1, wn = wid & 1, m16 = lane & 15, quad = lane >> 4;
    size_t outoff = (size_t)blockIdx.z * (size_t)(gridDim.y << 6) * N;
    #pragma unroll
    for (int ni = 0; ni < 2; ni++) {
        int colg = col0 + wn * 32 + ni * 16 + m16;
        float bval = (SPLITK == 1 || blockIdx.z == 0) ? bias[colg] : 0.0f;
        #pragma unroll
        for (int mi = 0; mi < 2; mi++) {
            #pragma unroll
            for (int r = 0; r < 4; r++) {
                int rowg = row0 + wm * 32 + mi * 16 + quad * 4 + r;
                float v = acc[mi][ni][r] + bval;
                if (GELU) v = 0.5f * v * (1.0f + erff(v * 0.70710678118654752f));
                if (OUT_BF16) ((unsigned short*)Cp)[(size_t)rowg * N + colg] = f2b(v);
                else          ((float*)Cp)[outoff + (size_t)rowg * N + colg] = v;
            }
        }
    }
}

// ---------------- fused Q,K,V,Pk,Pq projections: 1024 workgroups, one launch ----------------
// XCD-aware decode: op determined by (blockIdx.x & 7) so each XCD's L2 holds one A matrix
// + one weight. V output (op==2) is written TRANSPOSED: vbt[(b*NH+h)*HEAD+d][seq].
__global__ __launch_bounds__(256) void qkvp_gemm(
    const unsigned short* __restrict__ hb, const unsigned short* __restrict__ relb,
    const unsigned short* __restrict__ Wqt, const unsigned short* __restrict__ Wkt,
    const unsigned short* __restrict__ Wvt, const unsigned short* __restrict__ Wpkt,
    const unsigned short* __restrict__ Wpqt,
    const float* __restrict__ bq, const float* __restrict__ bk, const float* __restrict__ bv,
    const float* __restrict__ bpk, const float* __restrict__ bpq,
    unsigned short* __restrict__ qb, unsigned short* __restrict__ kb,
    unsigned short* __restrict__ vb, unsigned short* __restrict__ pkb,
    unsigned short* __restrict__ pqb) {
    __shared__ unsigned short As[64][72], Bs[64][72];
    int bid = blockIdx.x;
    int xcd = bid & 7, slot = bid >> 3;    // 128 slots per XCD
    int op, j;
    if (xcd < 6) { op = xcd >> 1; j = slot * 2 + (xcd & 1); }   // Q,K,V: j in [0,256)
    else         { op = xcd - 3;  j = slot; }                   // Pk,Pq: j in [0,128)
    int trow = j >> 3, tcol = j & 7;
    const unsigned short* A; const unsigned short* Bt; const float* bias; unsigned short* C;
    if (op < 3) {
        A = hb;
        Bt   = op == 0 ? Wqt : op == 1 ? Wkt : Wvt;
        bias = op == 0 ? bq  : op == 1 ? bk  : bv;
        C    = op == 0 ? qb  : op == 1 ? kb  : vb;
    } else {
        A = relb;
        Bt   = op == 3 ? Wpkt : Wpqt;
        bias = op == 3 ? bpk  : bpq;
        C    = op == 3 ? pkb  : pqb;
    }
    floatx4 acc[2][2];
    #pragma unroll
    for (int mi = 0; mi < 2; mi++)
        #pragma unroll
        for (int ni = 0; ni < 2; ni++) acc[mi][ni] = (floatx4){0.f, 0.f, 0.f, 0.f};
    gemm_tile_bt(A, Bt, trow * 64, tcol * 64, HID, 0, HID, acc, As, Bs);

    int tid = threadIdx.x, lane = tid & 63, wid = tid >> 6;
    int wm = wid >> 1, wn = wid & 1, m16 = lane & 15, quad = lane >> 4;
    if (op == 2) {
        // transposed V store: vbt[((b*NH+h)*HEAD+d)][seq], 4 consecutive seq per lane
        #pragma unroll
        for (int ni = 0; ni < 2; ni++) {
            int colg = tcol * 64 + wn * 32 + ni * 16 + m16;
            float bval = bias[colg];
            int h2 = colg >> 6, d2 = colg & 63;
            #pragma unroll
            for (int mi = 0; mi < 2; mi++) {
                int rg0 = trow * 64 + wm * 32 + mi * 16 + quad * 4;
                int b2 = rg0 >> 9, sq0 = rg0 & 511;
                ushort4 pv;
                pv.x = f2b(acc[mi][ni][0] + bval);
                pv.y = f2b(acc[mi][ni][1] + bval);
                pv.z = f2b(acc[mi][ni][2] + bval);
                pv.w = f2b(acc[mi][ni][3] + bval);
                *(ushort4*)(C + ((size_t)(b2 * NHEAD + h2) * HEAD + d2) * SEQ + sq0) = pv;
            }
        }
    } else {
        #pragma unroll
        for (int ni = 0; ni < 2; ni++) {
            int colg = tcol * 64 + wn * 32 + ni * 16 + m16;
            float bval = bias[colg];
            #pragma unroll
            for (int mi = 0; mi < 2; mi++) {
                #pragma unroll
                for (int r = 0; r < 4; r++) {
                    int rowg = trow * 64 + wm * 32 + mi * 16 + quad * 4 + r;
                    C[(size_t)rowg * HID + colg] = f2b(acc[mi][ni][r] + bval);
                }
            }
        }
    }
}

// ---------------- fallback MFMA GEMM: B fp32 inline-converted (baseline path) ----------------
template<bool OUT_BF16, bool GELU>
__global__ __launch_bounds__(256) void mfma_gemm(
    const unsigned short* __restrict__ A, const float* __restrict__ B,
    const float* __restrict__ bias, void* __restrict__ Cp, int N, int K) {
    __shared__ unsigned short As[64][72];   // [m][k]
    __shared__ unsigned short Bs[64][72];   // [n][k]
    int tid = threadIdx.x;
    int lane = tid & 63, wid = tid >> 6;
    int wm = wid >> 1, wn = wid & 1;
    int row0 = blockIdx.y * 64, col0 = blockIdx.x * 64;
    int m16 = lane & 15, quad = lane >> 4;

    int ar = tid >> 2, ac = (tid & 3) << 4;
    int bk = (tid >> 3) << 1, bn = (tid & 7) << 3;

    const unsigned short* Ag = A + (size_t)(row0 + ar) * K + ac;
    const float* Bg = B + (size_t)bk * N + col0 + bn;

    floatx4 acc[2][2];
    #pragma unroll
    for (int mi = 0; mi < 2; mi++)
        #pragma unroll
        for (int ni = 0; ni < 2; ni++) acc[mi][ni] = (floatx4){0.f, 0.f, 0.f, 0.f};

    for (int k0 = 0; k0 < K; k0 += 64) {
        uint4 av0 = *(const uint4*)(Ag + k0);
        uint4 av1 = *(const uint4*)(Ag + k0 + 8);
        const float* br0 = Bg + (size_t)k0 * N;
        const float* br1 = br0 + N;
        float4 b00 = *(const float4*)br0, b01 = *(const float4*)(br0 + 4);
        float4 b10 = *(const float4*)br1, b11 = *(const float4*)(br1 + 4);
        *(uint4*)&As[ar][ac] = av0;
        *(uint4*)&As[ar][ac + 8] = av1;
        float lo[8] = {b00.x, b00.y, b00.z, b00.w, b01.x, b01.y, b01.z, b01.w};
        float hi[8] = {b10.x, b10.y, b10.z, b10.w, b11.x, b11.y, b11.z, b11.w};
        #pragma unroll
        for (int i = 0; i < 8; i++) {
            unsigned int p = (unsigned int)f2b(lo[i]) | ((unsigned int)f2b(hi[i]) << 16);
            *(unsigned int*)&Bs[bn + i][bk] = p;
        }
        __syncthreads();
        #pragma unroll
        for (int kk = 0; kk < 2; kk++) {
            bf16x8 a0 = *(const bf16x8*)&As[wm * 32 + m16][kk * 32 + quad * 8];
            bf16x8 a1 = *(const bf16x8*)&As[wm * 32 + 16 + m16][kk * 32 + quad * 8];
            bf16x8 b0 = *(const bf16x8*)&Bs[wn * 32 + m16][kk * 32 + quad * 8];
            bf16x8 b1 = *(const bf16x8*)&Bs[wn * 32 + 16 + m16][kk * 32 + quad * 8];
            acc[0][0] = MFMA16(a0, b0, acc[0][0]);
            acc[0][1] = MFMA16(a0, b1, acc[0][1]);
            acc[1][0] = MFMA16(a1, b0, acc[1][0]);
            acc[1][1] = MFMA16(a1, b1, acc[1][1]);
        }
        __syncthreads();
    }
    #pragma unroll
    for (int ni = 0; ni < 2; ni++) {
        int colg = col0 + wn * 32 + ni * 16 + m16;
        float bv = bias[colg];
        #pragma unroll
        for (int mi = 0; mi < 2; mi++) {
            #pragma unroll
            for (int r = 0; r < 4; r++) {
                int rowg = row0 + wm * 32 + mi * 16 + quad * 4 + r;
                float v = acc[mi][ni][r] + bv;
                if (GELU) v = 0.5f * v * (1.0f + erff(v * 0.70710678118654752f));
                if (OUT_BF16) ((unsigned short*)Cp)[(size_t)rowg * N + colg] = f2b(v);
                else          ((float*)Cp)[(size_t)rowg * N + colg] = v;
            }
        }
    }
}

// ---------------- MFMA fused flash-style disentangled attention, v4 ----------------
// Barrier-free main loop: all MFMA operands (K, V^T, PK, PQ windows) are loaded directly
// from global (L2-resident via hh=bid&7 XCD mapping) into register fragments; LDS holds
// only wave-local band scratch (Afs/Bfs/Pls). K/PK/PQ fragments are prefetched one phase
// ahead (double register set). V is read from the pre-transposed vbt buffer. The only
// __syncthreads is the final split-k merge.
__global__ __launch_bounds__(256, 2) void attn_kernel(
    const unsigned short* __restrict__ Q, const unsigned short* __restrict__ K,
    const unsigned short* __restrict__ Vtg,
    const unsigned short* __restrict__ PK, const unsigned short* __restrict__ PQ,
    const int* __restrict__ am, unsigned short* __restrict__ ctx) {
    __shared__ float Afs[4][16][49];           // per-wave A band (c2p)
    __shared__ float Bfs[4][32][50];           // per-wave B band (p2c); s=1 wave's reused as mergeO
    __shared__ unsigned short Pls[4][16][40];  // per-wave P (bf16)
    __shared__ float mergeML[2][2][16];        // [strip][m|l][row]

    int bid = blockIdx.x;
    int hh = bid & 7;                  // head -> XCD (round-robin dispatch)
    int b  = (bid >> 3) & 3;
    int q0 = (bid >> 5) * 32;
    int bh = b * NHEAD + hh;
    int tid = threadIdx.x;
    int lane = tid & 63, wave = tid >> 6;
    int u = wave >> 1;                 // q-strip
    int s = wave & 1;                  // k-parity
    int quad = lane >> 4, m16 = lane & 15;
    const float inv_scale = 0.07216878364870323f; // 1/sqrt(192)

    // Q fragments in registers (row=m16, k=quad*8, 2 k-chunks)
    const unsigned short* qg = Q + (size_t)(b * SEQ + q0 + u * 16 + m16) * HID + hh * HEAD;
    bf16x8 qf0 = *(const bf16x8*)(qg + quad * 8);
    bf16x8 qf1 = *(const bf16x8*)(qg + 32 + quad * 8);

    // key-mask bitmask: bit (2t+n) = am[key = 32t + 16n + m16]
    unsigned int mbits = 0;
    #pragma unroll
    for (int i = 0; i < 32; i++)
        mbits |= (unsigned int)(am[b * SEQ + i * 16 + m16] != 0) << i;

    floatx4 accO[4];
    #pragma unroll
    for (int nt = 0; nt < 4; nt++) accO[nt] = (floatx4){0.f, 0.f, 0.f, 0.f};
    float mreg[4] = {NEG_BIG, NEG_BIG, NEG_BIG, NEG_BIG};
    float lreg[4] = {0.f, 0.f, 0.f, 0.f};

    struct KPRegs { bf16x8 kf[2][2]; bf16x8 pk[3][2]; bf16x8 pq[3][2]; };

    auto load_kp = [&](int t, KPRegs& R) {
        const unsigned short* kg = K + (size_t)(b * SEQ + t * 32 + m16) * HID + hh * HEAD + quad * 8;
        #pragma unroll
        for (int n = 0; n < 2; n++) {
            R.kf[n][0] = *(const bf16x8*)(kg + n * 16 * HID);
            R.kf[n][1] = *(const bf16x8*)(kg + n * 16 * HID + 32);
        }
        int baseA = q0 + 16 * u - 32 * t + 481;   // pk row base; rows baseA..baseA+46 gathered
        const unsigned short* pg = PK + (size_t)(baseA + m16) * HID + hh * HEAD + quad * 8;
        #pragma unroll
        for (int nt = 0; nt < 3; nt++) {
            R.pk[nt][0] = *(const bf16x8*)(pg + nt * 16 * HID);
            R.pk[nt][1] = *(const bf16x8*)(pg + nt * 16 * HID + 32);
        }
        int baseB = 32 * t - q0 - 16 * u + 497;   // pq row base
        const unsigned short* pg2 = PQ + (size_t)(baseB + m16) * HID + hh * HEAD + quad * 8;
        #pragma unroll
        for (int nt = 0; nt < 3; nt++) {
            R.pq[nt][0] = *(const bf16x8*)(pg2 + nt * 16 * HID);
            R.pq[nt][1] = *(const bf16x8*)(pg2 + nt * 16 * HID + 32);
        }
    };

    auto do_phase = [&](int t, KPRegs& R) {
        // V^T fragments for PV (issued early; consumed last)
        bf16x8 vf[4];
        const unsigned short* vg = Vtg + ((size_t)bh * HEAD + m16) * SEQ + t * 32 + quad * 8;
        #pragma unroll
        for (int nt = 0; nt < 4; nt++) vf[nt] = *(const bf16x8*)(vg + nt * 16 * SEQ);

        // S = Q @ K^T (16x32)
        floatx4 accS[2];
        #pragma unroll
        for (int n = 0; n < 2; n++) {
            accS[n] = (floatx4){0.f, 0.f, 0.f, 0.f};
            accS[n] = MFMA16(qf0, R.kf[n][0], accS[n]);
            accS[n] = MFMA16(qf1, R.kf[n][1], accS[n]);
        }
        // A = Q @ PKwin^T (16x48)
        {
            floatx4 accA[3];
            #pragma unroll
            for (int nt = 0; nt < 3; nt++) {
                accA[nt] = (floatx4){0.f, 0.f, 0.f, 0.f};
                accA[nt] = MFMA16(qf0, R.pk[nt][0], accA[nt]);
                accA[nt] = MFMA16(qf1, R.pk[nt][1], accA[nt]);
            }
            #pragma unroll
            for (int nt = 0; nt < 3; nt++)
                #pragma unroll
                for (int r = 0; r < 4; r++)
                    Afs[wave][quad * 4 + r][nt * 16 + m16] = accA[nt][r];
        }
        // B = K @ PQwin^T (32x48)
        {
            floatx4 accB[2][3];
            #pragma unroll
            for (int mt = 0; mt < 2; mt++)
                #pragma unroll
                for (int nt = 0; nt < 3; nt++) {
                    accB[mt][nt] = (floatx4){0.f, 0.f, 0.f, 0.f};
                    accB[mt][nt] = MFMA16(R.kf[mt][0], R.pq[nt][0], accB[mt][nt]);
                    accB[mt][nt] = MFMA16(R.kf[mt][1], R.pq[nt][1], accB[mt][nt]);
                }
            #pragma unroll
            for (int mt = 0; mt < 2; mt++)
                #pragma unroll
                for (int nt = 0; nt < 3; nt++)
                    #pragma unroll
                    for (int r = 0; r < 4; r++)
                        Bfs[wave][mt * 16 + quad * 4 + r][nt * 16 + m16] = accB[mt][nt][r];
        }
        // gather + combine + in-register online softmax
        unsigned int bm = mbits >> (2 * t);
        float sv[2][4];
        float tmax[4] = {NEG_BIG, NEG_BIG, NEG_BIG, NEG_BIG};
        #pragma unroll
        for (int n = 0; n < 2; n++) {
            #pragma unroll
            for (int r = 0; r < 4; r++) {
                int qq = quad * 4 + r;
                int kc = n * 16 + m16;
                float av = Afs[wave][qq][qq - kc + 31];
                float bv = Bfs[wave][kc][kc - qq + 15];
                float x = (accS[n][r] + av + bv) * inv_scale;
                x = ((bm >> n) & 1) ? x : NEG_BIG;
                sv[n][r] = x;
                tmax[r] = fmaxf(tmax[r], x);
            }
        }
        float alpha[4];
        #pragma unroll
        for (int r = 0; r < 4; r++) {
            float tm = tmax[r];
            tm = fmaxf(tm, __shfl_xor(tm, 1));
            tm = fmaxf(tm, __shfl_xor(tm, 2));
            tm = fmaxf(tm, __shfl_xor(tm, 4));
            tm = fmaxf(tm, __shfl_xor(tm, 8));
            float mo = mreg[r];
            float mn = fmaxf(mo, tm);
            alpha[r] = __expf(mo - mn);
            mreg[r] = mn;
        }
        float psum[4] = {0.f, 0.f, 0.f, 0.f};
        #pragma unroll
        for (int n = 0; n < 2; n++) {
            #pragma unroll
            for (int r = 0; r < 4; r++) {
                float p = (sv[n][r] > -1.5e38f) ? __expf(sv[n][r] - mreg[r]) : 0.0f;
                unsigned short pb = f2b(p);
                Pls[wave][quad * 4 + r][n * 16 + m16] = pb;
                psum[r] += b2f(pb);
            }
        }
        #pragma unroll
        for (int r = 0; r < 4; r++) {
            float ps = psum[r];
            ps += __shfl_xor(ps, 1);
            ps += __shfl_xor(ps, 2);
            ps += __shfl_xor(ps, 4);
            ps += __shfl_xor(ps, 8);
            lreg[r] = lreg[r] * alpha[r] + ps;
        }
        // rescale O, then PV
        #pragma unroll
        for (int nt = 0; nt < 4; nt++)
            #pragma unroll
            for (int r = 0; r < 4; r++) accO[nt][r] *= alpha[r];
        {
            bf16x8 pf = *(const bf16x8*)&Pls[wave][m16][quad * 8];
            #pragma unroll
            for (int nt = 0; nt < 4; nt++)
                accO[nt] = MFMA16(pf, vf[nt], accO[nt]);
        }
    };

    // prefetched phase loop: wave handles tiles t = s, s+2, ..., s+14
    KPRegs Ra, Rb;
    load_kp(s, Ra);
    for (int pp = 0; pp < 4; pp++) {
        int t0 = 4 * pp + s;
        load_kp(t0 + 2, Rb);
        do_phase(t0, Ra);
        if (pp < 3) load_kp(t0 + 4, Ra);
        do_phase(t0 + 2, Rb);
    }

    // merge the two k-halves per q-strip (flash split-k merge); single barrier
    float* mo = &Bfs[u * 2 + 1][0][0];   // s=1 wave's own Bfs; stride-66 layout (1053 < 1600 floats)
    if (s == 1) {
        #pragma unroll
        for (int nt = 0; nt < 4; nt++)
            #pragma unroll
            for (int r = 0; r < 4; r++)
                mo[(quad * 4 + r) * 66 + nt * 16 + m16] = accO[nt][r];
        if (m16 == 0) {
            #pragma unroll
            for (int r = 0; r < 4; r++) {
                mergeML[u][0][quad * 4 + r] = mreg[r];
                mergeML[u][1][quad * 4 + r] = lreg[r];
            }
        }
    }
    __syncthreads();
    if (s == 0) {
        #pragma unroll
        for (int r = 0; r < 4; r++) {
            int row = quad * 4 + r;
            float m1 = mergeML[u][0][row], l1 = mergeML[u][1][row];
            float m0 = mreg[r], l0 = lreg[r];
            float mt = fmaxf(m0, m1);
            float a0 = __expf(m0 - mt), a1 = __expf(m1 - mt);
            float lt = l0 * a0 + l1 * a1;
            float inv = lt > 0.0f ? 1.0f / lt : 0.0f;
            inv *= (float)am[b * SEQ + q0 + u * 16 + row];
            #pragma unroll
            for (int nt = 0; nt < 4; nt++) {
                float o1 = mo[row * 66 + nt * 16 + m16];
                float val = (accO[nt][r] * a0 + o1 * a1) * inv;
                ctx[(size_t)(b * SEQ + q0 + u * 16 + row) * HID + hh * HEAD + nt * 16 + m16] = f2b(val);
            }
        }
    }
}

// ---------------- output copy / classifier (fp32 out) ----------------
__global__ void copy_f_kernel(const float* __restrict__ in, float* __restrict__ out, int n) {
    int i = blockIdx.x * 256 + threadIdx.x;
    if (i < n) out[i] = in[i];
}
__global__ void cls_kernel(const float* __restrict__ h, const float* __restrict__ cls_w,
                           const float* __restrict__ cls_b, float* __restrict__ out) {
    int t = blockIdx.x, v = threadIdx.x;
    if (v < VOCAB) {
        const float* hr = h + (size_t)t * HID;
        const float* wr = cls_w + (size_t)v * HID;
        float acc = cls_b[v];
        for (int d = 0; d < HID; d++) acc += hr[d] * wr[d];
        out[t * VOCAB + v] = acc;
    }
}

extern "C" void kernel_launch(void* const* d_in, const int* in_sizes, int n_in,
                              void* d_out, int out_size, void* d_ws, size_t ws_size,
                              hipStream_t stream) {
    const int* x     = (const int*)d_in[0];
    const int* am    = (const int*)d_in[1];
    const float* word_emb = (const float*)d_in[2];
    const float* emb_g    = (const float*)d_in[3];
    const float* emb_b    = (const float*)d_in[4];
    const float* rel_emb  = (const float*)d_in[5];
    const float* Wq  = (const float*)d_in[6];  const float* bq  = (const float*)d_in[7];
    const float* Wk  = (const float*)d_in[8];  const float* bk  = (const float*)d_in[9];
    const float* Wv  = (const float*)d_in[10]; const float* bv  = (const float*)d_in[11];
    const float* Wpk = (const float*)d_in[12]; const float* bpk = (const float*)d_in[13];
    const float* Wpq = (const float*)d_in[14]; const float* bpq = (const float*)d_in[15];
    const float* Wo  = (const float*)d_in[16]; const float* bo  = (const float*)d_in[17];
    const float* ln1g = (const float*)d_in[18]; const float* ln1b = (const float*)d_in[19];
    const float* W1  = (const float*)d_in[20]; const float* b1  = (const float*)d_in[21];
    const float* W2  = (const float*)d_in[22]; const float* b2  = (const float*)d_in[23];
    const float* ln2g = (const float*)d_in[24]; const float* ln2b = (const float*)d_in[25];
    const float* cls_w = (const float*)d_in[26]; const float* cls_b = (const float*)d_in[27];

    char* wsb = (char*)d_ws;
    const size_t NEED_BIG = 107u << 20;   // 23 MB activations + 84 MB bf16 weights

    if (ws_size >= NEED_BIG) {
        // ---- big-workspace path: preconverted transposed bf16 weights ----
        float* h  = (float*)wsb;                                      // 4 MB
        float* t1 = (float*)(wsb + (4u << 20));                       // 4 MB (split-K part 0)
        float* t2 = (float*)(wsb + (8u << 20));                       // 4 MB (split-K part 1)
        unsigned short* qb   = (unsigned short*)(wsb + (12u << 20));  // 2 MB
        unsigned short* kb   = (unsigned short*)(wsb + (14u << 20));  // 2 MB
        unsigned short* vb   = (unsigned short*)(wsb + (16u << 20));  // 2 MB (TRANSPOSED layout)
        unsigned short* pkb  = (unsigned short*)(wsb + (18u << 20));  // 1 MB
        unsigned short* pqb  = (unsigned short*)(wsb + (19u << 20));  // 1 MB
        unsigned short* relb = (unsigned short*)(wsb + (20u << 20));  // 1 MB
        unsigned short* hb   = (unsigned short*)(wsb + (21u << 20));  // 2 MB
        unsigned short* ctx  = hb;   // alias: hb dead between attn and add_ln1
        unsigned short* ffb  = qb;   // alias: qb..pqb (8 MB) dead by FF1
        unsigned short* Wqt  = (unsigned short*)(wsb + (23u << 20));  // 6x6 MB: q,k,v,pk,pq,o
        unsigned short* W1t  = (unsigned short*)(wsb + (59u << 20));  // 24 MB
        unsigned short* W2t  = (unsigned short*)(wsb + (83u << 20));  // 24 MB

        const size_t M512 = (size_t)HID * HID;   // elements per 512x512 matrix

        tcvt6_kernel<<<dim3(16, 16, 72), dim3(32, 8), 0, stream>>>(Wq, Wk, Wv, Wpk, Wpq, Wo, Wqt);
        tcvt_kernel<<<dim3(64, 16, 12), dim3(32, 8), 0, stream>>>(W1, W1t, HID, FFDIM);
        tcvt_kernel<<<dim3(16, 64, 12), dim3(32, 8), 0, stream>>>(W2, W2t, FFDIM, HID);
        cvt_rel_kernel<<<dim3(SPAN2 * HID / 1024), dim3(256), 0, stream>>>(rel_emb, relb);
        embed_ln_kernel<<<dim3(TOK), dim3(256), 0, stream>>>(x, am, word_emb, emb_g, emb_b, h, hb);

        for (int l = 0; l < NLAYER; l++) {
            qkvp_gemm<<<dim3(1024), dim3(256), 0, stream>>>(
                hb, relb,
                Wqt + (size_t)(0 * NLAYER + l) * M512, Wqt + (size_t)(1 * NLAYER + l) * M512,
                Wqt + (size_t)(2 * NLAYER + l) * M512, Wqt + (size_t)(3 * NLAYER + l) * M512,
                Wqt + (size_t)(4 * NLAYER + l) * M512,
                bq + l * HID, bk + l * HID, bv + l * HID, bpk + l * HID, bpq + l * HID,
                qb, kb, vb, pkb, pqb);

            attn_kernel<<<dim3(512), dim3(256), 0, stream>>>(
                qb, kb, vb, pkb, pqb, am, ctx);

            gemm_bt<false, false, 2><<<dim3(HID / 64, TOK / 64, 2), dim3(256), 0, stream>>>(
                ctx, Wqt + (size_t)(5 * NLAYER + l) * M512, bo + l * HID, t1, HID, HID);
            add_ln2_kernel<<<dim3(TOK), dim3(256), 0, stream>>>(t1, t2, ln1g + l * HID, ln1b + l * HID, h, hb);

            gemm_bt<true, true, 1><<<dim3(FFDIM / 64, TOK / 64, 1), dim3(256), 0, stream>>>(
                hb, W1t + (size_t)l * HID * FFDIM, b1 + l * FFDIM, ffb, FFDIM, HID);
            gemm_bt<false, false, 2><<<dim3(HID / 64, TOK / 64, 2), dim3(256), 0, stream>>>(
                ffb, W2t + (size_t)l * HID * FFDIM, b2 + l * HID, t1, HID, FFDIM);
            add_ln2_kernel<<<dim3(TOK), dim3(256), 0, stream>>>(t1, t2, ln2g + l * HID, ln2b + l * HID, h, hb);
        }

        float* out_f = (float*)d_out;
        copy_f_kernel<<<dim3(TOK * HID / 256), dim3(256), 0, stream>>>(h, out_f, TOK * HID);
        cls_kernel<<<dim3(TOK), dim3(32), 0, stream>>>(h, cls_w, cls_b, out_f + TOK * HID);
        return;
    }

    // ---- fallback path: 21 MB layout, inline fp32->bf16 weight conversion + V transpose ----
    const size_t NEEDED = 21u << 20;
    if (ws_size < NEEDED) return;
    float* h  = (float*)wsb;                                     // 4 MB
    float* t1 = (float*)(wsb + (4u << 20));                      // 4 MB
    unsigned short* qb   = (unsigned short*)(wsb + (8u << 20));  // 2 MB
    unsigned short* kb   = qb  + (1u << 20);                     // 2 MB
    unsigned short* vb   = kb  + (1u << 20);                     // 2 MB (token-major)
    unsigned short* pkb  = vb  + (1u << 20);                     // 1 MB
    unsigned short* pqb  = pkb + (1u << 19);                     // 1 MB
    unsigned short* relb = (unsigned short*)(wsb + (16u << 20)); // 1 MB
    unsigned short* hb   = (unsigned short*)(wsb + (17u << 20)); // 2 MB
    unsigned short* vbt  = (unsigned short*)(wsb + (19u << 20)); // 2 MB (transposed V)
    unsigned short* ctx  = hb;   // alias: hb dead between V-GEMM and add_ln1
    unsigned short* ffb  = qb;   // alias: q..pq dead by FF1

    cvt_rel_kernel<<<dim3(SPAN2 * HID / 1024), dim3(256), 0, stream>>>(rel_emb, relb);
    embed_ln_kernel<<<dim3(TOK), dim3(256), 0, stream>>>(x, am, word_emb, emb_g, emb_b, h, hb);

    for (int l = 0; l < NLAYER; l++) {
        const float* Wq_l = Wq + (size_t)l * HID * HID;
        const float* Wk_l = Wk + (size_t)l * HID * HID;
        const float* Wv_l = Wv + (size_t)l * HID * HID;
        const float* Wo_l = Wo + (size_t)l * HID * HID;
        const float* Wpk_l = Wpk + (size_t)l * HID * HID;
        const float* Wpq_l = Wpq + (size_t)l * HID * HID;
        const float* W1_l = W1 + (size_t)l * HID * FFDIM;
        const float* W2_l = W2 + (size_t)l * FFDIM * HID;

        mfma_gemm<true,  false><<<dim3(HID/64, TOK/64),   dim3(256), 0, stream>>>(hb,   Wq_l,  bq + l*HID,  qb,  HID, HID);
        mfma_gemm<true,  false><<<dim3(HID/64, TOK/64),   dim3(256), 0, stream>>>(hb,   Wk_l,  bk + l*HID,  kb,  HID, HID);
        mfma_gemm<true,  false><<<dim3(HID/64, TOK/64),   dim3(256), 0, stream>>>(hb,   Wv_l,  bv + l*HID,  vb,  HID, HID);
        vtr_kernel<<<dim3(HID/32, TOK/32), dim3(32, 8), 0, stream>>>(vb, vbt);
        mfma_gemm<true,  false><<<dim3(HID/64, SPAN2/64), dim3(256), 0, stream>>>(relb, Wpk_l, bpk + l*HID, pkb, HID, HID);
        mfma_gemm<true,  false><<<dim3(HID/64, SPAN2/64), dim3(256), 0, stream>>>(relb, Wpq_l, bpq + l*HID, pqb, HID, HID);

        attn_kernel<<<dim3(512), dim3(256), 0, stream>>>(qb, kb, vbt, pkb, pqb, am, ctx);

        mfma_gemm<false, false><<<dim3(HID/64, TOK/64),   dim3(256), 0, stream>>>(ctx,  Wo_l,  bo + l*HID,  t1,  HID, HID);
        add_ln_kernel<<<dim3(TOK), dim3(256), 0, stream>>>(t1, ln1g + l*HID, ln1b + l*HID, h, hb);

        mfma_gemm<true,  true ><<<dim3(FFDIM/64, TOK/64), dim3(256), 0, stream>>>(hb,   W1_l,  b1 + l*FFDIM, ffb, FFDIM, HID);
        mfma_gemm<false, false><<<dim3(HID/64, TOK/64),   dim3(256), 0, stream>>>(ffb,  W2_l,  b2 + l*HID,  t1,  HID, FFDIM);
        add_ln_kernel<<<dim3(TOK), dim3(256), 0, stream>>>(t1, ln2g + l*HID, ln2b + l*HID, h, hb);
    }

    float* out_f = (float*)d_out;
    copy_f_kernel<<<dim3(TOK*HID/256), dim3(256), 0, stream>>>(h, out_f, TOK*HID);
    cls_kernel<<<dim3(TOK), dim3(32), 0, stream>>>(h, cls_w, cls_b, out_f + TOK*HID);
}

// Round 5
// 1430.807 us; speedup vs baseline: 1.0515x; 1.0515x over previous
//
#include <hip/hip_runtime.h>
#include <hip/hip_bf16.h>

// Model dims (fixed by the reference)
#define BATCH  4
#define SEQ    512
#define TOK    (BATCH*SEQ)     // 2048
#define HID    512
#define NHEAD  8
#define HEAD   64
#define FFDIM  2048
#define NLAYER 12
#define SPAN2  1024            // 2*SPAN
#define VOCAB  25
#define LNEPS  1e-7f
#define NEG_BIG -3.0e38f

typedef __attribute__((ext_vector_type(8))) short bf16x8;   // 8 bf16 = 4 VGPRs
typedef __attribute__((ext_vector_type(4))) float floatx4;

#define MFMA16(a, b, c) __builtin_amdgcn_mfma_f32_16x16x32_bf16((a), (b), (c), 0, 0, 0)

__device__ __forceinline__ float b2f(unsigned short u) {
    return __uint_as_float(((unsigned int)u) << 16);
}
__device__ __forceinline__ unsigned short f2b(float f) {
    __hip_bfloat16 h = __float2bfloat16(f);
    return *(unsigned short*)&h;
}

// ---------------- block reductions (blockDim = 256, 1-D) ----------------
__device__ __forceinline__ float block_reduce_sum(float v, float* red) {
    int tid = threadIdx.x;
    red[tid] = v; __syncthreads();
    for (int s = 128; s > 0; s >>= 1) { if (tid < s) red[tid] += red[tid + s]; __syncthreads(); }
    float r = red[0]; __syncthreads();
    return r;
}

// ---------------- embedding gather + LN + mask (writes fp32 h and bf16 hb) ----------------
__global__ void embed_ln_kernel(const int* __restrict__ x, const int* __restrict__ am,
                                const float* __restrict__ word_emb,
                                const float* __restrict__ g, const float* __restrict__ bb,
                                float* __restrict__ h, unsigned short* __restrict__ hb) {
    __shared__ float red[256];
    int t = blockIdx.x, tid = threadIdx.x;
    const float* we = word_emb + (size_t)x[t] * HID;
    float v1 = we[tid], v2 = we[tid + 256];
    float mean = block_reduce_sum(v1 + v2, red) * (1.0f / HID);
    float d1 = v1 - mean, d2 = v2 - mean;
    float var = block_reduce_sum(d1 * d1 + d2 * d2, red) * (1.0f / HID);
    float rstd = rsqrtf(var + LNEPS);
    float maskf = (float)am[t];
    size_t base = (size_t)t * HID;
    float o1 = (d1 * rstd * g[tid]       + bb[tid])       * maskf;
    float o2 = (d2 * rstd * g[tid + 256] + bb[tid + 256]) * maskf;
    h[base + tid] = o1;        h[base + tid + 256] = o2;
    hb[base + tid] = f2b(o1);  hb[base + tid + 256] = f2b(o2);
}

// ---------------- residual add + LN, single tmp (fallback path) ----------------
__global__ void add_ln_kernel(const float* __restrict__ tmp,
                              const float* __restrict__ g, const float* __restrict__ bb,
                              float* __restrict__ h, unsigned short* __restrict__ hb) {
    __shared__ float red[256];
    int t = blockIdx.x, tid = threadIdx.x;
    size_t base = (size_t)t * HID;
    float v1 = tmp[base + tid] + h[base + tid];
    float v2 = tmp[base + tid + 256] + h[base + tid + 256];
    float mean = block_reduce_sum(v1 + v2, red) * (1.0f / HID);
    float d1 = v1 - mean, d2 = v2 - mean;
    float var = block_reduce_sum(d1 * d1 + d2 * d2, red) * (1.0f / HID);
    float rstd = rsqrtf(var + LNEPS);
    float o1 = d1 * rstd * g[tid]       + bb[tid];
    float o2 = d2 * rstd * g[tid + 256] + bb[tid + 256];
    h[base + tid] = o1;        h[base + tid + 256] = o2;
    hb[base + tid] = f2b(o1);  hb[base + tid + 256] = f2b(o2);
}

// ---------------- residual add + LN, two split-K partials ----------------
__global__ void add_ln2_kernel(const float* __restrict__ t1a, const float* __restrict__ t1b,
                               const float* __restrict__ g, const float* __restrict__ bb,
                               float* __restrict__ h, unsigned short* __restrict__ hb) {
    __shared__ float red[256];
    int t = blockIdx.x, tid = threadIdx.x;
    size_t base = (size_t)t * HID;
    float v1 = t1a[base + tid] + t1b[base + tid] + h[base + tid];
    float v2 = t1a[base + tid + 256] + t1b[base + tid + 256] + h[base + tid + 256];
    float mean = block_reduce_sum(v1 + v2, red) * (1.0f / HID);
    float d1 = v1 - mean, d2 = v2 - mean;
    float var = block_reduce_sum(d1 * d1 + d2 * d2, red) * (1.0f / HID);
    float rstd = rsqrtf(var + LNEPS);
    float o1 = d1 * rstd * g[tid]       + bb[tid];
    float o2 = d2 * rstd * g[tid + 256] + bb[tid + 256];
    h[base + tid] = o1;        h[base + tid + 256] = o2;
    hb[base + tid] = f2b(o1);  hb[base + tid + 256] = f2b(o2);
}

// ---------------- fp32 -> bf16 convert (rel_emb, n multiple of 1024) ----------------
__global__ void cvt_rel_kernel(const float* __restrict__ in, unsigned short* __restrict__ out) {
    int i = (blockIdx.x * 256 + threadIdx.x) * 4;
    float4 v = *(const float4*)(in + i);
    out[i] = f2b(v.x); out[i+1] = f2b(v.y); out[i+2] = f2b(v.z); out[i+3] = f2b(v.w);
}

// ---------------- transpose+convert: W[K][N] fp32 -> Wt[N][K] bf16, blockIdx.z = layer ----------------
__global__ void tcvt_kernel(const float* __restrict__ in, unsigned short* __restrict__ out,
                            int K, int N) {
    __shared__ float tile[32][33];
    int l = blockIdx.z;
    const float* ip = in + (size_t)l * K * N;
    unsigned short* op = out + (size_t)l * K * N;
    int kb = blockIdx.y * 32, nb = blockIdx.x * 32;
    int tx = threadIdx.x, ty = threadIdx.y;   // block (32,8)
    #pragma unroll
    for (int i = 0; i < 32; i += 8) tile[ty + i][tx] = ip[(size_t)(kb + ty + i) * N + nb + tx];
    __syncthreads();
    #pragma unroll
    for (int i = 0; i < 32; i += 8) op[(size_t)(nb + ty + i) * K + kb + tx] = f2b(tile[tx][ty + i]);
}

// six [12][512][512] weight arrays in one launch; z = l*6 + w; out contiguous [w][l][512][512]
__global__ void tcvt6_kernel(const float* __restrict__ Wq, const float* __restrict__ Wk,
                             const float* __restrict__ Wv, const float* __restrict__ Wpk,
                             const float* __restrict__ Wpq, const float* __restrict__ Wo,
                             unsigned short* __restrict__ out) {
    __shared__ float tile[32][33];
    int z = blockIdx.z, l = z / 6, w = z - l * 6;
    const float* src = w == 0 ? Wq : w == 1 ? Wk : w == 2 ? Wv : w == 3 ? Wpk : w == 4 ? Wpq : Wo;
    const float* ip = src + (size_t)l * HID * HID;
    unsigned short* op = out + ((size_t)w * NLAYER + l) * HID * HID;
    int kb = blockIdx.y * 32, nb = blockIdx.x * 32;
    int tx = threadIdx.x, ty = threadIdx.y;
    #pragma unroll
    for (int i = 0; i < 32; i += 8) tile[ty + i][tx] = ip[(size_t)(kb + ty + i) * HID + nb + tx];
    __syncthreads();
    #pragma unroll
    for (int i = 0; i < 32; i += 8) op[(size_t)(nb + ty + i) * HID + kb + tx] = f2b(tile[tx][ty + i]);
}

// ---------------- shared 64x64 tile core, double-buffered LDS staging ----------------
// Per iteration: issue global loads for tile k+1 -> MFMA on buf[cur] (hides L2 latency)
// -> LDS-write tile k+1 into buf[cur^1] -> single barrier -> flip.
__device__ __forceinline__ void gemm_tile_bt(
    const unsigned short* __restrict__ A, const unsigned short* __restrict__ Bt,
    int row0, int col0, int K, int kbeg, int kend,
    floatx4 (&acc)[2][2], unsigned short (&As)[2][64][72], unsigned short (&Bs)[2][64][72]) {
    int tid = threadIdx.x;
    int lane = tid & 63, wid = tid >> 6;
    int wm = wid >> 1, wn = wid & 1;
    int m16 = lane & 15, quad = lane >> 4;
    int sr = tid >> 2, sc = (tid & 3) << 4;          // staging: row, 16 bf16 cols
    const unsigned short* Ag = A + (size_t)(row0 + sr) * K + sc;
    const unsigned short* Bg = Bt + (size_t)(col0 + sr) * K + sc;

    uint4 av0 = *(const uint4*)(Ag + kbeg);
    uint4 av1 = *(const uint4*)(Ag + kbeg + 8);
    uint4 bv0 = *(const uint4*)(Bg + kbeg);
    uint4 bv1 = *(const uint4*)(Bg + kbeg + 8);
    *(uint4*)&As[0][sr][sc]     = av0;
    *(uint4*)&As[0][sr][sc + 8] = av1;
    *(uint4*)&Bs[0][sr][sc]     = bv0;
    *(uint4*)&Bs[0][sr][sc + 8] = bv1;
    __syncthreads();

    int cur = 0;
    for (int k0 = kbeg; k0 < kend; k0 += 64) {
        int k1 = k0 + 64;
        bool more = k1 < kend;                 // uniform across block
        if (more) {                            // issue next-tile loads early
            av0 = *(const uint4*)(Ag + k1);
            av1 = *(const uint4*)(Ag + k1 + 8);
            bv0 = *(const uint4*)(Bg + k1);
            bv1 = *(const uint4*)(Bg + k1 + 8);
        }
        #pragma unroll
        for (int kk = 0; kk < 2; kk++) {       // MFMA on current buffer (hides load latency)
            bf16x8 a0 = *(const bf16x8*)&As[cur][wm * 32 + m16][kk * 32 + quad * 8];
            bf16x8 a1 = *(const bf16x8*)&As[cur][wm * 32 + 16 + m16][kk * 32 + quad * 8];
            bf16x8 b0 = *(const bf16x8*)&Bs[cur][wn * 32 + m16][kk * 32 + quad * 8];
            bf16x8 b1 = *(const bf16x8*)&Bs[cur][wn * 32 + 16 + m16][kk * 32 + quad * 8];
            acc[0][0] = MFMA16(a0, b0, acc[0][0]);
            acc[0][1] = MFMA16(a0, b1, acc[0][1]);
            acc[1][0] = MFMA16(a1, b0, acc[1][0]);
            acc[1][1] = MFMA16(a1, b1, acc[1][1]);
        }
        if (more) {                            // write next tile into the other buffer
            *(uint4*)&As[cur ^ 1][sr][sc]     = av0;
            *(uint4*)&As[cur ^ 1][sr][sc + 8] = av1;
            *(uint4*)&Bs[cur ^ 1][sr][sc]     = bv0;
            *(uint4*)&Bs[cur ^ 1][sr][sc + 8] = bv1;
            __syncthreads();                   // one barrier per k-step
            cur ^= 1;
        }
    }
}

// ---------------- generic bf16-weight GEMM, optional split-K over blockIdx.z ----------------
template<bool OUT_BF16, bool GELU, int SPLITK>
__global__ __launch_bounds__(256) void gemm_bt(
    const unsigned short* __restrict__ A, const unsigned short* __restrict__ Bt,
    const float* __restrict__ bias, void* __restrict__ Cp, int N, int K) {
    __shared__ unsigned short As[2][64][72], Bs[2][64][72];
    int row0 = blockIdx.y * 64, col0 = blockIdx.x * 64;
    int kseg = K / SPLITK;
    int kbeg = kseg * blockIdx.z, kend = kbeg + kseg;
    floatx4 acc[2][2];
    #pragma unroll
    for (int mi = 0; mi < 2; mi++)
        #pragma unroll
        for (int ni = 0; ni < 2; ni++) acc[mi][ni] = (floatx4){0.f, 0.f, 0.f, 0.f};
    gemm_tile_bt(A, Bt, row0, col0, K, kbeg, kend, acc, As, Bs);

    int tid = threadIdx.x, lane = tid & 63, wid = tid >> 6;
    int wm = wid >> 1, wn = wid & 1, m16 = lane & 15, quad = lane >> 4;
    size_t outoff = (size_t)blockIdx.z * (size_t)(gridDim.y << 6) * N;
    #pragma unroll
    for (int ni = 0; ni < 2; ni++) {
        int colg = col0 + wn * 32 + ni * 16 + m16;
        float bval = (SPLITK == 1 || blockIdx.z == 0) ? bias[colg] : 0.0f;
        #pragma unroll
        for (int mi = 0; mi < 2; mi++) {
            #pragma unroll
            for (int r = 0; r < 4; r++) {
                int rowg = row0 + wm * 32 + mi * 16 + quad * 4 + r;
                float v = acc[mi][ni][r] + bval;
                if (GELU) v = 0.5f * v * (1.0f + erff(v * 0.70710678118654752f));
                if (OUT_BF16) ((unsigned short*)Cp)[(size_t)rowg * N + colg] = f2b(v);
                else          ((float*)Cp)[outoff + (size_t)rowg * N + colg] = v;
            }
        }
    }
}

// ---------------- fused Q,K,V,Pk,Pq projections: 1024 workgroups, one launch ----------------
// XCD-aware decode: op is determined by (blockIdx.x & 7) so that each XCD's L2 holds
// one A matrix + one weight (Q,K,V -> XCD pairs {0,1},{2,3},{4,5}; Pk -> 6; Pq -> 7).
__global__ __launch_bounds__(256) void qkvp_gemm(
    const unsigned short* __restrict__ hb, const unsigned short* __restrict__ relb,
    const unsigned short* __restrict__ Wqt, const unsigned short* __restrict__ Wkt,
    const unsigned short* __restrict__ Wvt, const unsigned short* __restrict__ Wpkt,
    const unsigned short* __restrict__ Wpqt,
    const float* __restrict__ bq, const float* __restrict__ bk, const float* __restrict__ bv,
    const float* __restrict__ bpk, const float* __restrict__ bpq,
    unsigned short* __restrict__ qb, unsigned short* __restrict__ kb,
    unsigned short* __restrict__ vb, unsigned short* __restrict__ pkb,
    unsigned short* __restrict__ pqb) {
    __shared__ unsigned short As[2][64][72], Bs[2][64][72];
    int bid = blockIdx.x;
    int xcd = bid & 7, slot = bid >> 3;    // 128 slots per XCD
    int op, j;
    if (xcd < 6) { op = xcd >> 1; j = slot * 2 + (xcd & 1); }   // Q,K,V: j in [0,256)
    else         { op = xcd - 3;  j = slot; }                   // Pk,Pq: j in [0,128)
    int trow = j >> 3, tcol = j & 7;
    const unsigned short* A; const unsigned short* Bt; const float* bias; unsigned short* C;
    if (op < 3) {
        A = hb;
        Bt   = op == 0 ? Wqt : op == 1 ? Wkt : Wvt;
        bias = op == 0 ? bq  : op == 1 ? bk  : bv;
        C    = op == 0 ? qb  : op == 1 ? kb  : vb;
    } else {
        A = relb;
        Bt   = op == 3 ? Wpkt : Wpqt;
        bias = op == 3 ? bpk  : bpq;
        C    = op == 3 ? pkb  : pqb;
    }
    floatx4 acc[2][2];
    #pragma unroll
    for (int mi = 0; mi < 2; mi++)
        #pragma unroll
        for (int ni = 0; ni < 2; ni++) acc[mi][ni] = (floatx4){0.f, 0.f, 0.f, 0.f};
    gemm_tile_bt(A, Bt, trow * 64, tcol * 64, HID, 0, HID, acc, As, Bs);

    int tid = threadIdx.x, lane = tid & 63, wid = tid >> 6;
    int wm = wid >> 1, wn = wid & 1, m16 = lane & 15, quad = lane >> 4;
    #pragma unroll
    for (int ni = 0; ni < 2; ni++) {
        int colg = tcol * 64 + wn * 32 + ni * 16 + m16;
        float bval = bias[colg];
        #pragma unroll
        for (int mi = 0; mi < 2; mi++) {
            #pragma unroll
            for (int r = 0; r < 4; r++) {
                int rowg = trow * 64 + wm * 32 + mi * 16 + quad * 4 + r;
                C[(size_t)rowg * HID + colg] = f2b(acc[mi][ni][r] + bval);
            }
        }
    }
}

// ---------------- fallback MFMA GEMM: B fp32 inline-converted (baseline path) ----------------
template<bool OUT_BF16, bool GELU>
__global__ __launch_bounds__(256) void mfma_gemm(
    const unsigned short* __restrict__ A, const float* __restrict__ B,
    const float* __restrict__ bias, void* __restrict__ Cp, int N, int K) {
    __shared__ unsigned short As[64][72];   // [m][k]
    __shared__ unsigned short Bs[64][72];   // [n][k]
    int tid = threadIdx.x;
    int lane = tid & 63, wid = tid >> 6;
    int wm = wid >> 1, wn = wid & 1;
    int row0 = blockIdx.y * 64, col0 = blockIdx.x * 64;
    int m16 = lane & 15, quad = lane >> 4;

    int ar = tid >> 2, ac = (tid & 3) << 4;
    int bk = (tid >> 3) << 1, bn = (tid & 7) << 3;

    const unsigned short* Ag = A + (size_t)(row0 + ar) * K + ac;
    const float* Bg = B + (size_t)bk * N + col0 + bn;

    floatx4 acc[2][2];
    #pragma unroll
    for (int mi = 0; mi < 2; mi++)
        #pragma unroll
        for (int ni = 0; ni < 2; ni++) acc[mi][ni] = (floatx4){0.f, 0.f, 0.f, 0.f};

    for (int k0 = 0; k0 < K; k0 += 64) {
        uint4 av0 = *(const uint4*)(Ag + k0);
        uint4 av1 = *(const uint4*)(Ag + k0 + 8);
        const float* br0 = Bg + (size_t)k0 * N;
        const float* br1 = br0 + N;
        float4 b00 = *(const float4*)br0, b01 = *(const float4*)(br0 + 4);
        float4 b10 = *(const float4*)br1, b11 = *(const float4*)(br1 + 4);
        *(uint4*)&As[ar][ac] = av0;
        *(uint4*)&As[ar][ac + 8] = av1;
        float lo[8] = {b00.x, b00.y, b00.z, b00.w, b01.x, b01.y, b01.z, b01.w};
        float hi[8] = {b10.x, b10.y, b10.z, b10.w, b11.x, b11.y, b11.z, b11.w};
        #pragma unroll
        for (int i = 0; i < 8; i++) {
            unsigned int p = (unsigned int)f2b(lo[i]) | ((unsigned int)f2b(hi[i]) << 16);
            *(unsigned int*)&Bs[bn + i][bk] = p;
        }
        __syncthreads();
        #pragma unroll
        for (int kk = 0; kk < 2; kk++) {
            bf16x8 a0 = *(const bf16x8*)&As[wm * 32 + m16][kk * 32 + quad * 8];
            bf16x8 a1 = *(const bf16x8*)&As[wm * 32 + 16 + m16][kk * 32 + quad * 8];
            bf16x8 b0 = *(const bf16x8*)&Bs[wn * 32 + m16][kk * 32 + quad * 8];
            bf16x8 b1 = *(const bf16x8*)&Bs[wn * 32 + 16 + m16][kk * 32 + quad * 8];
            acc[0][0] = MFMA16(a0, b0, acc[0][0]);
            acc[0][1] = MFMA16(a0, b1, acc[0][1]);
            acc[1][0] = MFMA16(a1, b0, acc[1][0]);
            acc[1][1] = MFMA16(a1, b1, acc[1][1]);
        }
        __syncthreads();
    }
    #pragma unroll
    for (int ni = 0; ni < 2; ni++) {
        int colg = col0 + wn * 32 + ni * 16 + m16;
        float bv = bias[colg];
        #pragma unroll
        for (int mi = 0; mi < 2; mi++) {
            #pragma unroll
            for (int r = 0; r < 4; r++) {
                int rowg = row0 + wm * 32 + mi * 16 + quad * 4 + r;
                float v = acc[mi][ni][r] + bv;
                if (GELU) v = 0.5f * v * (1.0f + erff(v * 0.70710678118654752f));
                if (OUT_BF16) ((unsigned short*)Cp)[(size_t)rowg * N + colg] = f2b(v);
                else          ((float*)Cp)[(size_t)rowg * N + colg] = v;
            }
        }
    }
}

// ---------------- MFMA fused flash-style disentangled attention, v3 (proven 41 us) ----------------
// 4 waves = 2 q-strips (u) x 2 k-halves (s); XCD-aware flat grid (hh = bid&7) keeps the
// per-head working set L2-resident. Online softmax in registers; k-halves merged at end.
__global__ __launch_bounds__(256, 2) void attn_kernel(
    const unsigned short* __restrict__ Q, const unsigned short* __restrict__ K,
    const unsigned short* __restrict__ V,
    const unsigned short* __restrict__ PK, const unsigned short* __restrict__ PQ,
    const int* __restrict__ am, unsigned short* __restrict__ ctx) {
    __shared__ unsigned short Ks[2][32][72];   // [slot][key][d]
    __shared__ unsigned short Vt[2][64][40];   // [slot][d][key^swz]
    __shared__ float Afs[4][16][49];           // per-wave A band (c2p)
    __shared__ float Bfs[4][32][50];           // per-wave B band (p2c); aliased as mergeO at end
    __shared__ unsigned short Pls[4][16][40];  // per-wave P (bf16)
    __shared__ int mkk[2][32];
    __shared__ float mergeML[2][2][16];        // [strip][m|l][row]

    int bid = blockIdx.x;
    int hh = bid & 7;                  // head -> XCD (round-robin dispatch)
    int b  = (bid >> 3) & 3;
    int q0 = (bid >> 5) * 32;
    int tid = threadIdx.x;
    int lane = tid & 63, wave = tid >> 6;
    int u = wave >> 1;                 // q-strip
    int s = wave & 1;                  // k-parity
    int quad = lane >> 4, m16 = lane & 15;
    const float inv_scale = 0.07216878364870323f; // 1/sqrt(192)

    // Q fragments in registers (A-operand: row=m16, k=quad*8, 2 chains)
    const unsigned short* qg = Q + (size_t)(b * SEQ + q0 + u * 16 + m16) * HID + hh * HEAD;
    bf16x8 qf0 = *(const bf16x8*)(qg + quad * 8);
    bf16x8 qf1 = *(const bf16x8*)(qg + 32 + quad * 8);

    // staging indices
    int sr = tid >> 3;                 // 0..31 key row
    int sc = (tid & 7) * 8;            // d base
    int vkey = ((sc >> 3) & 3) << 3;   // Vt swizzle key (per-thread const)

    floatx4 accO[4];
    #pragma unroll
    for (int nt = 0; nt < 4; nt++) accO[nt] = (floatx4){0.f, 0.f, 0.f, 0.f};
    float mreg[4] = {NEG_BIG, NEG_BIG, NEG_BIG, NEG_BIG};
    float lreg[4] = {0.f, 0.f, 0.f, 0.f};

    for (int ph = 0; ph < 8; ph++) {
        int t = 2 * ph + s;
        int P0  = q0 - 32 * t + 481;   // pk window base (c2p), rows P0..P0+63 used
        int P20 = 32 * t - q0 + 481;   // pq window base (p2c)
        int Jb  = 16 - 16 * u;         // per-strip pq sub-window base

        // ---- issue PK/PQ operand fragment loads early (global, L2-hot) ----
        bf16x8 pkf[3][2], pqf[3][2];
        #pragma unroll
        for (int nt = 0; nt < 3; nt++) {
            int prow = P0 + 16 * u + nt * 16 + m16;              // <= 992, no clamp
            const unsigned short* pg = PK + (size_t)prow * HID + hh * HEAD + quad * 8;
            pkf[nt][0] = *(const bf16x8*)pg;
            pkf[nt][1] = *(const bf16x8*)(pg + 32);
            int prow2 = P20 + Jb + nt * 16 + m16;
            if (prow2 > 1023) prow2 = 1023;                      // pad row, never gathered
            const unsigned short* pg2 = PQ + (size_t)prow2 * HID + hh * HEAD + quad * 8;
            pqf[nt][0] = *(const bf16x8*)pg2;
            pqf[nt][1] = *(const bf16x8*)(pg2 + 32);
        }

        // ---- stage both parity tiles (K rows, V transposed+swizzled) ----
        #pragma unroll
        for (int sl = 0; sl < 2; sl++) {
            int k0 = ph * 64 + sl * 32;
            const unsigned short* kg = K + (size_t)(b * SEQ + k0 + sr) * HID + hh * HEAD + sc;
            *(uint4*)&Ks[sl][sr][sc] = *(const uint4*)kg;
            uint4 vv = *(const uint4*)(V + (size_t)(b * SEQ + k0 + sr) * HID + hh * HEAD + sc);
            unsigned short* vp = (unsigned short*)&vv;
            #pragma unroll
            for (int j = 0; j < 8; j++) Vt[sl][sc + j][sr ^ vkey] = vp[j];
        }
        if (tid < 64) mkk[tid >> 5][tid & 31] = am[b * SEQ + ph * 64 + tid];
        __syncthreads();

        // ---- S = Q @ K^T (16x32) ----
        floatx4 accS[2];
        accS[0] = (floatx4){0.f, 0.f, 0.f, 0.f};
        accS[1] = (floatx4){0.f, 0.f, 0.f, 0.f};
        #pragma unroll
        for (int n = 0; n < 2; n++) {
            bf16x8 kfa = *(const bf16x8*)&Ks[s][n * 16 + m16][quad * 8];
            bf16x8 kfb = *(const bf16x8*)&Ks[s][n * 16 + m16][32 + quad * 8];
            accS[n] = MFMA16(qf0, kfa, accS[n]);
            accS[n] = MFMA16(qf1, kfb, accS[n]);
        }

        // ---- A = Q @ PKwin^T (16x48), wave-local ----
        {
            floatx4 accA[3];
            #pragma unroll
            for (int nt = 0; nt < 3; nt++) {
                accA[nt] = (floatx4){0.f, 0.f, 0.f, 0.f};
                accA[nt] = MFMA16(qf0, pkf[nt][0], accA[nt]);
                accA[nt] = MFMA16(qf1, pkf[nt][1], accA[nt]);
            }
            #pragma unroll
            for (int nt = 0; nt < 3; nt++)
                #pragma unroll
                for (int r = 0; r < 4; r++)
                    Afs[wave][quad * 4 + r][nt * 16 + m16] = accA[nt][r];
        }

        // ---- B = K @ PQwin^T (32x48 at col offset Jb), wave-local ----
        {
            floatx4 accB[2][3];
            #pragma unroll
            for (int mt = 0; mt < 2; mt++) {
                bf16x8 afa = *(const bf16x8*)&Ks[s][mt * 16 + m16][quad * 8];
                bf16x8 afb = *(const bf16x8*)&Ks[s][mt * 16 + m16][32 + quad * 8];
                #pragma unroll
                for (int nt = 0; nt < 3; nt++) {
                    accB[mt][nt] = (floatx4){0.f, 0.f, 0.f, 0.f};
                    accB[mt][nt] = MFMA16(afa, pqf[nt][0], accB[mt][nt]);
                    accB[mt][nt] = MFMA16(afb, pqf[nt][1], accB[mt][nt]);
                }
            }
            #pragma unroll
            for (int mt = 0; mt < 2; mt++)
                #pragma unroll
                for (int nt = 0; nt < 3; nt++)
                    #pragma unroll
                    for (int r = 0; r < 4; r++)
                        Bfs[wave][mt * 16 + quad * 4 + r][nt * 16 + m16] = accB[mt][nt][r];
        }

        // ---- gather + combine + in-register online softmax ----
        float sv[2][4];
        float tmax[4] = {NEG_BIG, NEG_BIG, NEG_BIG, NEG_BIG};
        #pragma unroll
        for (int n = 0; n < 2; n++) {
            #pragma unroll
            for (int r = 0; r < 4; r++) {
                int qq = quad * 4 + r;
                int kc = n * 16 + m16;
                float av = Afs[wave][qq][qq - kc + 31];
                float bv = Bfs[wave][kc][kc - qq + 15];
                float x = (accS[n][r] + av + bv) * inv_scale;
                x = mkk[s][kc] ? x : NEG_BIG;
                sv[n][r] = x;
                tmax[r] = fmaxf(tmax[r], x);
            }
        }
        float alpha[4], psum[4];
        #pragma unroll
        for (int r = 0; r < 4; r++) {
            float tm = tmax[r];
            tm = fmaxf(tm, __shfl_xor(tm, 1));
            tm = fmaxf(tm, __shfl_xor(tm, 2));
            tm = fmaxf(tm, __shfl_xor(tm, 4));
            tm = fmaxf(tm, __shfl_xor(tm, 8));
            float mo = mreg[r];
            float mn = fmaxf(mo, tm);
            alpha[r] = __expf(mo - mn);
            mreg[r] = mn;
        }
        #pragma unroll
        for (int r = 0; r < 4; r++) psum[r] = 0.f;
        #pragma unroll
        for (int n = 0; n < 2; n++) {
            #pragma unroll
            for (int r = 0; r < 4; r++) {
                float p = (sv[n][r] > -1.5e38f) ? __expf(sv[n][r] - mreg[r]) : 0.0f;
                unsigned short pb = f2b(p);
                Pls[wave][quad * 4 + r][n * 16 + m16] = pb;
                psum[r] += b2f(pb);
            }
        }
        #pragma unroll
        for (int r = 0; r < 4; r++) {
            float ps = psum[r];
            ps += __shfl_xor(ps, 1);
            ps += __shfl_xor(ps, 2);
            ps += __shfl_xor(ps, 4);
            ps += __shfl_xor(ps, 8);
            lreg[r] = lreg[r] * alpha[r] + ps;
        }
        // ---- rescale O, then PV ----
        #pragma unroll
        for (int nt = 0; nt < 4; nt++)
            #pragma unroll
            for (int r = 0; r < 4; r++) accO[nt][r] *= alpha[r];
        {
            bf16x8 pf = *(const bf16x8*)&Pls[wave][m16][quad * 8];
            #pragma unroll
            for (int nt = 0; nt < 4; nt++) {
                int d = nt * 16 + m16;
                int kq = (quad ^ ((d >> 3) & 3)) * 8;
                bf16x8 vf = *(const bf16x8*)&Vt[s][d][kq];
                accO[nt] = MFMA16(pf, vf, accO[nt]);
            }
        }
        __syncthreads();   // tile fully consumed before next restage
    }

    // ---- merge the two k-halves per q-strip (flash split-k merge) ----
    __syncthreads();       // all Bfs gathers done -> safe to alias merge buffer
    float* mo = &Bfs[0][0][0];  // mergeO[u][row][col]: u*1056 + row*66 + col (2112 floats < 6400)
    if (s == 1) {
        #pragma unroll
        for (int nt = 0; nt < 4; nt++)
            #pragma unroll
            for (int r = 0; r < 4; r++)
                mo[u * 1056 + (quad * 4 + r) * 66 + nt * 16 + m16] = accO[nt][r];
        if (m16 == 0) {
            #pragma unroll
            for (int r = 0; r < 4; r++) {
                mergeML[u][0][quad * 4 + r] = mreg[r];
                mergeML[u][1][quad * 4 + r] = lreg[r];
            }
        }
    }
    __syncthreads();
    if (s == 0) {
        #pragma unroll
        for (int r = 0; r < 4; r++) {
            int row = quad * 4 + r;
            float m1 = mergeML[u][0][row], l1 = mergeML[u][1][row];
            float m0 = mreg[r], l0 = lreg[r];
            float mt = fmaxf(m0, m1);
            float a0 = __expf(m0 - mt), a1 = __expf(m1 - mt);
            float lt = l0 * a0 + l1 * a1;
            float inv = lt > 0.0f ? 1.0f / lt : 0.0f;
            inv *= (float)am[b * SEQ + q0 + u * 16 + row];
            #pragma unroll
            for (int nt = 0; nt < 4; nt++) {
                float o1 = mo[u * 1056 + row * 66 + nt * 16 + m16];
                float val = (accO[nt][r] * a0 + o1 * a1) * inv;
                ctx[(size_t)(b * SEQ + q0 + u * 16 + row) * HID + hh * HEAD + nt * 16 + m16] = f2b(val);
            }
        }
    }
}

// ---------------- output copy / classifier (fp32 out) ----------------
__global__ void copy_f_kernel(const float* __restrict__ in, float* __restrict__ out, int n) {
    int i = blockIdx.x * 256 + threadIdx.x;
    if (i < n) out[i] = in[i];
}
__global__ void cls_kernel(const float* __restrict__ h, const float* __restrict__ cls_w,
                           const float* __restrict__ cls_b, float* __restrict__ out) {
    int t = blockIdx.x, v = threadIdx.x;
    if (v < VOCAB) {
        const float* hr = h + (size_t)t * HID;
        const float* wr = cls_w + (size_t)v * HID;
        float acc = cls_b[v];
        for (int d = 0; d < HID; d++) acc += hr[d] * wr[d];
        out[t * VOCAB + v] = acc;
    }
}

extern "C" void kernel_launch(void* const* d_in, const int* in_sizes, int n_in,
                              void* d_out, int out_size, void* d_ws, size_t ws_size,
                              hipStream_t stream) {
    const int* x     = (const int*)d_in[0];
    const int* am    = (const int*)d_in[1];
    const float* word_emb = (const float*)d_in[2];
    const float* emb_g    = (const float*)d_in[3];
    const float* emb_b    = (const float*)d_in[4];
    const float* rel_emb  = (const float*)d_in[5];
    const float* Wq  = (const float*)d_in[6];  const float* bq  = (const float*)d_in[7];
    const float* Wk  = (const float*)d_in[8];  const float* bk  = (const float*)d_in[9];
    const float* Wv  = (const float*)d_in[10]; const float* bv  = (const float*)d_in[11];
    const float* Wpk = (const float*)d_in[12]; const float* bpk = (const float*)d_in[13];
    const float* Wpq = (const float*)d_in[14]; const float* bpq = (const float*)d_in[15];
    const float* Wo  = (const float*)d_in[16]; const float* bo  = (const float*)d_in[17];
    const float* ln1g = (const float*)d_in[18]; const float* ln1b = (const float*)d_in[19];
    const float* W1  = (const float*)d_in[20]; const float* b1  = (const float*)d_in[21];
    const float* W2  = (const float*)d_in[22]; const float* b2  = (const float*)d_in[23];
    const float* ln2g = (const float*)d_in[24]; const float* ln2b = (const float*)d_in[25];
    const float* cls_w = (const float*)d_in[26]; const float* cls_b = (const float*)d_in[27];

    char* wsb = (char*)d_ws;
    const size_t NEED_BIG = 107u << 20;   // 23 MB activations + 84 MB bf16 weights

    if (ws_size >= NEED_BIG) {
        // ---- big-workspace path: preconverted transposed bf16 weights ----
        float* h  = (float*)wsb;                                      // 4 MB
        float* t1 = (float*)(wsb + (4u << 20));                       // 4 MB (split-K part 0)
        float* t2 = (float*)(wsb + (8u << 20));                       // 4 MB (split-K part 1)
        unsigned short* qb   = (unsigned short*)(wsb + (12u << 20));  // 2 MB
        unsigned short* kb   = (unsigned short*)(wsb + (14u << 20));  // 2 MB
        unsigned short* vb   = (unsigned short*)(wsb + (16u << 20));  // 2 MB
        unsigned short* pkb  = (unsigned short*)(wsb + (18u << 20));  // 1 MB
        unsigned short* pqb  = (unsigned short*)(wsb + (19u << 20));  // 1 MB
        unsigned short* relb = (unsigned short*)(wsb + (20u << 20));  // 1 MB
        unsigned short* hb   = (unsigned short*)(wsb + (21u << 20));  // 2 MB
        unsigned short* ctx  = hb;   // alias: hb dead between attn and add_ln1
        unsigned short* ffb  = qb;   // alias: qb..pqb (8 MB) dead by FF1
        unsigned short* Wqt  = (unsigned short*)(wsb + (23u << 20));  // 6x6 MB: q,k,v,pk,pq,o
        unsigned short* W1t  = (unsigned short*)(wsb + (59u << 20));  // 24 MB
        unsigned short* W2t  = (unsigned short*)(wsb + (83u << 20));  // 24 MB

        const size_t M512 = (size_t)HID * HID;   // elements per 512x512 matrix

        tcvt6_kernel<<<dim3(16, 16, 72), dim3(32, 8), 0, stream>>>(Wq, Wk, Wv, Wpk, Wpq, Wo, Wqt);
        tcvt_kernel<<<dim3(64, 16, 12), dim3(32, 8), 0, stream>>>(W1, W1t, HID, FFDIM);
        tcvt_kernel<<<dim3(16, 64, 12), dim3(32, 8), 0, stream>>>(W2, W2t, FFDIM, HID);
        cvt_rel_kernel<<<dim3(SPAN2 * HID / 1024), dim3(256), 0, stream>>>(rel_emb, relb);
        embed_ln_kernel<<<dim3(TOK), dim3(256), 0, stream>>>(x, am, word_emb, emb_g, emb_b, h, hb);

        for (int l = 0; l < NLAYER; l++) {
            qkvp_gemm<<<dim3(1024), dim3(256), 0, stream>>>(
                hb, relb,
                Wqt + (size_t)(0 * NLAYER + l) * M512, Wqt + (size_t)(1 * NLAYER + l) * M512,
                Wqt + (size_t)(2 * NLAYER + l) * M512, Wqt + (size_t)(3 * NLAYER + l) * M512,
                Wqt + (size_t)(4 * NLAYER + l) * M512,
                bq + l * HID, bk + l * HID, bv + l * HID, bpk + l * HID, bpq + l * HID,
                qb, kb, vb, pkb, pqb);

            attn_kernel<<<dim3(512), dim3(256), 0, stream>>>(
                qb, kb, vb, pkb, pqb, am, ctx);

            gemm_bt<false, false, 2><<<dim3(HID / 64, TOK / 64, 2), dim3(256), 0, stream>>>(
                ctx, Wqt + (size_t)(5 * NLAYER + l) * M512, bo + l * HID, t1, HID, HID);
            add_ln2_kernel<<<dim3(TOK), dim3(256), 0, stream>>>(t1, t2, ln1g + l * HID, ln1b + l * HID, h, hb);

            gemm_bt<true, true, 1><<<dim3(FFDIM / 64, TOK / 64, 1), dim3(256), 0, stream>>>(
                hb, W1t + (size_t)l * HID * FFDIM, b1 + l * FFDIM, ffb, FFDIM, HID);
            gemm_bt<false, false, 2><<<dim3(HID / 64, TOK / 64, 2), dim3(256), 0, stream>>>(
                ffb, W2t + (size_t)l * HID * FFDIM, b2 + l * HID, t1, HID, FFDIM);
            add_ln2_kernel<<<dim3(TOK), dim3(256), 0, stream>>>(t1, t2, ln2g + l * HID, ln2b + l * HID, h, hb);
        }

        float* out_f = (float*)d_out;
        copy_f_kernel<<<dim3(TOK * HID / 256), dim3(256), 0, stream>>>(h, out_f, TOK * HID);
        cls_kernel<<<dim3(TOK), dim3(32), 0, stream>>>(h, cls_w, cls_b, out_f + TOK * HID);
        return;
    }

    // ---- fallback path: baseline 19 MB layout, inline fp32->bf16 weight conversion ----
    const size_t NEEDED = 19u << 20;
    if (ws_size < NEEDED) return;
    float* h  = (float*)wsb;                                     // 4 MB
    float* t1 = (float*)(wsb + (4u << 20));                      // 4 MB
    unsigned short* qb   = (unsigned short*)(wsb + (8u << 20));  // 2 MB
    unsigned short* kb   = qb  + (1u << 20);                     // 2 MB
    unsigned short* vb   = kb  + (1u << 20);                     // 2 MB
    unsigned short* pkb  = vb  + (1u << 20);                     // 1 MB
    unsigned short* pqb  = pkb + (1u << 19);                     // 1 MB
    unsigned short* relb = (unsigned short*)(wsb + (16u << 20)); // 1 MB
    unsigned short* hb   = (unsigned short*)(wsb + (17u << 20)); // 2 MB
    unsigned short* ctx  = hb;   // alias: hb dead between V-GEMM and add_ln1
    unsigned short* ffb  = qb;   // alias: q..pq dead by FF1

    cvt_rel_kernel<<<dim3(SPAN2 * HID / 1024), dim3(256), 0, stream>>>(rel_emb, relb);
    embed_ln_kernel<<<dim3(TOK), dim3(256), 0, stream>>>(x, am, word_emb, emb_g, emb_b, h, hb);

    for (int l = 0; l < NLAYER; l++) {
        const float* Wq_l = Wq + (size_t)l * HID * HID;
        const float* Wk_l = Wk + (size_t)l * HID * HID;
        const float* Wv_l = Wv + (size_t)l * HID * HID;
        const float* Wo_l = Wo + (size_t)l * HID * HID;
        const float* Wpk_l = Wpk + (size_t)l * HID * HID;
        const float* Wpq_l = Wpq + (size_t)l * HID * HID;
        const float* W1_l = W1 + (size_t)l * HID * FFDIM;
        const float* W2_l = W2 + (size_t)l * FFDIM * HID;

        mfma_gemm<true,  false><<<dim3(HID/64, TOK/64),   dim3(256), 0, stream>>>(hb,   Wq_l,  bq + l*HID,  qb,  HID, HID);
        mfma_gemm<true,  false><<<dim3(HID/64, TOK/64),   dim3(256), 0, stream>>>(hb,   Wk_l,  bk + l*HID,  kb,  HID, HID);
        mfma_gemm<true,  false><<<dim3(HID/64, TOK/64),   dim3(256), 0, stream>>>(hb,   Wv_l,  bv + l*HID,  vb,  HID, HID);
        mfma_gemm<true,  false><<<dim3(HID/64, SPAN2/64), dim3(256), 0, stream>>>(relb, Wpk_l, bpk + l*HID, pkb, HID, HID);
        mfma_gemm<true,  false><<<dim3(HID/64, SPAN2/64), dim3(256), 0, stream>>>(relb, Wpq_l, bpq + l*HID, pqb, HID, HID);

        attn_kernel<<<dim3(512), dim3(256), 0, stream>>>(qb, kb, vb, pkb, pqb, am, ctx);

        mfma_gemm<false, false><<<dim3(HID/64, TOK/64),   dim3(256), 0, stream>>>(ctx,  Wo_l,  bo + l*HID,  t1,  HID, HID);
        add_ln_kernel<<<dim3(TOK), dim3(256), 0, stream>>>(t1, ln1g + l*HID, ln1b + l*HID, h, hb);

        mfma_gemm<true,  true ><<<dim3(FFDIM/64, TOK/64), dim3(256), 0, stream>>>(hb,   W1_l,  b1 + l*FFDIM, ffb, FFDIM, HID);
        mfma_gemm<false, false><<<dim3(HID/64, TOK/64),   dim3(256), 0, stream>>>(ffb,  W2_l,  b2 + l*HID,  t1,  HID, FFDIM);
        add_ln_kernel<<<dim3(TOK), dim3(256), 0, stream>>>(t1, ln2g + l*HID, ln2b + l*HID, h, hb);
    }

    float* out_f = (float*)d_out;
    copy_f_kernel<<<dim3(TOK*HID/256), dim3(256), 0, stream>>>(h, out_f, TOK*HID);
    cls_kernel<<<dim3(TOK), dim3(32), 0, stream>>>(h, cls_w, cls_b, out_f + TOK*HID);
}

// Round 6
// 1424.223 us; speedup vs baseline: 1.0564x; 1.0046x over previous
//
#include <hip/hip_runtime.h>
#include <hip/hip_bf16.h>

// Model dims (fixed by the reference)
#define BATCH  4
#define SEQ    512
#define TOK    (BATCH*SEQ)     // 2048
#define HID    512
#define NHEAD  8
#define HEAD   64
#define FFDIM  2048
#define NLAYER 12
#define SPAN2  1024            // 2*SPAN
#define VOCAB  25
#define LNEPS  1e-7f
#define NEG_BIG -3.0e38f

typedef __attribute__((ext_vector_type(8))) short bf16x8;   // 8 bf16 = 4 VGPRs
typedef __attribute__((ext_vector_type(4))) float floatx4;

#define MFMA16(a, b, c) __builtin_amdgcn_mfma_f32_16x16x32_bf16((a), (b), (c), 0, 0, 0)

__device__ __forceinline__ float b2f(unsigned short u) {
    return __uint_as_float(((unsigned int)u) << 16);
}
__device__ __forceinline__ unsigned short f2b(float f) {
    __hip_bfloat16 h = __float2bfloat16(f);
    return *(unsigned short*)&h;
}

// ---------------- wave-per-token LayerNorm helpers (grid = TOK/4, block = 256) ----------------
__device__ __forceinline__ float wave_sum(float v) {
    #pragma unroll
    for (int o = 1; o < 64; o <<= 1) v += __shfl_xor(v, o);
    return v;
}

__device__ __forceinline__ void ln_finish(const float (&v)[8], const float* __restrict__ g,
                                          const float* __restrict__ bb, int lane, float maskf,
                                          size_t base, float* __restrict__ h,
                                          unsigned short* __restrict__ hb) {
    float sum = 0.f;
    #pragma unroll
    for (int j = 0; j < 8; j++) sum += v[j];
    float mean = wave_sum(sum) * (1.0f / HID);
    float d[8]; float var = 0.f;
    #pragma unroll
    for (int j = 0; j < 8; j++) { d[j] = v[j] - mean; var += d[j] * d[j]; }
    float rstd = rsqrtf(wave_sum(var) * (1.0f / HID) + LNEPS);
    const float* gp = g + lane * 8; const float* bp = bb + lane * 8;
    float4 g0 = *(const float4*)gp, g1 = *(const float4*)(gp + 4);
    float4 b0 = *(const float4*)bp, b1 = *(const float4*)(bp + 4);
    float gg[8] = {g0.x, g0.y, g0.z, g0.w, g1.x, g1.y, g1.z, g1.w};
    float bv[8] = {b0.x, b0.y, b0.z, b0.w, b1.x, b1.y, b1.z, b1.w};
    float o8[8];
    #pragma unroll
    for (int j = 0; j < 8; j++) o8[j] = (d[j] * rstd * gg[j] + bv[j]) * maskf;
    *(float4*)(h + base)     = make_float4(o8[0], o8[1], o8[2], o8[3]);
    *(float4*)(h + base + 4) = make_float4(o8[4], o8[5], o8[6], o8[7]);
    uint4 pb;
    pb.x = (unsigned int)f2b(o8[0]) | ((unsigned int)f2b(o8[1]) << 16);
    pb.y = (unsigned int)f2b(o8[2]) | ((unsigned int)f2b(o8[3]) << 16);
    pb.z = (unsigned int)f2b(o8[4]) | ((unsigned int)f2b(o8[5]) << 16);
    pb.w = (unsigned int)f2b(o8[6]) | ((unsigned int)f2b(o8[7]) << 16);
    *(uint4*)(hb + base) = pb;
}

// ---------------- embedding gather + LN + mask ----------------
__global__ void embed_ln_kernel(const int* __restrict__ x, const int* __restrict__ am,
                                const float* __restrict__ word_emb,
                                const float* __restrict__ g, const float* __restrict__ bb,
                                float* __restrict__ h, unsigned short* __restrict__ hb) {
    int wv = threadIdx.x >> 6, lane = threadIdx.x & 63;
    int t = blockIdx.x * 4 + wv;
    const float* we = word_emb + (size_t)x[t] * HID + lane * 8;
    float4 va = *(const float4*)we, vb2 = *(const float4*)(we + 4);
    float v[8] = {va.x, va.y, va.z, va.w, vb2.x, vb2.y, vb2.z, vb2.w};
    ln_finish(v, g, bb, lane, (float)am[t], (size_t)t * HID + lane * 8, h, hb);
}

// ---------------- residual add + LN, single tmp (fallback path) ----------------
__global__ void add_ln_kernel(const float* __restrict__ tmp,
                              const float* __restrict__ g, const float* __restrict__ bb,
                              float* __restrict__ h, unsigned short* __restrict__ hb) {
    int wv = threadIdx.x >> 6, lane = threadIdx.x & 63;
    int t = blockIdx.x * 4 + wv;
    size_t base = (size_t)t * HID + lane * 8;
    float4 ta = *(const float4*)(tmp + base), tb = *(const float4*)(tmp + base + 4);
    float4 ha = *(const float4*)(h + base),  hbb = *(const float4*)(h + base + 4);
    float v[8] = {ta.x + ha.x, ta.y + ha.y, ta.z + ha.z, ta.w + ha.w,
                  tb.x + hbb.x, tb.y + hbb.y, tb.z + hbb.z, tb.w + hbb.w};
    ln_finish(v, g, bb, lane, 1.0f, base, h, hb);
}

// ---------------- residual add + LN, two split-K partials ----------------
__global__ void add_ln2_kernel(const float* __restrict__ t1a, const float* __restrict__ t1b,
                               const float* __restrict__ g, const float* __restrict__ bb,
                               float* __restrict__ h, unsigned short* __restrict__ hb) {
    int wv = threadIdx.x >> 6, lane = threadIdx.x & 63;
    int t = blockIdx.x * 4 + wv;
    size_t base = (size_t)t * HID + lane * 8;
    float4 aa = *(const float4*)(t1a + base), ab = *(const float4*)(t1a + base + 4);
    float4 ba = *(const float4*)(t1b + base), bbv = *(const float4*)(t1b + base + 4);
    float4 ha = *(const float4*)(h + base),  hb2 = *(const float4*)(h + base + 4);
    float v[8] = {aa.x + ba.x + ha.x, aa.y + ba.y + ha.y, aa.z + ba.z + ha.z, aa.w + ba.w + ha.w,
                  ab.x + bbv.x + hb2.x, ab.y + bbv.y + hb2.y, ab.z + bbv.z + hb2.z, ab.w + bbv.w + hb2.w};
    ln_finish(v, g, bb, lane, 1.0f, base, h, hb);
}

// ---------------- fp32 -> bf16 convert (rel_emb, n multiple of 1024) ----------------
__global__ void cvt_rel_kernel(const float* __restrict__ in, unsigned short* __restrict__ out) {
    int i = (blockIdx.x * 256 + threadIdx.x) * 4;
    float4 v = *(const float4*)(in + i);
    out[i] = f2b(v.x); out[i+1] = f2b(v.y); out[i+2] = f2b(v.z); out[i+3] = f2b(v.w);
}

// ---------------- transpose+convert: W[K][N] fp32 -> Wt[N][K] bf16, blockIdx.z = layer ----------------
__global__ void tcvt_kernel(const float* __restrict__ in, unsigned short* __restrict__ out,
                            int K, int N) {
    __shared__ float tile[32][33];
    int l = blockIdx.z;
    const float* ip = in + (size_t)l * K * N;
    unsigned short* op = out + (size_t)l * K * N;
    int kb = blockIdx.y * 32, nb = blockIdx.x * 32;
    int tx = threadIdx.x, ty = threadIdx.y;   // block (32,8)
    #pragma unroll
    for (int i = 0; i < 32; i += 8) tile[ty + i][tx] = ip[(size_t)(kb + ty + i) * N + nb + tx];
    __syncthreads();
    #pragma unroll
    for (int i = 0; i < 32; i += 8) op[(size_t)(nb + ty + i) * K + kb + tx] = f2b(tile[tx][ty + i]);
}

// six [12][512][512] weight arrays in one launch; z = l*6 + w; out contiguous [w][l][512][512]
__global__ void tcvt6_kernel(const float* __restrict__ Wq, const float* __restrict__ Wk,
                             const float* __restrict__ Wv, const float* __restrict__ Wpk,
                             const float* __restrict__ Wpq, const float* __restrict__ Wo,
                             unsigned short* __restrict__ out) {
    __shared__ float tile[32][33];
    int z = blockIdx.z, l = z / 6, w = z - l * 6;
    const float* src = w == 0 ? Wq : w == 1 ? Wk : w == 2 ? Wv : w == 3 ? Wpk : w == 4 ? Wpq : Wo;
    const float* ip = src + (size_t)l * HID * HID;
    unsigned short* op = out + ((size_t)w * NLAYER + l) * HID * HID;
    int kb = blockIdx.y * 32, nb = blockIdx.x * 32;
    int tx = threadIdx.x, ty = threadIdx.y;
    #pragma unroll
    for (int i = 0; i < 32; i += 8) tile[ty + i][tx] = ip[(size_t)(kb + ty + i) * HID + nb + tx];
    __syncthreads();
    #pragma unroll
    for (int i = 0; i < 32; i += 8) op[(size_t)(nb + ty + i) * HID + kb + tx] = f2b(tile[tx][ty + i]);
}

// ---------------- 128x64 tile core: A[M][K] bf16 x Bt[N][K] bf16, double-buffered ----------------
// 4 waves (2x2): wave (wm,wn) owns 64x32 = 4x2 fragments of 16x16. BK=64.
// Per k-step per wave: 12 ds_read_b128, 16 MFMA (vs 8:8 for the old 64x64 tile).
__device__ __forceinline__ void gemm_core128(
    const unsigned short* __restrict__ A, const unsigned short* __restrict__ Bt,
    int row0, int col0, int K, int kbeg, int kend,
    floatx4 (&acc)[4][2], unsigned short (&As)[2][128][72], unsigned short (&Bs)[2][64][72]) {
    int tid = threadIdx.x;
    int lane = tid & 63, wid = tid >> 6;
    int wm = wid >> 1, wn = wid & 1;
    int m16 = lane & 15, quad = lane >> 4;
    int asr = tid >> 1, asc = (tid & 1) * 32;   // A staging: row, 32-col half
    int bsr = tid >> 2, bsc = (tid & 3) * 16;   // B staging: row, 16-col quarter
    const unsigned short* Ag = A + (size_t)(row0 + asr) * K + asc;
    const unsigned short* Bg = Bt + (size_t)(col0 + bsr) * K + bsc;

    uint4 a0 = *(const uint4*)(Ag + kbeg),      a1 = *(const uint4*)(Ag + kbeg + 8);
    uint4 a2 = *(const uint4*)(Ag + kbeg + 16), a3 = *(const uint4*)(Ag + kbeg + 24);
    uint4 b0 = *(const uint4*)(Bg + kbeg),      b1 = *(const uint4*)(Bg + kbeg + 8);
    *(uint4*)&As[0][asr][asc]      = a0;
    *(uint4*)&As[0][asr][asc + 8]  = a1;
    *(uint4*)&As[0][asr][asc + 16] = a2;
    *(uint4*)&As[0][asr][asc + 24] = a3;
    *(uint4*)&Bs[0][bsr][bsc]      = b0;
    *(uint4*)&Bs[0][bsr][bsc + 8]  = b1;
    __syncthreads();

    int cur = 0;
    for (int k0 = kbeg; k0 < kend; k0 += 64) {
        int k1 = k0 + 64;
        bool more = k1 < kend;                 // uniform across block
        if (more) {
            a0 = *(const uint4*)(Ag + k1);      a1 = *(const uint4*)(Ag + k1 + 8);
            a2 = *(const uint4*)(Ag + k1 + 16); a3 = *(const uint4*)(Ag + k1 + 24);
            b0 = *(const uint4*)(Bg + k1);      b1 = *(const uint4*)(Bg + k1 + 8);
        }
        #pragma unroll
        for (int kk = 0; kk < 2; kk++) {
            bf16x8 bf0 = *(const bf16x8*)&Bs[cur][wn * 32 + m16][kk * 32 + quad * 8];
            bf16x8 bf1 = *(const bf16x8*)&Bs[cur][wn * 32 + 16 + m16][kk * 32 + quad * 8];
            #pragma unroll
            for (int mi = 0; mi < 4; mi++) {
                bf16x8 af = *(const bf16x8*)&As[cur][wm * 64 + mi * 16 + m16][kk * 32 + quad * 8];
                acc[mi][0] = MFMA16(af, bf0, acc[mi][0]);
                acc[mi][1] = MFMA16(af, bf1, acc[mi][1]);
            }
        }
        if (more) {
            *(uint4*)&As[cur ^ 1][asr][asc]      = a0;
            *(uint4*)&As[cur ^ 1][asr][asc + 8]  = a1;
            *(uint4*)&As[cur ^ 1][asr][asc + 16] = a2;
            *(uint4*)&As[cur ^ 1][asr][asc + 24] = a3;
            *(uint4*)&Bs[cur ^ 1][bsr][bsc]      = b0;
            *(uint4*)&Bs[cur ^ 1][bsr][bsc + 8]  = b1;
            __syncthreads();
            cur ^= 1;
        }
    }
}

// ---------------- generic bf16-weight GEMM on the 128x64 core, optional split-K ----------------
template<bool OUT_BF16, bool GELU, int SPLITK>
__global__ __launch_bounds__(256, 2) void gemm_bt2(
    const unsigned short* __restrict__ A, const unsigned short* __restrict__ Bt,
    const float* __restrict__ bias, void* __restrict__ Cp, int N, int K) {
    __shared__ unsigned short As[2][128][72], Bs[2][64][72];
    int row0 = blockIdx.y * 128, col0 = blockIdx.x * 64;
    int kseg = K / SPLITK;
    int kbeg = kseg * blockIdx.z, kend = kbeg + kseg;
    floatx4 acc[4][2];
    #pragma unroll
    for (int mi = 0; mi < 4; mi++)
        #pragma unroll
        for (int ni = 0; ni < 2; ni++) acc[mi][ni] = (floatx4){0.f, 0.f, 0.f, 0.f};
    gemm_core128(A, Bt, row0, col0, K, kbeg, kend, acc, As, Bs);

    int tid = threadIdx.x, lane = tid & 63, wid = tid >> 6;
    int wm = wid >> 1, wn = wid & 1, m16 = lane & 15, quad = lane >> 4;
    size_t outoff = (size_t)blockIdx.z * (size_t)(gridDim.y << 7) * N;
    #pragma unroll
    for (int ni = 0; ni < 2; ni++) {
        int colg = col0 + wn * 32 + ni * 16 + m16;
        float bval = (SPLITK == 1 || blockIdx.z == 0) ? bias[colg] : 0.0f;
        #pragma unroll
        for (int mi = 0; mi < 4; mi++) {
            #pragma unroll
            for (int r = 0; r < 4; r++) {
                int rowg = row0 + wm * 64 + mi * 16 + quad * 4 + r;
                float v = acc[mi][ni][r] + bval;
                if (GELU) v = 0.5f * v * (1.0f + erff(v * 0.70710678118654752f));
                if (OUT_BF16) ((unsigned short*)Cp)[(size_t)rowg * N + colg] = f2b(v);
                else          ((float*)Cp)[outoff + (size_t)rowg * N + colg] = v;
            }
        }
    }
}

// ---------------- fused Q,K,V,Pk,Pq projections on the 128x64 core: 512 WGs ----------------
// XCD-aware decode: op = f(blockIdx.x & 7) so each XCD's L2 holds one A matrix + one weight.
__global__ __launch_bounds__(256, 2) void qkvp_gemm(
    const unsigned short* __restrict__ hb, const unsigned short* __restrict__ relb,
    const unsigned short* __restrict__ Wqt, const unsigned short* __restrict__ Wkt,
    const unsigned short* __restrict__ Wvt, const unsigned short* __restrict__ Wpkt,
    const unsigned short* __restrict__ Wpqt,
    const float* __restrict__ bq, const float* __restrict__ bk, const float* __restrict__ bv,
    const float* __restrict__ bpk, const float* __restrict__ bpq,
    unsigned short* __restrict__ qb, unsigned short* __restrict__ kb,
    unsigned short* __restrict__ vb, unsigned short* __restrict__ pkb,
    unsigned short* __restrict__ pqb) {
    __shared__ unsigned short As[2][128][72], Bs[2][64][72];
    int bid = blockIdx.x;
    int xcd = bid & 7, slot = bid >> 3;    // 64 slots per XCD
    int op, j;
    if (xcd < 6) { op = xcd >> 1; j = slot * 2 + (xcd & 1); }   // Q,K,V: j in [0,128)
    else         { op = xcd - 3;  j = slot; }                   // Pk,Pq: j in [0,64)
    int trow = j >> 3, tcol = j & 7;       // 128-row x 64-col tiles, 8 col-tiles
    const unsigned short* A; const unsigned short* Bt; const float* bias; unsigned short* C;
    if (op < 3) {
        A = hb;
        Bt   = op == 0 ? Wqt : op == 1 ? Wkt : Wvt;
        bias = op == 0 ? bq  : op == 1 ? bk  : bv;
        C    = op == 0 ? qb  : op == 1 ? kb  : vb;
    } else {
        A = relb;
        Bt   = op == 3 ? Wpkt : Wpqt;
        bias = op == 3 ? bpk  : bpq;
        C    = op == 3 ? pkb  : pqb;
    }
    floatx4 acc[4][2];
    #pragma unroll
    for (int mi = 0; mi < 4; mi++)
        #pragma unroll
        for (int ni = 0; ni < 2; ni++) acc[mi][ni] = (floatx4){0.f, 0.f, 0.f, 0.f};
    gemm_core128(A, Bt, trow * 128, tcol * 64, HID, 0, HID, acc, As, Bs);

    int tid = threadIdx.x, lane = tid & 63, wid = tid >> 6;
    int wm = wid >> 1, wn = wid & 1, m16 = lane & 15, quad = lane >> 4;
    #pragma unroll
    for (int ni = 0; ni < 2; ni++) {
        int colg = tcol * 64 + wn * 32 + ni * 16 + m16;
        float bval = bias[colg];
        #pragma unroll
        for (int mi = 0; mi < 4; mi++) {
            #pragma unroll
            for (int r = 0; r < 4; r++) {
                int rowg = trow * 128 + wm * 64 + mi * 16 + quad * 4 + r;
                C[(size_t)rowg * HID + colg] = f2b(acc[mi][ni][r] + bval);
            }
        }
    }
}

// ---------------- fallback MFMA GEMM: B fp32 inline-converted (baseline path) ----------------
template<bool OUT_BF16, bool GELU>
__global__ __launch_bounds__(256) void mfma_gemm(
    const unsigned short* __restrict__ A, const float* __restrict__ B,
    const float* __restrict__ bias, void* __restrict__ Cp, int N, int K) {
    __shared__ unsigned short As[64][72];   // [m][k]
    __shared__ unsigned short Bs[64][72];   // [n][k]
    int tid = threadIdx.x;
    int lane = tid & 63, wid = tid >> 6;
    int wm = wid >> 1, wn = wid & 1;
    int row0 = blockIdx.y * 64, col0 = blockIdx.x * 64;
    int m16 = lane & 15, quad = lane >> 4;

    int ar = tid >> 2, ac = (tid & 3) << 4;
    int bk = (tid >> 3) << 1, bn = (tid & 7) << 3;

    const unsigned short* Ag = A + (size_t)(row0 + ar) * K + ac;
    const float* Bg = B + (size_t)bk * N + col0 + bn;

    floatx4 acc[2][2];
    #pragma unroll
    for (int mi = 0; mi < 2; mi++)
        #pragma unroll
        for (int ni = 0; ni < 2; ni++) acc[mi][ni] = (floatx4){0.f, 0.f, 0.f, 0.f};

    for (int k0 = 0; k0 < K; k0 += 64) {
        uint4 av0 = *(const uint4*)(Ag + k0);
        uint4 av1 = *(const uint4*)(Ag + k0 + 8);
        const float* br0 = Bg + (size_t)k0 * N;
        const float* br1 = br0 + N;
        float4 b00 = *(const float4*)br0, b01 = *(const float4*)(br0 + 4);
        float4 b10 = *(const float4*)br1, b11 = *(const float4*)(br1 + 4);
        *(uint4*)&As[ar][ac] = av0;
        *(uint4*)&As[ar][ac + 8] = av1;
        float lo[8] = {b00.x, b00.y, b00.z, b00.w, b01.x, b01.y, b01.z, b01.w};
        float hi[8] = {b10.x, b10.y, b10.z, b10.w, b11.x, b11.y, b11.z, b11.w};
        #pragma unroll
        for (int i = 0; i < 8; i++) {
            unsigned int p = (unsigned int)f2b(lo[i]) | ((unsigned int)f2b(hi[i]) << 16);
            *(unsigned int*)&Bs[bn + i][bk] = p;
        }
        __syncthreads();
        #pragma unroll
        for (int kk = 0; kk < 2; kk++) {
            bf16x8 a0 = *(const bf16x8*)&As[wm * 32 + m16][kk * 32 + quad * 8];
            bf16x8 a1 = *(const bf16x8*)&As[wm * 32 + 16 + m16][kk * 32 + quad * 8];
            bf16x8 b0 = *(const bf16x8*)&Bs[wn * 32 + m16][kk * 32 + quad * 8];
            bf16x8 b1 = *(const bf16x8*)&Bs[wn * 32 + 16 + m16][kk * 32 + quad * 8];
            acc[0][0] = MFMA16(a0, b0, acc[0][0]);
            acc[0][1] = MFMA16(a0, b1, acc[0][1]);
            acc[1][0] = MFMA16(a1, b0, acc[1][0]);
            acc[1][1] = MFMA16(a1, b1, acc[1][1]);
        }
        __syncthreads();
    }
    #pragma unroll
    for (int ni = 0; ni < 2; ni++) {
        int colg = col0 + wn * 32 + ni * 16 + m16;
        float bv = bias[colg];
        #pragma unroll
        for (int mi = 0; mi < 2; mi++) {
            #pragma unroll
            for (int r = 0; r < 4; r++) {
                int rowg = row0 + wm * 32 + mi * 16 + quad * 4 + r;
                float v = acc[mi][ni][r] + bv;
                if (GELU) v = 0.5f * v * (1.0f + erff(v * 0.70710678118654752f));
                if (OUT_BF16) ((unsigned short*)Cp)[(size_t)rowg * N + colg] = f2b(v);
                else          ((float*)Cp)[(size_t)rowg * N + colg] = v;
            }
        }
    }
}

// ---------------- MFMA fused flash-style disentangled attention, v3 + PK/PQ prefetch ----------------
// Identical to the proven v3 (41 us) except the PK/PQ fragment loads for phase ph+1 are
// issued during phase ph into a second register set (unrolled A/B pair, static indexing).
__global__ __launch_bounds__(256, 2) void attn_kernel(
    const unsigned short* __restrict__ Q, const unsigned short* __restrict__ K,
    const unsigned short* __restrict__ V,
    const unsigned short* __restrict__ PK, const unsigned short* __restrict__ PQ,
    const int* __restrict__ am, unsigned short* __restrict__ ctx) {
    __shared__ unsigned short Ks[2][32][72];   // [slot][key][d]
    __shared__ unsigned short Vt[2][64][40];   // [slot][d][key^swz]
    __shared__ float Afs[4][16][49];           // per-wave A band (c2p)
    __shared__ float Bfs[4][32][50];           // per-wave B band (p2c); aliased as mergeO at end
    __shared__ unsigned short Pls[4][16][40];  // per-wave P (bf16)
    __shared__ int mkk[2][32];
    __shared__ float mergeML[2][2][16];        // [strip][m|l][row]

    int bid = blockIdx.x;
    int hh = bid & 7;                  // head -> XCD (round-robin dispatch)
    int b  = (bid >> 3) & 3;
    int q0 = (bid >> 5) * 32;
    int tid = threadIdx.x;
    int lane = tid & 63, wave = tid >> 6;
    int u = wave >> 1;                 // q-strip
    int s = wave & 1;                  // k-parity
    int quad = lane >> 4, m16 = lane & 15;
    const float inv_scale = 0.07216878364870323f; // 1/sqrt(192)

    // Q fragments in registers (A-operand: row=m16, k=quad*8, 2 chains)
    const unsigned short* qg = Q + (size_t)(b * SEQ + q0 + u * 16 + m16) * HID + hh * HEAD;
    bf16x8 qf0 = *(const bf16x8*)(qg + quad * 8);
    bf16x8 qf1 = *(const bf16x8*)(qg + 32 + quad * 8);

    // staging indices
    int sr = tid >> 3;                 // 0..31 key row
    int sc = (tid & 7) * 8;            // d base
    int vkey = ((sc >> 3) & 3) << 3;   // Vt swizzle key (per-thread const)

    floatx4 accO[4];
    #pragma unroll
    for (int nt = 0; nt < 4; nt++) accO[nt] = (floatx4){0.f, 0.f, 0.f, 0.f};
    float mreg[4] = {NEG_BIG, NEG_BIG, NEG_BIG, NEG_BIG};
    float lreg[4] = {0.f, 0.f, 0.f, 0.f};

    auto loadPQ = [&](int t, bf16x8 (&pkf)[3][2], bf16x8 (&pqf)[3][2]) {
        int P0  = q0 - 32 * t + 481;   // pk window base (c2p)
        int P20 = 32 * t - q0 + 481;   // pq window base (p2c)
        int Jb  = 16 - 16 * u;
        #pragma unroll
        for (int nt = 0; nt < 3; nt++) {
            int prow = P0 + 16 * u + nt * 16 + m16;              // <= 992, no clamp
            const unsigned short* pg = PK + (size_t)prow * HID + hh * HEAD + quad * 8;
            pkf[nt][0] = *(const bf16x8*)pg;
            pkf[nt][1] = *(const bf16x8*)(pg + 32);
            int prow2 = P20 + Jb + nt * 16 + m16;
            if (prow2 > 1023) prow2 = 1023;                      // pad row, never gathered
            const unsigned short* pg2 = PQ + (size_t)prow2 * HID + hh * HEAD + quad * 8;
            pqf[nt][0] = *(const bf16x8*)pg2;
            pqf[nt][1] = *(const bf16x8*)(pg2 + 32);
        }
    };

    auto stageKV = [&](int ph) {
        #pragma unroll
        for (int sl = 0; sl < 2; sl++) {
            int k0 = ph * 64 + sl * 32;
            const unsigned short* kg = K + (size_t)(b * SEQ + k0 + sr) * HID + hh * HEAD + sc;
            *(uint4*)&Ks[sl][sr][sc] = *(const uint4*)kg;
            uint4 vv = *(const uint4*)(V + (size_t)(b * SEQ + k0 + sr) * HID + hh * HEAD + sc);
            unsigned short* vp = (unsigned short*)&vv;
            #pragma unroll
            for (int j = 0; j < 8; j++) Vt[sl][sc + j][sr ^ vkey] = vp[j];
        }
        if (tid < 64) mkk[tid >> 5][tid & 31] = am[b * SEQ + ph * 64 + tid];
    };

    auto computePhase = [&](bf16x8 (&pkf)[3][2], bf16x8 (&pqf)[3][2]) {
        // ---- S = Q @ K^T (16x32) ----
        floatx4 accS[2];
        accS[0] = (floatx4){0.f, 0.f, 0.f, 0.f};
        accS[1] = (floatx4){0.f, 0.f, 0.f, 0.f};
        #pragma unroll
        for (int n = 0; n < 2; n++) {
            bf16x8 kfa = *(const bf16x8*)&Ks[s][n * 16 + m16][quad * 8];
            bf16x8 kfb = *(const bf16x8*)&Ks[s][n * 16 + m16][32 + quad * 8];
            accS[n] = MFMA16(qf0, kfa, accS[n]);
            accS[n] = MFMA16(qf1, kfb, accS[n]);
        }
        // ---- A = Q @ PKwin^T (16x48), wave-local ----
        {
            floatx4 accA[3];
            #pragma unroll
            for (int nt = 0; nt < 3; nt++) {
                accA[nt] = (floatx4){0.f, 0.f, 0.f, 0.f};
                accA[nt] = MFMA16(qf0, pkf[nt][0], accA[nt]);
                accA[nt] = MFMA16(qf1, pkf[nt][1], accA[nt]);
            }
            #pragma unroll
            for (int nt = 0; nt < 3; nt++)
                #pragma unroll
                for (int r = 0; r < 4; r++)
                    Afs[wave][quad * 4 + r][nt * 16 + m16] = accA[nt][r];
        }
        // ---- B = K @ PQwin^T (32x48), wave-local ----
        {
            floatx4 accB[2][3];
            #pragma unroll
            for (int mt = 0; mt < 2; mt++) {
                bf16x8 afa = *(const bf16x8*)&Ks[s][mt * 16 + m16][quad * 8];
                bf16x8 afb = *(const bf16x8*)&Ks[s][mt * 16 + m16][32 + quad * 8];
                #pragma unroll
                for (int nt = 0; nt < 3; nt++) {
                    accB[mt][nt] = (floatx4){0.f, 0.f, 0.f, 0.f};
                    accB[mt][nt] = MFMA16(afa, pqf[nt][0], accB[mt][nt]);
                    accB[mt][nt] = MFMA16(afb, pqf[nt][1], accB[mt][nt]);
                }
            }
            #pragma unroll
            for (int mt = 0; mt < 2; mt++)
                #pragma unroll
                for (int nt = 0; nt < 3; nt++)
                    #pragma unroll
                    for (int r = 0; r < 4; r++)
                        Bfs[wave][mt * 16 + quad * 4 + r][nt * 16 + m16] = accB[mt][nt][r];
        }
        // ---- gather + combine + in-register online softmax ----
        float sv[2][4];
        float tmax[4] = {NEG_BIG, NEG_BIG, NEG_BIG, NEG_BIG};
        #pragma unroll
        for (int n = 0; n < 2; n++) {
            #pragma unroll
            for (int r = 0; r < 4; r++) {
                int qq = quad * 4 + r;
                int kc = n * 16 + m16;
                float av = Afs[wave][qq][qq - kc + 31];
                float bv = Bfs[wave][kc][kc - qq + 15];
                float x = (accS[n][r] + av + bv) * inv_scale;
                x = mkk[s][kc] ? x : NEG_BIG;
                sv[n][r] = x;
                tmax[r] = fmaxf(tmax[r], x);
            }
        }
        float alpha[4], psum[4];
        #pragma unroll
        for (int r = 0; r < 4; r++) {
            float tm = tmax[r];
            tm = fmaxf(tm, __shfl_xor(tm, 1));
            tm = fmaxf(tm, __shfl_xor(tm, 2));
            tm = fmaxf(tm, __shfl_xor(tm, 4));
            tm = fmaxf(tm, __shfl_xor(tm, 8));
            float mo = mreg[r];
            float mn = fmaxf(mo, tm);
            alpha[r] = __expf(mo - mn);
            mreg[r] = mn;
        }
        #pragma unroll
        for (int r = 0; r < 4; r++) psum[r] = 0.f;
        #pragma unroll
        for (int n = 0; n < 2; n++) {
            #pragma unroll
            for (int r = 0; r < 4; r++) {
                float p = (sv[n][r] > -1.5e38f) ? __expf(sv[n][r] - mreg[r]) : 0.0f;
                unsigned short pb = f2b(p);
                Pls[wave][quad * 4 + r][n * 16 + m16] = pb;
                psum[r] += b2f(pb);
            }
        }
        #pragma unroll
        for (int r = 0; r < 4; r++) {
            float ps = psum[r];
            ps += __shfl_xor(ps, 1);
            ps += __shfl_xor(ps, 2);
            ps += __shfl_xor(ps, 4);
            ps += __shfl_xor(ps, 8);
            lreg[r] = lreg[r] * alpha[r] + ps;
        }
        // ---- rescale O, then PV ----
        #pragma unroll
        for (int nt = 0; nt < 4; nt++)
            #pragma unroll
            for (int r = 0; r < 4; r++) accO[nt][r] *= alpha[r];
        {
            bf16x8 pf = *(const bf16x8*)&Pls[wave][m16][quad * 8];
            #pragma unroll
            for (int nt = 0; nt < 4; nt++) {
                int d = nt * 16 + m16;
                int kq = (quad ^ ((d >> 3) & 3)) * 8;
                bf16x8 vf = *(const bf16x8*)&Vt[s][d][kq];
                accO[nt] = MFMA16(pf, vf, accO[nt]);
            }
        }
    };

    bf16x8 pkfA[3][2], pqfA[3][2], pkfB[3][2], pqfB[3][2];
    loadPQ(s, pkfA, pqfA);                        // ph=0 window
    #pragma unroll
    for (int pp = 0; pp < 4; pp++) {
        {   // even phase: uses A set, prefetches B set
            int ph = 2 * pp;
            __syncthreads();                      // prior PV/gather reads complete
            stageKV(ph);
            __syncthreads();
            if (ph < 7) loadPQ(2 * (ph + 1) + s, pkfB, pqfB);
            computePhase(pkfA, pqfA);
        }
        {   // odd phase: uses B set, prefetches A set
            int ph = 2 * pp + 1;
            __syncthreads();
            stageKV(ph);
            __syncthreads();
            if (ph < 7) loadPQ(2 * (ph + 1) + s, pkfA, pqfA);
            computePhase(pkfB, pqfB);
        }
    }

    // ---- merge the two k-halves per q-strip (flash split-k merge) ----
    __syncthreads();       // all Bfs gathers done -> safe to alias merge buffer
    float* mo = &Bfs[0][0][0];  // mergeO[u][row][col]: u*1056 + row*66 + col (2112 floats < 6400)
    if (s == 1) {
        #pragma unroll
        for (int nt = 0; nt < 4; nt++)
            #pragma unroll
            for (int r = 0; r < 4; r++)
                mo[u * 1056 + (quad * 4 + r) * 66 + nt * 16 + m16] = accO[nt][r];
        if (m16 == 0) {
            #pragma unroll
            for (int r = 0; r < 4; r++) {
                mergeML[u][0][quad * 4 + r] = mreg[r];
                mergeML[u][1][quad * 4 + r] = lreg[r];
            }
        }
    }
    __syncthreads();
    if (s == 0) {
        #pragma unroll
        for (int r = 0; r < 4; r++) {
            int row = quad * 4 + r;
            float m1 = mergeML[u][0][row], l1 = mergeML[u][1][row];
            float m0 = mreg[r], l0 = lreg[r];
            float mt = fmaxf(m0, m1);
            float a0 = __expf(m0 - mt), a1 = __expf(m1 - mt);
            float lt = l0 * a0 + l1 * a1;
            float inv = lt > 0.0f ? 1.0f / lt : 0.0f;
            inv *= (float)am[b * SEQ + q0 + u * 16 + row];
            #pragma unroll
            for (int nt = 0; nt < 4; nt++) {
                float o1 = mo[u * 1056 + row * 66 + nt * 16 + m16];
                float val = (accO[nt][r] * a0 + o1 * a1) * inv;
                ctx[(size_t)(b * SEQ + q0 + u * 16 + row) * HID + hh * HEAD + nt * 16 + m16] = f2b(val);
            }
        }
    }
}

// ---------------- output copy / classifier (fp32 out) ----------------
__global__ void copy_f_kernel(const float* __restrict__ in, float* __restrict__ out, int n) {
    int i = blockIdx.x * 256 + threadIdx.x;
    if (i < n) out[i] = in[i];
}
__global__ void cls_kernel(const float* __restrict__ h, const float* __restrict__ cls_w,
                           const float* __restrict__ cls_b, float* __restrict__ out) {
    int t = blockIdx.x, v = threadIdx.x;
    if (v < VOCAB) {
        const float* hr = h + (size_t)t * HID;
        const float* wr = cls_w + (size_t)v * HID;
        float acc = cls_b[v];
        for (int d = 0; d < HID; d++) acc += hr[d] * wr[d];
        out[t * VOCAB + v] = acc;
    }
}

extern "C" void kernel_launch(void* const* d_in, const int* in_sizes, int n_in,
                              void* d_out, int out_size, void* d_ws, size_t ws_size,
                              hipStream_t stream) {
    const int* x     = (const int*)d_in[0];
    const int* am    = (const int*)d_in[1];
    const float* word_emb = (const float*)d_in[2];
    const float* emb_g    = (const float*)d_in[3];
    const float* emb_b    = (const float*)d_in[4];
    const float* rel_emb  = (const float*)d_in[5];
    const float* Wq  = (const float*)d_in[6];  const float* bq  = (const float*)d_in[7];
    const float* Wk  = (const float*)d_in[8];  const float* bk  = (const float*)d_in[9];
    const float* Wv  = (const float*)d_in[10]; const float* bv  = (const float*)d_in[11];
    const float* Wpk = (const float*)d_in[12]; const float* bpk = (const float*)d_in[13];
    const float* Wpq = (const float*)d_in[14]; const float* bpq = (const float*)d_in[15];
    const float* Wo  = (const float*)d_in[16]; const float* bo  = (const float*)d_in[17];
    const float* ln1g = (const float*)d_in[18]; const float* ln1b = (const float*)d_in[19];
    const float* W1  = (const float*)d_in[20]; const float* b1  = (const float*)d_in[21];
    const float* W2  = (const float*)d_in[22]; const float* b2  = (const float*)d_in[23];
    const float* ln2g = (const float*)d_in[24]; const float* ln2b = (const float*)d_in[25];
    const float* cls_w = (const float*)d_in[26]; const float* cls_b = (const float*)d_in[27];

    char* wsb = (char*)d_ws;
    const size_t NEED_BIG = 107u << 20;   // 23 MB activations + 84 MB bf16 weights

    if (ws_size >= NEED_BIG) {
        // ---- big-workspace path: preconverted transposed bf16 weights ----
        float* h  = (float*)wsb;                                      // 4 MB
        float* t1 = (float*)(wsb + (4u << 20));                       // 4 MB (split-K part 0)
        float* t2 = (float*)(wsb + (8u << 20));                       // 4 MB (split-K part 1)
        unsigned short* qb   = (unsigned short*)(wsb + (12u << 20));  // 2 MB
        unsigned short* kb   = (unsigned short*)(wsb + (14u << 20));  // 2 MB
        unsigned short* vb   = (unsigned short*)(wsb + (16u << 20));  // 2 MB
        unsigned short* pkb  = (unsigned short*)(wsb + (18u << 20));  // 1 MB
        unsigned short* pqb  = (unsigned short*)(wsb + (19u << 20));  // 1 MB
        unsigned short* relb = (unsigned short*)(wsb + (20u << 20));  // 1 MB
        unsigned short* hb   = (unsigned short*)(wsb + (21u << 20));  // 2 MB
        unsigned short* ctx  = hb;   // alias: hb dead between attn and add_ln1
        unsigned short* ffb  = qb;   // alias: qb..pqb (8 MB) dead by FF1
        unsigned short* Wqt  = (unsigned short*)(wsb + (23u << 20));  // 6x6 MB: q,k,v,pk,pq,o
        unsigned short* W1t  = (unsigned short*)(wsb + (59u << 20));  // 24 MB
        unsigned short* W2t  = (unsigned short*)(wsb + (83u << 20));  // 24 MB

        const size_t M512 = (size_t)HID * HID;   // elements per 512x512 matrix

        tcvt6_kernel<<<dim3(16, 16, 72), dim3(32, 8), 0, stream>>>(Wq, Wk, Wv, Wpk, Wpq, Wo, Wqt);
        tcvt_kernel<<<dim3(64, 16, 12), dim3(32, 8), 0, stream>>>(W1, W1t, HID, FFDIM);
        tcvt_kernel<<<dim3(16, 64, 12), dim3(32, 8), 0, stream>>>(W2, W2t, FFDIM, HID);
        cvt_rel_kernel<<<dim3(SPAN2 * HID / 1024), dim3(256), 0, stream>>>(rel_emb, relb);
        embed_ln_kernel<<<dim3(TOK / 4), dim3(256), 0, stream>>>(x, am, word_emb, emb_g, emb_b, h, hb);

        for (int l = 0; l < NLAYER; l++) {
            qkvp_gemm<<<dim3(512), dim3(256), 0, stream>>>(
                hb, relb,
                Wqt + (size_t)(0 * NLAYER + l) * M512, Wqt + (size_t)(1 * NLAYER + l) * M512,
                Wqt + (size_t)(2 * NLAYER + l) * M512, Wqt + (size_t)(3 * NLAYER + l) * M512,
                Wqt + (size_t)(4 * NLAYER + l) * M512,
                bq + l * HID, bk + l * HID, bv + l * HID, bpk + l * HID, bpq + l * HID,
                qb, kb, vb, pkb, pqb);

            attn_kernel<<<dim3(512), dim3(256), 0, stream>>>(
                qb, kb, vb, pkb, pqb, am, ctx);

            gemm_bt2<false, false, 2><<<dim3(HID / 64, TOK / 128, 2), dim3(256), 0, stream>>>(
                ctx, Wqt + (size_t)(5 * NLAYER + l) * M512, bo + l * HID, t1, HID, HID);
            add_ln2_kernel<<<dim3(TOK / 4), dim3(256), 0, stream>>>(t1, t2, ln1g + l * HID, ln1b + l * HID, h, hb);

            gemm_bt2<true, true, 1><<<dim3(FFDIM / 64, TOK / 128, 1), dim3(256), 0, stream>>>(
                hb, W1t + (size_t)l * HID * FFDIM, b1 + l * FFDIM, ffb, FFDIM, HID);
            gemm_bt2<false, false, 2><<<dim3(HID / 64, TOK / 128, 2), dim3(256), 0, stream>>>(
                ffb, W2t + (size_t)l * HID * FFDIM, b2 + l * HID, t1, HID, FFDIM);
            add_ln2_kernel<<<dim3(TOK / 4), dim3(256), 0, stream>>>(t1, t2, ln2g + l * HID, ln2b + l * HID, h, hb);
        }

        float* out_f = (float*)d_out;
        copy_f_kernel<<<dim3(TOK * HID / 256), dim3(256), 0, stream>>>(h, out_f, TOK * HID);
        cls_kernel<<<dim3(TOK), dim3(32), 0, stream>>>(h, cls_w, cls_b, out_f + TOK * HID);
        return;
    }

    // ---- fallback path: baseline 19 MB layout, inline fp32->bf16 weight conversion ----
    const size_t NEEDED = 19u << 20;
    if (ws_size < NEEDED) return;
    float* h  = (float*)wsb;                                     // 4 MB
    float* t1 = (float*)(wsb + (4u << 20));                      // 4 MB
    unsigned short* qb   = (unsigned short*)(wsb + (8u << 20));  // 2 MB
    unsigned short* kb   = qb  + (1u << 20);                     // 2 MB
    unsigned short* vb   = kb  + (1u << 20);                     // 2 MB
    unsigned short* pkb  = vb  + (1u << 20);                     // 1 MB
    unsigned short* pqb  = pkb + (1u << 19);                     // 1 MB
    unsigned short* relb = (unsigned short*)(wsb + (16u << 20)); // 1 MB
    unsigned short* hb   = (unsigned short*)(wsb + (17u << 20)); // 2 MB
    unsigned short* ctx  = hb;   // alias: hb dead between V-GEMM and add_ln1
    unsigned short* ffb  = qb;   // alias: q..pq dead by FF1

    cvt_rel_kernel<<<dim3(SPAN2 * HID / 1024), dim3(256), 0, stream>>>(rel_emb, relb);
    embed_ln_kernel<<<dim3(TOK / 4), dim3(256), 0, stream>>>(x, am, word_emb, emb_g, emb_b, h, hb);

    for (int l = 0; l < NLAYER; l++) {
        const float* Wq_l = Wq + (size_t)l * HID * HID;
        const float* Wk_l = Wk + (size_t)l * HID * HID;
        const float* Wv_l = Wv + (size_t)l * HID * HID;
        const float* Wo_l = Wo + (size_t)l * HID * HID;
        const float* Wpk_l = Wpk + (size_t)l * HID * HID;
        const float* Wpq_l = Wpq + (size_t)l * HID * HID;
        const float* W1_l = W1 + (size_t)l * HID * FFDIM;
        const float* W2_l = W2 + (size_t)l * FFDIM * HID;

        mfma_gemm<true,  false><<<dim3(HID/64, TOK/64),   dim3(256), 0, stream>>>(hb,   Wq_l,  bq + l*HID,  qb,  HID, HID);
        mfma_gemm<true,  false><<<dim3(HID/64, TOK/64),   dim3(256), 0, stream>>>(hb,   Wk_l,  bk + l*HID,  kb,  HID, HID);
        mfma_gemm<true,  false><<<dim3(HID/64, TOK/64),   dim3(256), 0, stream>>>(hb,   Wv_l,  bv + l*HID,  vb,  HID, HID);
        mfma_gemm<true,  false><<<dim3(HID/64, SPAN2/64), dim3(256), 0, stream>>>(relb, Wpk_l, bpk + l*HID, pkb, HID, HID);
        mfma_gemm<true,  false><<<dim3(HID/64, SPAN2/64), dim3(256), 0, stream>>>(relb, Wpq_l, bpq + l*HID, pqb, HID, HID);

        attn_kernel<<<dim3(512), dim3(256), 0, stream>>>(qb, kb, vb, pkb, pqb, am, ctx);

        mfma_gemm<false, false><<<dim3(HID/64, TOK/64),   dim3(256), 0, stream>>>(ctx,  Wo_l,  bo + l*HID,  t1,  HID, HID);
        add_ln_kernel<<<dim3(TOK / 4), dim3(256), 0, stream>>>(t1, ln1g + l*HID, ln1b + l*HID, h, hb);

        mfma_gemm<true,  true ><<<dim3(FFDIM/64, TOK/64), dim3(256), 0, stream>>>(hb,   W1_l,  b1 + l*FFDIM, ffb, FFDIM, HID);
        mfma_gemm<false, false><<<dim3(HID/64, TOK/64),   dim3(256), 0, stream>>>(ffb,  W2_l,  b2 + l*HID,  t1,  HID, FFDIM);
        add_ln_kernel<<<dim3(TOK / 4), dim3(256), 0, stream>>>(t1, ln2g + l*HID, ln2b + l*HID, h, hb);
    }

    float* out_f = (float*)d_out;
    copy_f_kernel<<<dim3(TOK*HID/256), dim3(256), 0, stream>>>(h, out_f, TOK*HID);
    cls_kernel<<<dim3(TOK), dim3(32), 0, stream>>>(h, cls_w, cls_b, out_f + TOK*HID);
}

// Round 7
// 1423.941 us; speedup vs baseline: 1.0566x; 1.0002x over previous
//
#include <hip/hip_runtime.h>
#include <hip/hip_bf16.h>

// Model dims (fixed by the reference)
#define BATCH  4
#define SEQ    512
#define TOK    (BATCH*SEQ)     // 2048
#define HID    512
#define NHEAD  8
#define HEAD   64
#define FFDIM  2048
#define NLAYER 12
#define SPAN2  1024            // 2*SPAN
#define VOCAB  25
#define LNEPS  1e-7f
#define NEG_BIG -3.0e38f

typedef __attribute__((ext_vector_type(8))) short bf16x8;   // 8 bf16 = 4 VGPRs
typedef __attribute__((ext_vector_type(4))) float floatx4;

#define MFMA16(a, b, c) __builtin_amdgcn_mfma_f32_16x16x32_bf16((a), (b), (c), 0, 0, 0)

__device__ __forceinline__ float b2f(unsigned short u) {
    return __uint_as_float(((unsigned int)u) << 16);
}
__device__ __forceinline__ unsigned short f2b(float f) {
    __hip_bfloat16 h = __float2bfloat16(f);
    return *(unsigned short*)&h;
}

// async global->LDS, 16 bytes per lane: LDS dest = wave-uniform base + lane*16
__device__ __forceinline__ void gload16(const unsigned short* g, unsigned short* lds_base) {
    __builtin_amdgcn_global_load_lds((const __attribute__((address_space(1))) void*)g,
                                     (__attribute__((address_space(3))) void*)lds_base, 16, 0, 0);
}

// ---------------- wave-per-token LayerNorm helpers (grid = TOK/4, block = 256) ----------------
__device__ __forceinline__ float wave_sum(float v) {
    #pragma unroll
    for (int o = 1; o < 64; o <<= 1) v += __shfl_xor(v, o);
    return v;
}

__device__ __forceinline__ void ln_finish(const float (&v)[8], const float* __restrict__ g,
                                          const float* __restrict__ bb, int lane, float maskf,
                                          size_t base, float* __restrict__ h,
                                          unsigned short* __restrict__ hb) {
    float sum = 0.f;
    #pragma unroll
    for (int j = 0; j < 8; j++) sum += v[j];
    float mean = wave_sum(sum) * (1.0f / HID);
    float d[8]; float var = 0.f;
    #pragma unroll
    for (int j = 0; j < 8; j++) { d[j] = v[j] - mean; var += d[j] * d[j]; }
    float rstd = rsqrtf(wave_sum(var) * (1.0f / HID) + LNEPS);
    const float* gp = g + lane * 8; const float* bp = bb + lane * 8;
    float4 g0 = *(const float4*)gp, g1 = *(const float4*)(gp + 4);
    float4 b0 = *(const float4*)bp, b1 = *(const float4*)(bp + 4);
    float gg[8] = {g0.x, g0.y, g0.z, g0.w, g1.x, g1.y, g1.z, g1.w};
    float bv[8] = {b0.x, b0.y, b0.z, b0.w, b1.x, b1.y, b1.z, b1.w};
    float o8[8];
    #pragma unroll
    for (int j = 0; j < 8; j++) o8[j] = (d[j] * rstd * gg[j] + bv[j]) * maskf;
    *(float4*)(h + base)     = make_float4(o8[0], o8[1], o8[2], o8[3]);
    *(float4*)(h + base + 4) = make_float4(o8[4], o8[5], o8[6], o8[7]);
    uint4 pb;
    pb.x = (unsigned int)f2b(o8[0]) | ((unsigned int)f2b(o8[1]) << 16);
    pb.y = (unsigned int)f2b(o8[2]) | ((unsigned int)f2b(o8[3]) << 16);
    pb.z = (unsigned int)f2b(o8[4]) | ((unsigned int)f2b(o8[5]) << 16);
    pb.w = (unsigned int)f2b(o8[6]) | ((unsigned int)f2b(o8[7]) << 16);
    *(uint4*)(hb + base) = pb;
}

// ---------------- embedding gather + LN + mask ----------------
__global__ void embed_ln_kernel(const int* __restrict__ x, const int* __restrict__ am,
                                const float* __restrict__ word_emb,
                                const float* __restrict__ g, const float* __restrict__ bb,
                                float* __restrict__ h, unsigned short* __restrict__ hb) {
    int wv = threadIdx.x >> 6, lane = threadIdx.x & 63;
    int t = blockIdx.x * 4 + wv;
    const float* we = word_emb + (size_t)x[t] * HID + lane * 8;
    float4 va = *(const float4*)we, vb2 = *(const float4*)(we + 4);
    float v[8] = {va.x, va.y, va.z, va.w, vb2.x, vb2.y, vb2.z, vb2.w};
    ln_finish(v, g, bb, lane, (float)am[t], (size_t)t * HID + lane * 8, h, hb);
}

// ---------------- residual add + LN, single tmp (fallback path) ----------------
__global__ void add_ln_kernel(const float* __restrict__ tmp,
                              const float* __restrict__ g, const float* __restrict__ bb,
                              float* __restrict__ h, unsigned short* __restrict__ hb) {
    int wv = threadIdx.x >> 6, lane = threadIdx.x & 63;
    int t = blockIdx.x * 4 + wv;
    size_t base = (size_t)t * HID + lane * 8;
    float4 ta = *(const float4*)(tmp + base), tb = *(const float4*)(tmp + base + 4);
    float4 ha = *(const float4*)(h + base),  hbb = *(const float4*)(h + base + 4);
    float v[8] = {ta.x + ha.x, ta.y + ha.y, ta.z + ha.z, ta.w + ha.w,
                  tb.x + hbb.x, tb.y + hbb.y, tb.z + hbb.z, tb.w + hbb.w};
    ln_finish(v, g, bb, lane, 1.0f, base, h, hb);
}

// ---------------- residual add + LN, two split-K partials ----------------
__global__ void add_ln2_kernel(const float* __restrict__ t1a, const float* __restrict__ t1b,
                               const float* __restrict__ g, const float* __restrict__ bb,
                               float* __restrict__ h, unsigned short* __restrict__ hb) {
    int wv = threadIdx.x >> 6, lane = threadIdx.x & 63;
    int t = blockIdx.x * 4 + wv;
    size_t base = (size_t)t * HID + lane * 8;
    float4 aa = *(const float4*)(t1a + base), ab = *(const float4*)(t1a + base + 4);
    float4 ba = *(const float4*)(t1b + base), bbv = *(const float4*)(t1b + base + 4);
    float4 ha = *(const float4*)(h + base),  hb2 = *(const float4*)(h + base + 4);
    float v[8] = {aa.x + ba.x + ha.x, aa.y + ba.y + ha.y, aa.z + ba.z + ha.z, aa.w + ba.w + ha.w,
                  ab.x + bbv.x + hb2.x, ab.y + bbv.y + hb2.y, ab.z + bbv.z + hb2.z, ab.w + bbv.w + hb2.w};
    ln_finish(v, g, bb, lane, 1.0f, base, h, hb);
}

// ---------------- fp32 -> bf16 convert (rel_emb, n multiple of 1024) ----------------
__global__ void cvt_rel_kernel(const float* __restrict__ in, unsigned short* __restrict__ out) {
    int i = (blockIdx.x * 256 + threadIdx.x) * 4;
    float4 v = *(const float4*)(in + i);
    out[i] = f2b(v.x); out[i+1] = f2b(v.y); out[i+2] = f2b(v.z); out[i+3] = f2b(v.w);
}

// ---------------- transpose+convert: W[K][N] fp32 -> Wt[N][K] bf16, blockIdx.z = layer ----------------
__global__ void tcvt_kernel(const float* __restrict__ in, unsigned short* __restrict__ out,
                            int K, int N) {
    __shared__ float tile[32][33];
    int l = blockIdx.z;
    const float* ip = in + (size_t)l * K * N;
    unsigned short* op = out + (size_t)l * K * N;
    int kb = blockIdx.y * 32, nb = blockIdx.x * 32;
    int tx = threadIdx.x, ty = threadIdx.y;   // block (32,8)
    #pragma unroll
    for (int i = 0; i < 32; i += 8) tile[ty + i][tx] = ip[(size_t)(kb + ty + i) * N + nb + tx];
    __syncthreads();
    #pragma unroll
    for (int i = 0; i < 32; i += 8) op[(size_t)(nb + ty + i) * K + kb + tx] = f2b(tile[tx][ty + i]);
}

// six [12][512][512] weight arrays in one launch; z = l*6 + w; out contiguous [w][l][512][512]
__global__ void tcvt6_kernel(const float* __restrict__ Wq, const float* __restrict__ Wk,
                             const float* __restrict__ Wv, const float* __restrict__ Wpk,
                             const float* __restrict__ Wpq, const float* __restrict__ Wo,
                             unsigned short* __restrict__ out) {
    __shared__ float tile[32][33];
    int z = blockIdx.z, l = z / 6, w = z - l * 6;
    const float* src = w == 0 ? Wq : w == 1 ? Wk : w == 2 ? Wv : w == 3 ? Wpk : w == 4 ? Wpq : Wo;
    const float* ip = src + (size_t)l * HID * HID;
    unsigned short* op = out + ((size_t)w * NLAYER + l) * HID * HID;
    int kb = blockIdx.y * 32, nb = blockIdx.x * 32;
    int tx = threadIdx.x, ty = threadIdx.y;
    #pragma unroll
    for (int i = 0; i < 32; i += 8) tile[ty + i][tx] = ip[(size_t)(kb + ty + i) * HID + nb + tx];
    __syncthreads();
    #pragma unroll
    for (int i = 0; i < 32; i += 8) op[(size_t)(nb + ty + i) * HID + kb + tx] = f2b(tile[tx][ty + i]);
}

// ---------------- 128x64 tile core v2: global_load_lds + XOR-swizzled unpadded LDS ----------------
// LDS: As = [2][128][64] bf16 linear (16 KB/buf), Bs = [2][64][64] (8 KB/buf); total 48 KB.
// Swizzle s(byte) = byte ^ ((row&7)<<4), row = byte>>7 (involution, preserves 16B chunks).
// LDS content at addr a = logical element s(a): achieved by per-lane INVERSE-swizzled global
// source + linear gload_lds dest; fragment ds_reads use swizzled addresses -> conflict-free.
// One barrier per k-step: stage(next) -> MFMA(cur) -> __syncthreads (drains vmcnt) -> flip.
__device__ __forceinline__ void gemm_core128(
    const unsigned short* __restrict__ A, const unsigned short* __restrict__ Bt,
    int row0, int col0, int K, int kbeg, int kend,
    floatx4 (&acc)[4][2], unsigned short* AsB, unsigned short* BsB) {
    int tid = threadIdx.x;
    int lane = tid & 63, w = tid >> 6;
    int wm = w >> 1, wn = w & 1;
    int m16 = lane & 15, quad = lane >> 4;

    // per-lane logical (row, col-byte) for each staging chunk (A: 4 chunks, B: 2)
    int arow[4], acol[4], brow[2], bcol[2];
    #pragma unroll
    for (int c = 0; c < 4; c++) {
        int o = ((w * 4 + c) * 64 + lane) * 16;        // linear LDS byte dest
        int r = o >> 7;                                 // 128 B per row
        arow[c] = r;
        acol[c] = (o & 127) ^ ((r & 7) << 4);           // inverse-swizzled source column
    }
    #pragma unroll
    for (int c = 0; c < 2; c++) {
        int o = ((w * 2 + c) * 64 + lane) * 16;
        int r = o >> 7;
        brow[c] = r;
        bcol[c] = (o & 127) ^ ((r & 7) << 4);
    }

    auto stage = [&](int bf, int k0) {
        #pragma unroll
        for (int c = 0; c < 4; c++)
            gload16(A + (size_t)(row0 + arow[c]) * K + k0 + (acol[c] >> 1),
                    AsB + bf * 8192 + (w * 4 + c) * 512);
        #pragma unroll
        for (int c = 0; c < 2; c++)
            gload16(Bt + (size_t)(col0 + brow[c]) * K + k0 + (bcol[c] >> 1),
                    BsB + bf * 4096 + (w * 2 + c) * 512);
    };

    stage(0, kbeg);
    __syncthreads();                                   // vmcnt(0) drain + barrier
    int cur = 0;
    for (int k0 = kbeg; k0 < kend; k0 += 64) {
        if (k0 + 64 < kend) stage(cur ^ 1, k0 + 64);   // async loads into other buffer
        const char* Ab = (const char*)(AsB + cur * 8192);
        const char* Bb = (const char*)(BsB + cur * 4096);
        int br0 = wn * 32 + m16, br1 = wn * 32 + 16 + m16;
        #pragma unroll
        for (int kk = 0; kk < 2; kk++) {
            bf16x8 bf0 = *(const bf16x8*)(Bb + ((((br0 << 7) + kk * 64 + quad * 16)) ^ ((m16 & 7) << 4)));
            bf16x8 bf1 = *(const bf16x8*)(Bb + ((((br1 << 7) + kk * 64 + quad * 16)) ^ ((m16 & 7) << 4)));
            #pragma unroll
            for (int mi = 0; mi < 4; mi++) {
                int ar = wm * 64 + mi * 16 + m16;
                bf16x8 af = *(const bf16x8*)(Ab + ((((ar << 7) + kk * 64 + quad * 16)) ^ ((m16 & 7) << 4)));
                acc[mi][0] = MFMA16(af, bf0, acc[mi][0]);
                acc[mi][1] = MFMA16(af, bf1, acc[mi][1]);
            }
        }
        __syncthreads();                               // drains next-tile loads + syncs reads
        cur ^= 1;
    }
}

// ---------------- generic bf16-weight GEMM on the 128x64 core, optional split-K ----------------
template<bool OUT_BF16, bool GELU, int SPLITK>
__global__ __launch_bounds__(256, 2) void gemm_bt2(
    const unsigned short* __restrict__ A, const unsigned short* __restrict__ Bt,
    const float* __restrict__ bias, void* __restrict__ Cp, int N, int K) {
    __shared__ unsigned short As[2][8192], Bs[2][4096];
    int row0 = blockIdx.y * 128, col0 = blockIdx.x * 64;
    int kseg = K / SPLITK;
    int kbeg = kseg * blockIdx.z, kend = kbeg + kseg;
    floatx4 acc[4][2];
    #pragma unroll
    for (int mi = 0; mi < 4; mi++)
        #pragma unroll
        for (int ni = 0; ni < 2; ni++) acc[mi][ni] = (floatx4){0.f, 0.f, 0.f, 0.f};
    gemm_core128(A, Bt, row0, col0, K, kbeg, kend, acc, &As[0][0], &Bs[0][0]);

    int tid = threadIdx.x, lane = tid & 63, wid = tid >> 6;
    int wm = wid >> 1, wn = wid & 1, m16 = lane & 15, quad = lane >> 4;
    size_t outoff = (size_t)blockIdx.z * (size_t)(gridDim.y << 7) * N;
    #pragma unroll
    for (int ni = 0; ni < 2; ni++) {
        int colg = col0 + wn * 32 + ni * 16 + m16;
        float bval = (SPLITK == 1 || blockIdx.z == 0) ? bias[colg] : 0.0f;
        #pragma unroll
        for (int mi = 0; mi < 4; mi++) {
            #pragma unroll
            for (int r = 0; r < 4; r++) {
                int rowg = row0 + wm * 64 + mi * 16 + quad * 4 + r;
                float v = acc[mi][ni][r] + bval;
                if (GELU) v = 0.5f * v * (1.0f + erff(v * 0.70710678118654752f));
                if (OUT_BF16) ((unsigned short*)Cp)[(size_t)rowg * N + colg] = f2b(v);
                else          ((float*)Cp)[outoff + (size_t)rowg * N + colg] = v;
            }
        }
    }
}

// ---------------- fused Q,K,V,Pk,Pq projections on the 128x64 core: 512 WGs ----------------
// XCD-aware decode: op = f(blockIdx.x & 7) so each XCD's L2 holds one A matrix + one weight.
__global__ __launch_bounds__(256, 2) void qkvp_gemm(
    const unsigned short* __restrict__ hb, const unsigned short* __restrict__ relb,
    const unsigned short* __restrict__ Wqt, const unsigned short* __restrict__ Wkt,
    const unsigned short* __restrict__ Wvt, const unsigned short* __restrict__ Wpkt,
    const unsigned short* __restrict__ Wpqt,
    const float* __restrict__ bq, const float* __restrict__ bk, const float* __restrict__ bv,
    const float* __restrict__ bpk, const float* __restrict__ bpq,
    unsigned short* __restrict__ qb, unsigned short* __restrict__ kb,
    unsigned short* __restrict__ vb, unsigned short* __restrict__ pkb,
    unsigned short* __restrict__ pqb) {
    __shared__ unsigned short As[2][8192], Bs[2][4096];
    int bid = blockIdx.x;
    int xcd = bid & 7, slot = bid >> 3;    // 64 slots per XCD
    int op, j;
    if (xcd < 6) { op = xcd >> 1; j = slot * 2 + (xcd & 1); }   // Q,K,V: j in [0,128)
    else         { op = xcd - 3;  j = slot; }                   // Pk,Pq: j in [0,64)
    int trow = j >> 3, tcol = j & 7;       // 128-row x 64-col tiles, 8 col-tiles
    const unsigned short* A; const unsigned short* Bt; const float* bias; unsigned short* C;
    if (op < 3) {
        A = hb;
        Bt   = op == 0 ? Wqt : op == 1 ? Wkt : Wvt;
        bias = op == 0 ? bq  : op == 1 ? bk  : bv;
        C    = op == 0 ? qb  : op == 1 ? kb  : vb;
    } else {
        A = relb;
        Bt   = op == 3 ? Wpkt : Wpqt;
        bias = op == 3 ? bpk  : bpq;
        C    = op == 3 ? pkb  : pqb;
    }
    floatx4 acc[4][2];
    #pragma unroll
    for (int mi = 0; mi < 4; mi++)
        #pragma unroll
        for (int ni = 0; ni < 2; ni++) acc[mi][ni] = (floatx4){0.f, 0.f, 0.f, 0.f};
    gemm_core128(A, Bt, trow * 128, tcol * 64, HID, 0, HID, acc, &As[0][0], &Bs[0][0]);

    int tid = threadIdx.x, lane = tid & 63, wid = tid >> 6;
    int wm = wid >> 1, wn = wid & 1, m16 = lane & 15, quad = lane >> 4;
    #pragma unroll
    for (int ni = 0; ni < 2; ni++) {
        int colg = tcol * 64 + wn * 32 + ni * 16 + m16;
        float bval = bias[colg];
        #pragma unroll
        for (int mi = 0; mi < 4; mi++) {
            #pragma unroll
            for (int r = 0; r < 4; r++) {
                int rowg = trow * 128 + wm * 64 + mi * 16 + quad * 4 + r;
                C[(size_t)rowg * HID + colg] = f2b(acc[mi][ni][r] + bval);
            }
        }
    }
}

// ---------------- fallback MFMA GEMM: B fp32 inline-converted (baseline path) ----------------
template<bool OUT_BF16, bool GELU>
__global__ __launch_bounds__(256) void mfma_gemm(
    const unsigned short* __restrict__ A, const float* __restrict__ B,
    const float* __restrict__ bias, void* __restrict__ Cp, int N, int K) {
    __shared__ unsigned short As[64][72];   // [m][k]
    __shared__ unsigned short Bs[64][72];   // [n][k]
    int tid = threadIdx.x;
    int lane = tid & 63, wid = tid >> 6;
    int wm = wid >> 1, wn = wid & 1;
    int row0 = blockIdx.y * 64, col0 = blockIdx.x * 64;
    int m16 = lane & 15, quad = lane >> 4;

    int ar = tid >> 2, ac = (tid & 3) << 4;
    int bk = (tid >> 3) << 1, bn = (tid & 7) << 3;

    const unsigned short* Ag = A + (size_t)(row0 + ar) * K + ac;
    const float* Bg = B + (size_t)bk * N + col0 + bn;

    floatx4 acc[2][2];
    #pragma unroll
    for (int mi = 0; mi < 2; mi++)
        #pragma unroll
        for (int ni = 0; ni < 2; ni++) acc[mi][ni] = (floatx4){0.f, 0.f, 0.f, 0.f};

    for (int k0 = 0; k0 < K; k0 += 64) {
        uint4 av0 = *(const uint4*)(Ag + k0);
        uint4 av1 = *(const uint4*)(Ag + k0 + 8);
        const float* br0 = Bg + (size_t)k0 * N;
        const float* br1 = br0 + N;
        float4 b00 = *(const float4*)br0, b01 = *(const float4*)(br0 + 4);
        float4 b10 = *(const float4*)br1, b11 = *(const float4*)(br1 + 4);
        *(uint4*)&As[ar][ac] = av0;
        *(uint4*)&As[ar][ac + 8] = av1;
        float lo[8] = {b00.x, b00.y, b00.z, b00.w, b01.x, b01.y, b01.z, b01.w};
        float hi[8] = {b10.x, b10.y, b10.z, b10.w, b11.x, b11.y, b11.z, b11.w};
        #pragma unroll
        for (int i = 0; i < 8; i++) {
            unsigned int p = (unsigned int)f2b(lo[i]) | ((unsigned int)f2b(hi[i]) << 16);
            *(unsigned int*)&Bs[bn + i][bk] = p;
        }
        __syncthreads();
        #pragma unroll
        for (int kk = 0; kk < 2; kk++) {
            bf16x8 a0 = *(const bf16x8*)&As[wm * 32 + m16][kk * 32 + quad * 8];
            bf16x8 a1 = *(const bf16x8*)&As[wm * 32 + 16 + m16][kk * 32 + quad * 8];
            bf16x8 b0 = *(const bf16x8*)&Bs[wn * 32 + m16][kk * 32 + quad * 8];
            bf16x8 b1 = *(const bf16x8*)&Bs[wn * 32 + 16 + m16][kk * 32 + quad * 8];
            acc[0][0] = MFMA16(a0, b0, acc[0][0]);
            acc[0][1] = MFMA16(a0, b1, acc[0][1]);
            acc[1][0] = MFMA16(a1, b0, acc[1][0]);
            acc[1][1] = MFMA16(a1, b1, acc[1][1]);
        }
        __syncthreads();
    }
    #pragma unroll
    for (int ni = 0; ni < 2; ni++) {
        int colg = col0 + wn * 32 + ni * 16 + m16;
        float bv = bias[colg];
        #pragma unroll
        for (int mi = 0; mi < 2; mi++) {
            #pragma unroll
            for (int r = 0; r < 4; r++) {
                int rowg = row0 + wm * 32 + mi * 16 + quad * 4 + r;
                float v = acc[mi][ni][r] + bv;
                if (GELU) v = 0.5f * v * (1.0f + erff(v * 0.70710678118654752f));
                if (OUT_BF16) ((unsigned short*)Cp)[(size_t)rowg * N + colg] = f2b(v);
                else          ((float*)Cp)[(size_t)rowg * N + colg] = v;
            }
        }
    }
}

// ---------------- MFMA fused flash-style disentangled attention, v3 + PK/PQ prefetch ----------------
// Identical to the proven v3 (41 us) except the PK/PQ fragment loads for phase ph+1 are
// issued during phase ph into a second register set (unrolled A/B pair, static indexing).
__global__ __launch_bounds__(256, 2) void attn_kernel(
    const unsigned short* __restrict__ Q, const unsigned short* __restrict__ K,
    const unsigned short* __restrict__ V,
    const unsigned short* __restrict__ PK, const unsigned short* __restrict__ PQ,
    const int* __restrict__ am, unsigned short* __restrict__ ctx) {
    __shared__ unsigned short Ks[2][32][72];   // [slot][key][d]
    __shared__ unsigned short Vt[2][64][40];   // [slot][d][key^swz]
    __shared__ float Afs[4][16][49];           // per-wave A band (c2p)
    __shared__ float Bfs[4][32][50];           // per-wave B band (p2c); aliased as mergeO at end
    __shared__ unsigned short Pls[4][16][40];  // per-wave P (bf16)
    __shared__ int mkk[2][32];
    __shared__ float mergeML[2][2][16];        // [strip][m|l][row]

    int bid = blockIdx.x;
    int hh = bid & 7;                  // head -> XCD (round-robin dispatch)
    int b  = (bid >> 3) & 3;
    int q0 = (bid >> 5) * 32;
    int tid = threadIdx.x;
    int lane = tid & 63, wave = tid >> 6;
    int u = wave >> 1;                 // q-strip
    int s = wave & 1;                  // k-parity
    int quad = lane >> 4, m16 = lane & 15;
    const float inv_scale = 0.07216878364870323f; // 1/sqrt(192)

    // Q fragments in registers (A-operand: row=m16, k=quad*8, 2 chains)
    const unsigned short* qg = Q + (size_t)(b * SEQ + q0 + u * 16 + m16) * HID + hh * HEAD;
    bf16x8 qf0 = *(const bf16x8*)(qg + quad * 8);
    bf16x8 qf1 = *(const bf16x8*)(qg + 32 + quad * 8);

    // staging indices
    int sr = tid >> 3;                 // 0..31 key row
    int sc = (tid & 7) * 8;            // d base
    int vkey = ((sc >> 3) & 3) << 3;   // Vt swizzle key (per-thread const)

    floatx4 accO[4];
    #pragma unroll
    for (int nt = 0; nt < 4; nt++) accO[nt] = (floatx4){0.f, 0.f, 0.f, 0.f};
    float mreg[4] = {NEG_BIG, NEG_BIG, NEG_BIG, NEG_BIG};
    float lreg[4] = {0.f, 0.f, 0.f, 0.f};

    auto loadPQ = [&](int t, bf16x8 (&pkf)[3][2], bf16x8 (&pqf)[3][2]) {
        int P0  = q0 - 32 * t + 481;   // pk window base (c2p)
        int P20 = 32 * t - q0 + 481;   // pq window base (p2c)
        int Jb  = 16 - 16 * u;
        #pragma unroll
        for (int nt = 0; nt < 3; nt++) {
            int prow = P0 + 16 * u + nt * 16 + m16;              // <= 992, no clamp
            const unsigned short* pg = PK + (size_t)prow * HID + hh * HEAD + quad * 8;
            pkf[nt][0] = *(const bf16x8*)pg;
            pkf[nt][1] = *(const bf16x8*)(pg + 32);
            int prow2 = P20 + Jb + nt * 16 + m16;
            if (prow2 > 1023) prow2 = 1023;                      // pad row, never gathered
            const unsigned short* pg2 = PQ + (size_t)prow2 * HID + hh * HEAD + quad * 8;
            pqf[nt][0] = *(const bf16x8*)pg2;
            pqf[nt][1] = *(const bf16x8*)(pg2 + 32);
        }
    };

    auto stageKV = [&](int ph) {
        #pragma unroll
        for (int sl = 0; sl < 2; sl++) {
            int k0 = ph * 64 + sl * 32;
            const unsigned short* kg = K + (size_t)(b * SEQ + k0 + sr) * HID + hh * HEAD + sc;
            *(uint4*)&Ks[sl][sr][sc] = *(const uint4*)kg;
            uint4 vv = *(const uint4*)(V + (size_t)(b * SEQ + k0 + sr) * HID + hh * HEAD + sc);
            unsigned short* vp = (unsigned short*)&vv;
            #pragma unroll
            for (int j = 0; j < 8; j++) Vt[sl][sc + j][sr ^ vkey] = vp[j];
        }
        if (tid < 64) mkk[tid >> 5][tid & 31] = am[b * SEQ + ph * 64 + tid];
    };

    auto computePhase = [&](bf16x8 (&pkf)[3][2], bf16x8 (&pqf)[3][2]) {
        // ---- S = Q @ K^T (16x32) ----
        floatx4 accS[2];
        accS[0] = (floatx4){0.f, 0.f, 0.f, 0.f};
        accS[1] = (floatx4){0.f, 0.f, 0.f, 0.f};
        #pragma unroll
        for (int n = 0; n < 2; n++) {
            bf16x8 kfa = *(const bf16x8*)&Ks[s][n * 16 + m16][quad * 8];
            bf16x8 kfb = *(const bf16x8*)&Ks[s][n * 16 + m16][32 + quad * 8];
            accS[n] = MFMA16(qf0, kfa, accS[n]);
            accS[n] = MFMA16(qf1, kfb, accS[n]);
        }
        // ---- A = Q @ PKwin^T (16x48), wave-local ----
        {
            floatx4 accA[3];
            #pragma unroll
            for (int nt = 0; nt < 3; nt++) {
                accA[nt] = (floatx4){0.f, 0.f, 0.f, 0.f};
                accA[nt] = MFMA16(qf0, pkf[nt][0], accA[nt]);
                accA[nt] = MFMA16(qf1, pkf[nt][1], accA[nt]);
            }
            #pragma unroll
            for (int nt = 0; nt < 3; nt++)
                #pragma unroll
                for (int r = 0; r < 4; r++)
                    Afs[wave][quad * 4 + r][nt * 16 + m16] = accA[nt][r];
        }
        // ---- B = K @ PQwin^T (32x48), wave-local ----
        {
            floatx4 accB[2][3];
            #pragma unroll
            for (int mt = 0; mt < 2; mt++) {
                bf16x8 afa = *(const bf16x8*)&Ks[s][mt * 16 + m16][quad * 8];
                bf16x8 afb = *(const bf16x8*)&Ks[s][mt * 16 + m16][32 + quad * 8];
                #pragma unroll
                for (int nt = 0; nt < 3; nt++) {
                    accB[mt][nt] = (floatx4){0.f, 0.f, 0.f, 0.f};
                    accB[mt][nt] = MFMA16(afa, pqf[nt][0], accB[mt][nt]);
                    accB[mt][nt] = MFMA16(afb, pqf[nt][1], accB[mt][nt]);
                }
            }
            #pragma unroll
            for (int mt = 0; mt < 2; mt++)
                #pragma unroll
                for (int nt = 0; nt < 3; nt++)
                    #pragma unroll
                    for (int r = 0; r < 4; r++)
                        Bfs[wave][mt * 16 + quad * 4 + r][nt * 16 + m16] = accB[mt][nt][r];
        }
        // ---- gather + combine + in-register online softmax ----
        float sv[2][4];
        float tmax[4] = {NEG_BIG, NEG_BIG, NEG_BIG, NEG_BIG};
        #pragma unroll
        for (int n = 0; n < 2; n++) {
            #pragma unroll
            for (int r = 0; r < 4; r++) {
                int qq = quad * 4 + r;
                int kc = n * 16 + m16;
                float av = Afs[wave][qq][qq - kc + 31];
                float bv = Bfs[wave][kc][kc - qq + 15];
                float x = (accS[n][r] + av + bv) * inv_scale;
                x = mkk[s][kc] ? x : NEG_BIG;
                sv[n][r] = x;
                tmax[r] = fmaxf(tmax[r], x);
            }
        }
        float alpha[4], psum[4];
        #pragma unroll
        for (int r = 0; r < 4; r++) {
            float tm = tmax[r];
            tm = fmaxf(tm, __shfl_xor(tm, 1));
            tm = fmaxf(tm, __shfl_xor(tm, 2));
            tm = fmaxf(tm, __shfl_xor(tm, 4));
            tm = fmaxf(tm, __shfl_xor(tm, 8));
            float mo = mreg[r];
            float mn = fmaxf(mo, tm);
            alpha[r] = __expf(mo - mn);
            mreg[r] = mn;
        }
        #pragma unroll
        for (int r = 0; r < 4; r++) psum[r] = 0.f;
        #pragma unroll
        for (int n = 0; n < 2; n++) {
            #pragma unroll
            for (int r = 0; r < 4; r++) {
                float p = (sv[n][r] > -1.5e38f) ? __expf(sv[n][r] - mreg[r]) : 0.0f;
                unsigned short pb = f2b(p);
                Pls[wave][quad * 4 + r][n * 16 + m16] = pb;
                psum[r] += b2f(pb);
            }
        }
        #pragma unroll
        for (int r = 0; r < 4; r++) {
            float ps = psum[r];
            ps += __shfl_xor(ps, 1);
            ps += __shfl_xor(ps, 2);
            ps += __shfl_xor(ps, 4);
            ps += __shfl_xor(ps, 8);
            lreg[r] = lreg[r] * alpha[r] + ps;
        }
        // ---- rescale O, then PV ----
        #pragma unroll
        for (int nt = 0; nt < 4; nt++)
            #pragma unroll
            for (int r = 0; r < 4; r++) accO[nt][r] *= alpha[r];
        {
            bf16x8 pf = *(const bf16x8*)&Pls[wave][m16][quad * 8];
            #pragma unroll
            for (int nt = 0; nt < 4; nt++) {
                int d = nt * 16 + m16;
                int kq = (quad ^ ((d >> 3) & 3)) * 8;
                bf16x8 vf = *(const bf16x8*)&Vt[s][d][kq];
                accO[nt] = MFMA16(pf, vf, accO[nt]);
            }
        }
    };

    bf16x8 pkfA[3][2], pqfA[3][2], pkfB[3][2], pqfB[3][2];
    loadPQ(s, pkfA, pqfA);                        // ph=0 window
    #pragma unroll
    for (int pp = 0; pp < 4; pp++) {
        {   // even phase: uses A set, prefetches B set
            int ph = 2 * pp;
            __syncthreads();                      // prior PV/gather reads complete
            stageKV(ph);
            __syncthreads();
            if (ph < 7) loadPQ(2 * (ph + 1) + s, pkfB, pqfB);
            computePhase(pkfA, pqfA);
        }
        {   // odd phase: uses B set, prefetches A set
            int ph = 2 * pp + 1;
            __syncthreads();
            stageKV(ph);
            __syncthreads();
            if (ph < 7) loadPQ(2 * (ph + 1) + s, pkfA, pqfA);
            computePhase(pkfB, pqfB);
        }
    }

    // ---- merge the two k-halves per q-strip (flash split-k merge) ----
    __syncthreads();       // all Bfs gathers done -> safe to alias merge buffer
    float* mo = &Bfs[0][0][0];  // mergeO[u][row][col]: u*1056 + row*66 + col (2112 floats < 6400)
    if (s == 1) {
        #pragma unroll
        for (int nt = 0; nt < 4; nt++)
            #pragma unroll
            for (int r = 0; r < 4; r++)
                mo[u * 1056 + (quad * 4 + r) * 66 + nt * 16 + m16] = accO[nt][r];
        if (m16 == 0) {
            #pragma unroll
            for (int r = 0; r < 4; r++) {
                mergeML[u][0][quad * 4 + r] = mreg[r];
                mergeML[u][1][quad * 4 + r] = lreg[r];
            }
        }
    }
    __syncthreads();
    if (s == 0) {
        #pragma unroll
        for (int r = 0; r < 4; r++) {
            int row = quad * 4 + r;
            float m1 = mergeML[u][0][row], l1 = mergeML[u][1][row];
            float m0 = mreg[r], l0 = lreg[r];
            float mt = fmaxf(m0, m1);
            float a0 = __expf(m0 - mt), a1 = __expf(m1 - mt);
            float lt = l0 * a0 + l1 * a1;
            float inv = lt > 0.0f ? 1.0f / lt : 0.0f;
            inv *= (float)am[b * SEQ + q0 + u * 16 + row];
            #pragma unroll
            for (int nt = 0; nt < 4; nt++) {
                float o1 = mo[u * 1056 + row * 66 + nt * 16 + m16];
                float val = (accO[nt][r] * a0 + o1 * a1) * inv;
                ctx[(size_t)(b * SEQ + q0 + u * 16 + row) * HID + hh * HEAD + nt * 16 + m16] = f2b(val);
            }
        }
    }
}

// ---------------- output copy / classifier (fp32 out) ----------------
__global__ void copy_f_kernel(const float* __restrict__ in, float* __restrict__ out, int n) {
    int i = blockIdx.x * 256 + threadIdx.x;
    if (i < n) out[i] = in[i];
}
__global__ void cls_kernel(const float* __restrict__ h, const float* __restrict__ cls_w,
                           const float* __restrict__ cls_b, float* __restrict__ out) {
    int t = blockIdx.x, v = threadIdx.x;
    if (v < VOCAB) {
        const float* hr = h + (size_t)t * HID;
        const float* wr = cls_w + (size_t)v * HID;
        float acc = cls_b[v];
        for (int d = 0; d < HID; d++) acc += hr[d] * wr[d];
        out[t * VOCAB + v] = acc;
    }
}

extern "C" void kernel_launch(void* const* d_in, const int* in_sizes, int n_in,
                              void* d_out, int out_size, void* d_ws, size_t ws_size,
                              hipStream_t stream) {
    const int* x     = (const int*)d_in[0];
    const int* am    = (const int*)d_in[1];
    const float* word_emb = (const float*)d_in[2];
    const float* emb_g    = (const float*)d_in[3];
    const float* emb_b    = (const float*)d_in[4];
    const float* rel_emb  = (const float*)d_in[5];
    const float* Wq  = (const float*)d_in[6];  const float* bq  = (const float*)d_in[7];
    const float* Wk  = (const float*)d_in[8];  const float* bk  = (const float*)d_in[9];
    const float* Wv  = (const float*)d_in[10]; const float* bv  = (const float*)d_in[11];
    const float* Wpk = (const float*)d_in[12]; const float* bpk = (const float*)d_in[13];
    const float* Wpq = (const float*)d_in[14]; const float* bpq = (const float*)d_in[15];
    const float* Wo  = (const float*)d_in[16]; const float* bo  = (const float*)d_in[17];
    const float* ln1g = (const float*)d_in[18]; const float* ln1b = (const float*)d_in[19];
    const float* W1  = (const float*)d_in[20]; const float* b1  = (const float*)d_in[21];
    const float* W2  = (const float*)d_in[22]; const float* b2  = (const float*)d_in[23];
    const float* ln2g = (const float*)d_in[24]; const float* ln2b = (const float*)d_in[25];
    const float* cls_w = (const float*)d_in[26]; const float* cls_b = (const float*)d_in[27];

    char* wsb = (char*)d_ws;
    const size_t NEED_BIG = 107u << 20;   // 23 MB activations + 84 MB bf16 weights

    if (ws_size >= NEED_BIG) {
        // ---- big-workspace path: preconverted transposed bf16 weights ----
        float* h  = (float*)wsb;                                      // 4 MB
        float* t1 = (float*)(wsb + (4u << 20));                       // 4 MB (split-K part 0)
        float* t2 = (float*)(wsb + (8u << 20));                       // 4 MB (split-K part 1)
        unsigned short* qb   = (unsigned short*)(wsb + (12u << 20));  // 2 MB
        unsigned short* kb   = (unsigned short*)(wsb + (14u << 20));  // 2 MB
        unsigned short* vb   = (unsigned short*)(wsb + (16u << 20));  // 2 MB
        unsigned short* pkb  = (unsigned short*)(wsb + (18u << 20));  // 1 MB
        unsigned short* pqb  = (unsigned short*)(wsb + (19u << 20));  // 1 MB
        unsigned short* relb = (unsigned short*)(wsb + (20u << 20));  // 1 MB
        unsigned short* hb   = (unsigned short*)(wsb + (21u << 20));  // 2 MB
        unsigned short* ctx  = hb;   // alias: hb dead between attn and add_ln1
        unsigned short* ffb  = qb;   // alias: qb..pqb (8 MB) dead by FF1
        unsigned short* Wqt  = (unsigned short*)(wsb + (23u << 20));  // 6x6 MB: q,k,v,pk,pq,o
        unsigned short* W1t  = (unsigned short*)(wsb + (59u << 20));  // 24 MB
        unsigned short* W2t  = (unsigned short*)(wsb + (83u << 20));  // 24 MB

        const size_t M512 = (size_t)HID * HID;   // elements per 512x512 matrix

        tcvt6_kernel<<<dim3(16, 16, 72), dim3(32, 8), 0, stream>>>(Wq, Wk, Wv, Wpk, Wpq, Wo, Wqt);
        tcvt_kernel<<<dim3(64, 16, 12), dim3(32, 8), 0, stream>>>(W1, W1t, HID, FFDIM);
        tcvt_kernel<<<dim3(16, 64, 12), dim3(32, 8), 0, stream>>>(W2, W2t, FFDIM, HID);
        cvt_rel_kernel<<<dim3(SPAN2 * HID / 1024), dim3(256), 0, stream>>>(rel_emb, relb);
        embed_ln_kernel<<<dim3(TOK / 4), dim3(256), 0, stream>>>(x, am, word_emb, emb_g, emb_b, h, hb);

        for (int l = 0; l < NLAYER; l++) {
            qkvp_gemm<<<dim3(512), dim3(256), 0, stream>>>(
                hb, relb,
                Wqt + (size_t)(0 * NLAYER + l) * M512, Wqt + (size_t)(1 * NLAYER + l) * M512,
                Wqt + (size_t)(2 * NLAYER + l) * M512, Wqt + (size_t)(3 * NLAYER + l) * M512,
                Wqt + (size_t)(4 * NLAYER + l) * M512,
                bq + l * HID, bk + l * HID, bv + l * HID, bpk + l * HID, bpq + l * HID,
                qb, kb, vb, pkb, pqb);

            attn_kernel<<<dim3(512), dim3(256), 0, stream>>>(
                qb, kb, vb, pkb, pqb, am, ctx);

            gemm_bt2<false, false, 2><<<dim3(HID / 64, TOK / 128, 2), dim3(256), 0, stream>>>(
                ctx, Wqt + (size_t)(5 * NLAYER + l) * M512, bo + l * HID, t1, HID, HID);
            add_ln2_kernel<<<dim3(TOK / 4), dim3(256), 0, stream>>>(t1, t2, ln1g + l * HID, ln1b + l * HID, h, hb);

            gemm_bt2<true, true, 1><<<dim3(FFDIM / 64, TOK / 128, 1), dim3(256), 0, stream>>>(
                hb, W1t + (size_t)l * HID * FFDIM, b1 + l * FFDIM, ffb, FFDIM, HID);
            gemm_bt2<false, false, 2><<<dim3(HID / 64, TOK / 128, 2), dim3(256), 0, stream>>>(
                ffb, W2t + (size_t)l * HID * FFDIM, b2 + l * HID, t1, HID, FFDIM);
            add_ln2_kernel<<<dim3(TOK / 4), dim3(256), 0, stream>>>(t1, t2, ln2g + l * HID, ln2b + l * HID, h, hb);
        }

        float* out_f = (float*)d_out;
        copy_f_kernel<<<dim3(TOK * HID / 256), dim3(256), 0, stream>>>(h, out_f, TOK * HID);
        cls_kernel<<<dim3(TOK), dim3(32), 0, stream>>>(h, cls_w, cls_b, out_f + TOK * HID);
        return;
    }

    // ---- fallback path: baseline 19 MB layout, inline fp32->bf16 weight conversion ----
    const size_t NEEDED = 19u << 20;
    if (ws_size < NEEDED) return;
    float* h  = (float*)wsb;                                     // 4 MB
    float* t1 = (float*)(wsb + (4u << 20));                      // 4 MB
    unsigned short* qb   = (unsigned short*)(wsb + (8u << 20));  // 2 MB
    unsigned short* kb   = qb  + (1u << 20);                     // 2 MB
    unsigned short* vb   = kb  + (1u << 20);                     // 2 MB
    unsigned short* pkb  = vb  + (1u << 20);                     // 1 MB
    unsigned short* pqb  = pkb + (1u << 19);                     // 1 MB
    unsigned short* relb = (unsigned short*)(wsb + (16u << 20)); // 1 MB
    unsigned short* hb   = (unsigned short*)(wsb + (17u << 20)); // 2 MB
    unsigned short* ctx  = hb;   // alias: hb dead between V-GEMM and add_ln1
    unsigned short* ffb  = qb;   // alias: q..pq dead by FF1

    cvt_rel_kernel<<<dim3(SPAN2 * HID / 1024), dim3(256), 0, stream>>>(rel_emb, relb);
    embed_ln_kernel<<<dim3(TOK / 4), dim3(256), 0, stream>>>(x, am, word_emb, emb_g, emb_b, h, hb);

    for (int l = 0; l < NLAYER; l++) {
        const float* Wq_l = Wq + (size_t)l * HID * HID;
        const float* Wk_l = Wk + (size_t)l * HID * HID;
        const float* Wv_l = Wv + (size_t)l * HID * HID;
        const float* Wo_l = Wo + (size_t)l * HID * HID;
        const float* Wpk_l = Wpk + (size_t)l * HID * HID;
        const float* Wpq_l = Wpq + (size_t)l * HID * HID;
        const float* W1_l = W1 + (size_t)l * HID * FFDIM;
        const float* W2_l = W2 + (size_t)l * FFDIM * HID;

        mfma_gemm<true,  false><<<dim3(HID/64, TOK/64),   dim3(256), 0, stream>>>(hb,   Wq_l,  bq + l*HID,  qb,  HID, HID);
        mfma_gemm<true,  false><<<dim3(HID/64, TOK/64),   dim3(256), 0, stream>>>(hb,   Wk_l,  bk + l*HID,  kb,  HID, HID);
        mfma_gemm<true,  false><<<dim3(HID/64, TOK/64),   dim3(256), 0, stream>>>(hb,   Wv_l,  bv + l*HID,  vb,  HID, HID);
        mfma_gemm<true,  false><<<dim3(HID/64, SPAN2/64), dim3(256), 0, stream>>>(relb, Wpk_l, bpk + l*HID, pkb, HID, HID);
        mfma_gemm<true,  false><<<dim3(HID/64, SPAN2/64), dim3(256), 0, stream>>>(relb, Wpq_l, bpq + l*HID, pqb, HID, HID);

        attn_kernel<<<dim3(512), dim3(256), 0, stream>>>(qb, kb, vb, pkb, pqb, am, ctx);

        mfma_gemm<false, false><<<dim3(HID/64, TOK/64),   dim3(256), 0, stream>>>(ctx,  Wo_l,  bo + l*HID,  t1,  HID, HID);
        add_ln_kernel<<<dim3(TOK / 4), dim3(256), 0, stream>>>(t1, ln1g + l*HID, ln1b + l*HID, h, hb);

        mfma_gemm<true,  true ><<<dim3(FFDIM/64, TOK/64), dim3(256), 0, stream>>>(hb,   W1_l,  b1 + l*FFDIM, ffb, FFDIM, HID);
        mfma_gemm<false, false><<<dim3(HID/64, TOK/64),   dim3(256), 0, stream>>>(ffb,  W2_l,  b2 + l*HID,  t1,  HID, FFDIM);
        add_ln_kernel<<<dim3(TOK / 4), dim3(256), 0, stream>>>(t1, ln2g + l*HID, ln2b + l*HID, h, hb);
    }

    float* out_f = (float*)d_out;
    copy_f_kernel<<<dim3(TOK*HID/256), dim3(256), 0, stream>>>(h, out_f, TOK*HID);
    cls_kernel<<<dim3(TOK), dim3(32), 0, stream>>>(h, cls_w, cls_b, out_f + TOK*HID);
}

// Round 8
// 1347.648 us; speedup vs baseline: 1.1164x; 1.0566x over previous
//
#include <hip/hip_runtime.h>
#include <hip/hip_bf16.h>

// Model dims (fixed by the reference)
#define BATCH  4
#define SEQ    512
#define TOK    (BATCH*SEQ)     // 2048
#define HID    512
#define NHEAD  8
#define HEAD   64
#define FFDIM  2048
#define NLAYER 12
#define SPAN2  1024            // 2*SPAN
#define VOCAB  25
#define LNEPS  1e-7f
#define NEG_BIG -3.0e38f

typedef __attribute__((ext_vector_type(8))) short bf16x8;   // 8 bf16 = 4 VGPRs
typedef __attribute__((ext_vector_type(4))) float floatx4;

#define MFMA16(a, b, c) __builtin_amdgcn_mfma_f32_16x16x32_bf16((a), (b), (c), 0, 0, 0)

__device__ __forceinline__ float b2f(unsigned short u) {
    return __uint_as_float(((unsigned int)u) << 16);
}
__device__ __forceinline__ unsigned short f2b(float f) {
    __hip_bfloat16 h = __float2bfloat16(f);
    return *(unsigned short*)&h;
}
// tanh-form GELU (max |err| vs exact erf ~1e-3, well inside tolerance); __expf is HW exp2
__device__ __forceinline__ float gelu_tanh(float v) {
    float y = 1.5957691216057308f * (v + 0.044715f * v * v * v);   // 2*0.7978845608*(...)
    float t = 1.0f - 2.0f / (__expf(y) + 1.0f);                    // tanh(y/2*2)=tanh(0.798(..))
    return 0.5f * v * (1.0f + t);
}

// async global->LDS, 16 bytes per lane: LDS dest = wave-uniform base + lane*16
__device__ __forceinline__ void gload16(const unsigned short* g, unsigned short* lds_base) {
    __builtin_amdgcn_global_load_lds((const __attribute__((address_space(1))) void*)g,
                                     (__attribute__((address_space(3))) void*)lds_base, 16, 0, 0);
}

// ---------------- wave-per-token LayerNorm helpers (grid = TOK/4, block = 256) ----------------
__device__ __forceinline__ float wave_sum(float v) {
    #pragma unroll
    for (int o = 1; o < 64; o <<= 1) v += __shfl_xor(v, o);
    return v;
}

__device__ __forceinline__ void ln_finish(const float (&v)[8], const float* __restrict__ g,
                                          const float* __restrict__ bb, int lane, float maskf,
                                          size_t base, float* __restrict__ h,
                                          unsigned short* __restrict__ hb) {
    float sum = 0.f;
    #pragma unroll
    for (int j = 0; j < 8; j++) sum += v[j];
    float mean = wave_sum(sum) * (1.0f / HID);
    float d[8]; float var = 0.f;
    #pragma unroll
    for (int j = 0; j < 8; j++) { d[j] = v[j] - mean; var += d[j] * d[j]; }
    float rstd = rsqrtf(wave_sum(var) * (1.0f / HID) + LNEPS);
    const float* gp = g + lane * 8; const float* bp = bb + lane * 8;
    float4 g0 = *(const float4*)gp, g1 = *(const float4*)(gp + 4);
    float4 b0 = *(const float4*)bp, b1 = *(const float4*)(bp + 4);
    float gg[8] = {g0.x, g0.y, g0.z, g0.w, g1.x, g1.y, g1.z, g1.w};
    float bv[8] = {b0.x, b0.y, b0.z, b0.w, b1.x, b1.y, b1.z, b1.w};
    float o8[8];
    #pragma unroll
    for (int j = 0; j < 8; j++) o8[j] = (d[j] * rstd * gg[j] + bv[j]) * maskf;
    *(float4*)(h + base)     = make_float4(o8[0], o8[1], o8[2], o8[3]);
    *(float4*)(h + base + 4) = make_float4(o8[4], o8[5], o8[6], o8[7]);
    uint4 pb;
    pb.x = (unsigned int)f2b(o8[0]) | ((unsigned int)f2b(o8[1]) << 16);
    pb.y = (unsigned int)f2b(o8[2]) | ((unsigned int)f2b(o8[3]) << 16);
    pb.z = (unsigned int)f2b(o8[4]) | ((unsigned int)f2b(o8[5]) << 16);
    pb.w = (unsigned int)f2b(o8[6]) | ((unsigned int)f2b(o8[7]) << 16);
    *(uint4*)(hb + base) = pb;
}

// ---------------- embedding gather + LN + mask ----------------
__global__ void embed_ln_kernel(const int* __restrict__ x, const int* __restrict__ am,
                                const float* __restrict__ word_emb,
                                const float* __restrict__ g, const float* __restrict__ bb,
                                float* __restrict__ h, unsigned short* __restrict__ hb) {
    int wv = threadIdx.x >> 6, lane = threadIdx.x & 63;
    int t = blockIdx.x * 4 + wv;
    const float* we = word_emb + (size_t)x[t] * HID + lane * 8;
    float4 va = *(const float4*)we, vb2 = *(const float4*)(we + 4);
    float v[8] = {va.x, va.y, va.z, va.w, vb2.x, vb2.y, vb2.z, vb2.w};
    ln_finish(v, g, bb, lane, (float)am[t], (size_t)t * HID + lane * 8, h, hb);
}

// ---------------- residual add + LN, single tmp (fallback path) ----------------
__global__ void add_ln_kernel(const float* __restrict__ tmp,
                              const float* __restrict__ g, const float* __restrict__ bb,
                              float* __restrict__ h, unsigned short* __restrict__ hb) {
    int wv = threadIdx.x >> 6, lane = threadIdx.x & 63;
    int t = blockIdx.x * 4 + wv;
    size_t base = (size_t)t * HID + lane * 8;
    float4 ta = *(const float4*)(tmp + base), tb = *(const float4*)(tmp + base + 4);
    float4 ha = *(const float4*)(h + base),  hbb = *(const float4*)(h + base + 4);
    float v[8] = {ta.x + ha.x, ta.y + ha.y, ta.z + ha.z, ta.w + ha.w,
                  tb.x + hbb.x, tb.y + hbb.y, tb.z + hbb.z, tb.w + hbb.w};
    ln_finish(v, g, bb, lane, 1.0f, base, h, hb);
}

// ---------------- residual add + LN, two split-K partials; hout may differ from h ----------------
__global__ void add_ln2_kernel(const float* __restrict__ t1a, const float* __restrict__ t1b,
                               const float* __restrict__ g, const float* __restrict__ bb,
                               const float* __restrict__ hin, float* __restrict__ hout,
                               unsigned short* __restrict__ hb) {
    int wv = threadIdx.x >> 6, lane = threadIdx.x & 63;
    int t = blockIdx.x * 4 + wv;
    size_t base = (size_t)t * HID + lane * 8;
    float4 aa = *(const float4*)(t1a + base), ab = *(const float4*)(t1a + base + 4);
    float4 ba = *(const float4*)(t1b + base), bbv = *(const float4*)(t1b + base + 4);
    float4 ha = *(const float4*)(hin + base), hb2 = *(const float4*)(hin + base + 4);
    float v[8] = {aa.x + ba.x + ha.x, aa.y + ba.y + ha.y, aa.z + ba.z + ha.z, aa.w + ba.w + ha.w,
                  ab.x + bbv.x + hb2.x, ab.y + bbv.y + hb2.y, ab.z + bbv.z + hb2.z, ab.w + bbv.w + hb2.w};
    ln_finish(v, g, bb, lane, 1.0f, base, hout, hb);
}

// ---------------- fp32 -> bf16 convert (rel_emb, n multiple of 1024) ----------------
__global__ void cvt_rel_kernel(const float* __restrict__ in, unsigned short* __restrict__ out) {
    int i = (blockIdx.x * 256 + threadIdx.x) * 4;
    float4 v = *(const float4*)(in + i);
    out[i] = f2b(v.x); out[i+1] = f2b(v.y); out[i+2] = f2b(v.z); out[i+3] = f2b(v.w);
}

// ---------------- transpose+convert: W[K][N] fp32 -> Wt[N][K] bf16, blockIdx.z = layer ----------------
__global__ void tcvt_kernel(const float* __restrict__ in, unsigned short* __restrict__ out,
                            int K, int N) {
    __shared__ float tile[32][33];
    int l = blockIdx.z;
    const float* ip = in + (size_t)l * K * N;
    unsigned short* op = out + (size_t)l * K * N;
    int kb = blockIdx.y * 32, nb = blockIdx.x * 32;
    int tx = threadIdx.x, ty = threadIdx.y;   // block (32,8)
    #pragma unroll
    for (int i = 0; i < 32; i += 8) tile[ty + i][tx] = ip[(size_t)(kb + ty + i) * N + nb + tx];
    __syncthreads();
    #pragma unroll
    for (int i = 0; i < 32; i += 8) op[(size_t)(nb + ty + i) * K + kb + tx] = f2b(tile[tx][ty + i]);
}

// six [12][512][512] weight arrays in one launch; z = l*6 + w; out contiguous [w][l][512][512]
__global__ void tcvt6_kernel(const float* __restrict__ Wq, const float* __restrict__ Wk,
                             const float* __restrict__ Wv, const float* __restrict__ Wpk,
                             const float* __restrict__ Wpq, const float* __restrict__ Wo,
                             unsigned short* __restrict__ out) {
    __shared__ float tile[32][33];
    int z = blockIdx.z, l = z / 6, w = z - l * 6;
    const float* src = w == 0 ? Wq : w == 1 ? Wk : w == 2 ? Wv : w == 3 ? Wpk : w == 4 ? Wpq : Wo;
    const float* ip = src + (size_t)l * HID * HID;
    unsigned short* op = out + ((size_t)w * NLAYER + l) * HID * HID;
    int kb = blockIdx.y * 32, nb = blockIdx.x * 32;
    int tx = threadIdx.x, ty = threadIdx.y;
    #pragma unroll
    for (int i = 0; i < 32; i += 8) tile[ty + i][tx] = ip[(size_t)(kb + ty + i) * HID + nb + tx];
    __syncthreads();
    #pragma unroll
    for (int i = 0; i < 32; i += 8) op[(size_t)(nb + ty + i) * HID + kb + tx] = f2b(tile[tx][ty + i]);
}

// ---------------- 64x64 tile core, double-buffered LDS staging (proven round-5 code) ----------------
__device__ __forceinline__ void gemm_tile_bt(
    const unsigned short* __restrict__ A, const unsigned short* __restrict__ Bt,
    int row0, int col0, int K, int kbeg, int kend,
    floatx4 (&acc)[2][2], unsigned short (&As)[2][64][72], unsigned short (&Bs)[2][64][72]) {
    int tid = threadIdx.x;
    int lane = tid & 63, wid = tid >> 6;
    int wm = wid >> 1, wn = wid & 1;
    int m16 = lane & 15, quad = lane >> 4;
    int sr = tid >> 2, sc = (tid & 3) << 4;          // staging: row, 16 bf16 cols
    const unsigned short* Ag = A + (size_t)(row0 + sr) * K + sc;
    const unsigned short* Bg = Bt + (size_t)(col0 + sr) * K + sc;

    uint4 av0 = *(const uint4*)(Ag + kbeg);
    uint4 av1 = *(const uint4*)(Ag + kbeg + 8);
    uint4 bv0 = *(const uint4*)(Bg + kbeg);
    uint4 bv1 = *(const uint4*)(Bg + kbeg + 8);
    *(uint4*)&As[0][sr][sc]     = av0;
    *(uint4*)&As[0][sr][sc + 8] = av1;
    *(uint4*)&Bs[0][sr][sc]     = bv0;
    *(uint4*)&Bs[0][sr][sc + 8] = bv1;
    __syncthreads();

    int cur = 0;
    for (int k0 = kbeg; k0 < kend; k0 += 64) {
        int k1 = k0 + 64;
        bool more = k1 < kend;                 // uniform across block
        if (more) {                            // issue next-tile loads early
            av0 = *(const uint4*)(Ag + k1);
            av1 = *(const uint4*)(Ag + k1 + 8);
            bv0 = *(const uint4*)(Bg + k1);
            bv1 = *(const uint4*)(Bg + k1 + 8);
        }
        #pragma unroll
        for (int kk = 0; kk < 2; kk++) {       // MFMA on current buffer (hides load latency)
            bf16x8 a0 = *(const bf16x8*)&As[cur][wm * 32 + m16][kk * 32 + quad * 8];
            bf16x8 a1 = *(const bf16x8*)&As[cur][wm * 32 + 16 + m16][kk * 32 + quad * 8];
            bf16x8 b0 = *(const bf16x8*)&Bs[cur][wn * 32 + m16][kk * 32 + quad * 8];
            bf16x8 b1 = *(const bf16x8*)&Bs[cur][wn * 32 + 16 + m16][kk * 32 + quad * 8];
            acc[0][0] = MFMA16(a0, b0, acc[0][0]);
            acc[0][1] = MFMA16(a0, b1, acc[0][1]);
            acc[1][0] = MFMA16(a1, b0, acc[1][0]);
            acc[1][1] = MFMA16(a1, b1, acc[1][1]);
        }
        if (more) {                            // write next tile into the other buffer
            *(uint4*)&As[cur ^ 1][sr][sc]     = av0;
            *(uint4*)&As[cur ^ 1][sr][sc + 8] = av1;
            *(uint4*)&Bs[cur ^ 1][sr][sc]     = bv0;
            *(uint4*)&Bs[cur ^ 1][sr][sc + 8] = bv1;
            __syncthreads();                   // one barrier per k-step
            cur ^= 1;
        }
    }
}

// ---------------- 64x64 bf16-weight GEMM, split-K over blockIdx.z (for Wo / FF2: 512-WG grids) ----------------
template<bool OUT_BF16, bool GELU, int SPLITK>
__global__ __launch_bounds__(256) void gemm_bt(
    const unsigned short* __restrict__ A, const unsigned short* __restrict__ Bt,
    const float* __restrict__ bias, void* __restrict__ Cp, int N, int K) {
    __shared__ unsigned short As[2][64][72], Bs[2][64][72];
    int row0 = blockIdx.y * 64, col0 = blockIdx.x * 64;
    int kseg = K / SPLITK;
    int kbeg = kseg * blockIdx.z, kend = kbeg + kseg;
    floatx4 acc[2][2];
    #pragma unroll
    for (int mi = 0; mi < 2; mi++)
        #pragma unroll
        for (int ni = 0; ni < 2; ni++) acc[mi][ni] = (floatx4){0.f, 0.f, 0.f, 0.f};
    gemm_tile_bt(A, Bt, row0, col0, K, kbeg, kend, acc, As, Bs);

    int tid = threadIdx.x, lane = tid & 63, wid = tid >> 6;
    int wm = wid >> 1, wn = wid & 1, m16 = lane & 15, quad = lane >> 4;
    size_t outoff = (size_t)blockIdx.z * (size_t)(gridDim.y << 6) * N;
    #pragma unroll
    for (int ni = 0; ni < 2; ni++) {
        int colg = col0 + wn * 32 + ni * 16 + m16;
        float bval = (SPLITK == 1 || blockIdx.z == 0) ? bias[colg] : 0.0f;
        #pragma unroll
        for (int mi = 0; mi < 2; mi++) {
            #pragma unroll
            for (int r = 0; r < 4; r++) {
                int rowg = row0 + wm * 32 + mi * 16 + quad * 4 + r;
                float v = acc[mi][ni][r] + bval;
                if (GELU) v = gelu_tanh(v);
                if (OUT_BF16) ((unsigned short*)Cp)[(size_t)rowg * N + colg] = f2b(v);
                else          ((float*)Cp)[outoff + (size_t)rowg * N + colg] = v;
            }
        }
    }
}

// ---------------- 128x64 tile core: global_load_lds + XOR-swizzled unpadded LDS ----------------
__device__ __forceinline__ void gemm_core128(
    const unsigned short* __restrict__ A, const unsigned short* __restrict__ Bt,
    int row0, int col0, int K, int kbeg, int kend,
    floatx4 (&acc)[4][2], unsigned short* AsB, unsigned short* BsB) {
    int tid = threadIdx.x;
    int lane = tid & 63, w = tid >> 6;
    int wm = w >> 1, wn = w & 1;
    int m16 = lane & 15, quad = lane >> 4;

    int arow[4], acol[4], brow[2], bcol[2];
    #pragma unroll
    for (int c = 0; c < 4; c++) {
        int o = ((w * 4 + c) * 64 + lane) * 16;        // linear LDS byte dest
        int r = o >> 7;                                 // 128 B per row
        arow[c] = r;
        acol[c] = (o & 127) ^ ((r & 7) << 4);           // inverse-swizzled source column
    }
    #pragma unroll
    for (int c = 0; c < 2; c++) {
        int o = ((w * 2 + c) * 64 + lane) * 16;
        int r = o >> 7;
        brow[c] = r;
        bcol[c] = (o & 127) ^ ((r & 7) << 4);
    }

    auto stage = [&](int bf, int k0) {
        #pragma unroll
        for (int c = 0; c < 4; c++)
            gload16(A + (size_t)(row0 + arow[c]) * K + k0 + (acol[c] >> 1),
                    AsB + bf * 8192 + (w * 4 + c) * 512);
        #pragma unroll
        for (int c = 0; c < 2; c++)
            gload16(Bt + (size_t)(col0 + brow[c]) * K + k0 + (bcol[c] >> 1),
                    BsB + bf * 4096 + (w * 2 + c) * 512);
    };

    stage(0, kbeg);
    __syncthreads();
    int cur = 0;
    for (int k0 = kbeg; k0 < kend; k0 += 64) {
        if (k0 + 64 < kend) stage(cur ^ 1, k0 + 64);
        const char* Ab = (const char*)(AsB + cur * 8192);
        const char* Bb = (const char*)(BsB + cur * 4096);
        int br0 = wn * 32 + m16, br1 = wn * 32 + 16 + m16;
        #pragma unroll
        for (int kk = 0; kk < 2; kk++) {
            bf16x8 bf0 = *(const bf16x8*)(Bb + ((((br0 << 7) + kk * 64 + quad * 16)) ^ ((m16 & 7) << 4)));
            bf16x8 bf1 = *(const bf16x8*)(Bb + ((((br1 << 7) + kk * 64 + quad * 16)) ^ ((m16 & 7) << 4)));
            #pragma unroll
            for (int mi = 0; mi < 4; mi++) {
                int ar = wm * 64 + mi * 16 + m16;
                bf16x8 af = *(const bf16x8*)(Ab + ((((ar << 7) + kk * 64 + quad * 16)) ^ ((m16 & 7) << 4)));
                acc[mi][0] = MFMA16(af, bf0, acc[mi][0]);
                acc[mi][1] = MFMA16(af, bf1, acc[mi][1]);
            }
        }
        __syncthreads();
        cur ^= 1;
    }
}

// ---------------- generic bf16-weight GEMM on the 128x64 core (FF1) ----------------
template<bool OUT_BF16, bool GELU, int SPLITK>
__global__ __launch_bounds__(256, 2) void gemm_bt2(
    const unsigned short* __restrict__ A, const unsigned short* __restrict__ Bt,
    const float* __restrict__ bias, void* __restrict__ Cp, int N, int K) {
    __shared__ unsigned short As[2][8192], Bs[2][4096];
    int row0 = blockIdx.y * 128, col0 = blockIdx.x * 64;
    int kseg = K / SPLITK;
    int kbeg = kseg * blockIdx.z, kend = kbeg + kseg;
    floatx4 acc[4][2];
    #pragma unroll
    for (int mi = 0; mi < 4; mi++)
        #pragma unroll
        for (int ni = 0; ni < 2; ni++) acc[mi][ni] = (floatx4){0.f, 0.f, 0.f, 0.f};
    gemm_core128(A, Bt, row0, col0, K, kbeg, kend, acc, &As[0][0], &Bs[0][0]);

    int tid = threadIdx.x, lane = tid & 63, wid = tid >> 6;
    int wm = wid >> 1, wn = wid & 1, m16 = lane & 15, quad = lane >> 4;
    size_t outoff = (size_t)blockIdx.z * (size_t)(gridDim.y << 7) * N;
    #pragma unroll
    for (int ni = 0; ni < 2; ni++) {
        int colg = col0 + wn * 32 + ni * 16 + m16;
        float bval = (SPLITK == 1 || blockIdx.z == 0) ? bias[colg] : 0.0f;
        #pragma unroll
        for (int mi = 0; mi < 4; mi++) {
            #pragma unroll
            for (int r = 0; r < 4; r++) {
                int rowg = row0 + wm * 64 + mi * 16 + quad * 4 + r;
                float v = acc[mi][ni][r] + bval;
                if (GELU) v = gelu_tanh(v);
                if (OUT_BF16) ((unsigned short*)Cp)[(size_t)rowg * N + colg] = f2b(v);
                else          ((float*)Cp)[outoff + (size_t)rowg * N + colg] = v;
            }
        }
    }
}

// ---------------- fused Q,K,V,Pk,Pq projections on the 128x64 core: 512 WGs ----------------
__global__ __launch_bounds__(256, 2) void qkvp_gemm(
    const unsigned short* __restrict__ hb, const unsigned short* __restrict__ relb,
    const unsigned short* __restrict__ Wqt, const unsigned short* __restrict__ Wkt,
    const unsigned short* __restrict__ Wvt, const unsigned short* __restrict__ Wpkt,
    const unsigned short* __restrict__ Wpqt,
    const float* __restrict__ bq, const float* __restrict__ bk, const float* __restrict__ bv,
    const float* __restrict__ bpk, const float* __restrict__ bpq,
    unsigned short* __restrict__ qb, unsigned short* __restrict__ kb,
    unsigned short* __restrict__ vb, unsigned short* __restrict__ pkb,
    unsigned short* __restrict__ pqb) {
    __shared__ unsigned short As[2][8192], Bs[2][4096];
    int bid = blockIdx.x;
    int xcd = bid & 7, slot = bid >> 3;    // 64 slots per XCD
    int op, j;
    if (xcd < 6) { op = xcd >> 1; j = slot * 2 + (xcd & 1); }   // Q,K,V: j in [0,128)
    else         { op = xcd - 3;  j = slot; }                   // Pk,Pq: j in [0,64)
    int trow = j >> 3, tcol = j & 7;
    const unsigned short* A; const unsigned short* Bt; const float* bias; unsigned short* C;
    if (op < 3) {
        A = hb;
        Bt   = op == 0 ? Wqt : op == 1 ? Wkt : Wvt;
        bias = op == 0 ? bq  : op == 1 ? bk  : bv;
        C    = op == 0 ? qb  : op == 1 ? kb  : vb;
    } else {
        A = relb;
        Bt   = op == 3 ? Wpkt : Wpqt;
        bias = op == 3 ? bpk  : bpq;
        C    = op == 3 ? pkb  : pqb;
    }
    floatx4 acc[4][2];
    #pragma unroll
    for (int mi = 0; mi < 4; mi++)
        #pragma unroll
        for (int ni = 0; ni < 2; ni++) acc[mi][ni] = (floatx4){0.f, 0.f, 0.f, 0.f};
    gemm_core128(A, Bt, trow * 128, tcol * 64, HID, 0, HID, acc, &As[0][0], &Bs[0][0]);

    int tid = threadIdx.x, lane = tid & 63, wid = tid >> 6;
    int wm = wid >> 1, wn = wid & 1, m16 = lane & 15, quad = lane >> 4;
    #pragma unroll
    for (int ni = 0; ni < 2; ni++) {
        int colg = tcol * 64 + wn * 32 + ni * 16 + m16;
        float bval = bias[colg];
        #pragma unroll
        for (int mi = 0; mi < 4; mi++) {
            #pragma unroll
            for (int r = 0; r < 4; r++) {
                int rowg = trow * 128 + wm * 64 + mi * 16 + quad * 4 + r;
                C[(size_t)rowg * HID + colg] = f2b(acc[mi][ni][r] + bval);
            }
        }
    }
}

// ---------------- fallback MFMA GEMM: B fp32 inline-converted (baseline path) ----------------
template<bool OUT_BF16, bool GELU>
__global__ __launch_bounds__(256) void mfma_gemm(
    const unsigned short* __restrict__ A, const float* __restrict__ B,
    const float* __restrict__ bias, void* __restrict__ Cp, int N, int K) {
    __shared__ unsigned short As[64][72];   // [m][k]
    __shared__ unsigned short Bs[64][72];   // [n][k]
    int tid = threadIdx.x;
    int lane = tid & 63, wid = tid >> 6;
    int wm = wid >> 1, wn = wid & 1;
    int row0 = blockIdx.y * 64, col0 = blockIdx.x * 64;
    int m16 = lane & 15, quad = lane >> 4;

    int ar = tid >> 2, ac = (tid & 3) << 4;
    int bk = (tid >> 3) << 1, bn = (tid & 7) << 3;

    const unsigned short* Ag = A + (size_t)(row0 + ar) * K + ac;
    const float* Bg = B + (size_t)bk * N + col0 + bn;

    floatx4 acc[2][2];
    #pragma unroll
    for (int mi = 0; mi < 2; mi++)
        #pragma unroll
        for (int ni = 0; ni < 2; ni++) acc[mi][ni] = (floatx4){0.f, 0.f, 0.f, 0.f};

    for (int k0 = 0; k0 < K; k0 += 64) {
        uint4 av0 = *(const uint4*)(Ag + k0);
        uint4 av1 = *(const uint4*)(Ag + k0 + 8);
        const float* br0 = Bg + (size_t)k0 * N;
        const float* br1 = br0 + N;
        float4 b00 = *(const float4*)br0, b01 = *(const float4*)(br0 + 4);
        float4 b10 = *(const float4*)br1, b11 = *(const float4*)(br1 + 4);
        *(uint4*)&As[ar][ac] = av0;
        *(uint4*)&As[ar][ac + 8] = av1;
        float lo[8] = {b00.x, b00.y, b00.z, b00.w, b01.x, b01.y, b01.z, b01.w};
        float hi[8] = {b10.x, b10.y, b10.z, b10.w, b11.x, b11.y, b11.z, b11.w};
        #pragma unroll
        for (int i = 0; i < 8; i++) {
            unsigned int p = (unsigned int)f2b(lo[i]) | ((unsigned int)f2b(hi[i]) << 16);
            *(unsigned int*)&Bs[bn + i][bk] = p;
        }
        __syncthreads();
        #pragma unroll
        for (int kk = 0; kk < 2; kk++) {
            bf16x8 a0 = *(const bf16x8*)&As[wm * 32 + m16][kk * 32 + quad * 8];
            bf16x8 a1 = *(const bf16x8*)&As[wm * 32 + 16 + m16][kk * 32 + quad * 8];
            bf16x8 b0 = *(const bf16x8*)&Bs[wn * 32 + m16][kk * 32 + quad * 8];
            bf16x8 b1 = *(const bf16x8*)&Bs[wn * 32 + 16 + m16][kk * 32 + quad * 8];
            acc[0][0] = MFMA16(a0, b0, acc[0][0]);
            acc[0][1] = MFMA16(a0, b1, acc[0][1]);
            acc[1][0] = MFMA16(a1, b0, acc[1][0]);
            acc[1][1] = MFMA16(a1, b1, acc[1][1]);
        }
        __syncthreads();
    }
    #pragma unroll
    for (int ni = 0; ni < 2; ni++) {
        int colg = col0 + wn * 32 + ni * 16 + m16;
        float bv = bias[colg];
        #pragma unroll
        for (int mi = 0; mi < 2; mi++) {
            #pragma unroll
            for (int r = 0; r < 4; r++) {
                int rowg = row0 + wm * 32 + mi * 16 + quad * 4 + r;
                float v = acc[mi][ni][r] + bv;
                if (GELU) v = gelu_tanh(v);
                if (OUT_BF16) ((unsigned short*)Cp)[(size_t)rowg * N + colg] = f2b(v);
                else          ((float*)Cp)[(size_t)rowg * N + colg] = v;
            }
        }
    }
}

// ---------------- MFMA fused flash-style disentangled attention, v3 + PK/PQ prefetch + setprio ----------------
__global__ __launch_bounds__(256, 2) void attn_kernel(
    const unsigned short* __restrict__ Q, const unsigned short* __restrict__ K,
    const unsigned short* __restrict__ V,
    const unsigned short* __restrict__ PK, const unsigned short* __restrict__ PQ,
    const int* __restrict__ am, unsigned short* __restrict__ ctx) {
    __shared__ unsigned short Ks[2][32][72];   // [slot][key][d]
    __shared__ unsigned short Vt[2][64][40];   // [slot][d][key^swz]
    __shared__ float Afs[4][16][49];           // per-wave A band (c2p)
    __shared__ float Bfs[4][32][50];           // per-wave B band (p2c); aliased as mergeO at end
    __shared__ unsigned short Pls[4][16][40];  // per-wave P (bf16)
    __shared__ int mkk[2][32];
    __shared__ float mergeML[2][2][16];        // [strip][m|l][row]

    int bid = blockIdx.x;
    int hh = bid & 7;                  // head -> XCD (round-robin dispatch)
    int b  = (bid >> 3) & 3;
    int q0 = (bid >> 5) * 32;
    int tid = threadIdx.x;
    int lane = tid & 63, wave = tid >> 6;
    int u = wave >> 1;                 // q-strip
    int s = wave & 1;                  // k-parity
    int quad = lane >> 4, m16 = lane & 15;
    const float inv_scale = 0.07216878364870323f; // 1/sqrt(192)

    const unsigned short* qg = Q + (size_t)(b * SEQ + q0 + u * 16 + m16) * HID + hh * HEAD;
    bf16x8 qf0 = *(const bf16x8*)(qg + quad * 8);
    bf16x8 qf1 = *(const bf16x8*)(qg + 32 + quad * 8);

    int sr = tid >> 3;                 // 0..31 key row
    int sc = (tid & 7) * 8;            // d base
    int vkey = ((sc >> 3) & 3) << 3;   // Vt swizzle key (per-thread const)

    floatx4 accO[4];
    #pragma unroll
    for (int nt = 0; nt < 4; nt++) accO[nt] = (floatx4){0.f, 0.f, 0.f, 0.f};
    float mreg[4] = {NEG_BIG, NEG_BIG, NEG_BIG, NEG_BIG};
    float lreg[4] = {0.f, 0.f, 0.f, 0.f};

    auto loadPQ = [&](int t, bf16x8 (&pkf)[3][2], bf16x8 (&pqf)[3][2]) {
        int P0  = q0 - 32 * t + 481;
        int P20 = 32 * t - q0 + 481;
        int Jb  = 16 - 16 * u;
        #pragma unroll
        for (int nt = 0; nt < 3; nt++) {
            int prow = P0 + 16 * u + nt * 16 + m16;
            const unsigned short* pg = PK + (size_t)prow * HID + hh * HEAD + quad * 8;
            pkf[nt][0] = *(const bf16x8*)pg;
            pkf[nt][1] = *(const bf16x8*)(pg + 32);
            int prow2 = P20 + Jb + nt * 16 + m16;
            if (prow2 > 1023) prow2 = 1023;
            const unsigned short* pg2 = PQ + (size_t)prow2 * HID + hh * HEAD + quad * 8;
            pqf[nt][0] = *(const bf16x8*)pg2;
            pqf[nt][1] = *(const bf16x8*)(pg2 + 32);
        }
    };

    auto stageKV = [&](int ph) {
        #pragma unroll
        for (int sl = 0; sl < 2; sl++) {
            int k0 = ph * 64 + sl * 32;
            const unsigned short* kg = K + (size_t)(b * SEQ + k0 + sr) * HID + hh * HEAD + sc;
            *(uint4*)&Ks[sl][sr][sc] = *(const uint4*)kg;
            uint4 vv = *(const uint4*)(V + (size_t)(b * SEQ + k0 + sr) * HID + hh * HEAD + sc);
            unsigned short* vp = (unsigned short*)&vv;
            #pragma unroll
            for (int j = 0; j < 8; j++) Vt[sl][sc + j][sr ^ vkey] = vp[j];
        }
        if (tid < 64) mkk[tid >> 5][tid & 31] = am[b * SEQ + ph * 64 + tid];
    };

    auto computePhase = [&](bf16x8 (&pkf)[3][2], bf16x8 (&pqf)[3][2]) {
        __builtin_amdgcn_s_setprio(1);
        floatx4 accS[2];
        accS[0] = (floatx4){0.f, 0.f, 0.f, 0.f};
        accS[1] = (floatx4){0.f, 0.f, 0.f, 0.f};
        #pragma unroll
        for (int n = 0; n < 2; n++) {
            bf16x8 kfa = *(const bf16x8*)&Ks[s][n * 16 + m16][quad * 8];
            bf16x8 kfb = *(const bf16x8*)&Ks[s][n * 16 + m16][32 + quad * 8];
            accS[n] = MFMA16(qf0, kfa, accS[n]);
            accS[n] = MFMA16(qf1, kfb, accS[n]);
        }
        {
            floatx4 accA[3];
            #pragma unroll
            for (int nt = 0; nt < 3; nt++) {
                accA[nt] = (floatx4){0.f, 0.f, 0.f, 0.f};
                accA[nt] = MFMA16(qf0, pkf[nt][0], accA[nt]);
                accA[nt] = MFMA16(qf1, pkf[nt][1], accA[nt]);
            }
            #pragma unroll
            for (int nt = 0; nt < 3; nt++)
                #pragma unroll
                for (int r = 0; r < 4; r++)
                    Afs[wave][quad * 4 + r][nt * 16 + m16] = accA[nt][r];
        }
        {
            floatx4 accB[2][3];
            #pragma unroll
            for (int mt = 0; mt < 2; mt++) {
                bf16x8 afa = *(const bf16x8*)&Ks[s][mt * 16 + m16][quad * 8];
                bf16x8 afb = *(const bf16x8*)&Ks[s][mt * 16 + m16][32 + quad * 8];
                #pragma unroll
                for (int nt = 0; nt < 3; nt++) {
                    accB[mt][nt] = (floatx4){0.f, 0.f, 0.f, 0.f};
                    accB[mt][nt] = MFMA16(afa, pqf[nt][0], accB[mt][nt]);
                    accB[mt][nt] = MFMA16(afb, pqf[nt][1], accB[mt][nt]);
                }
            }
            #pragma unroll
            for (int mt = 0; mt < 2; mt++)
                #pragma unroll
                for (int nt = 0; nt < 3; nt++)
                    #pragma unroll
                    for (int r = 0; r < 4; r++)
                        Bfs[wave][mt * 16 + quad * 4 + r][nt * 16 + m16] = accB[mt][nt][r];
        }
        __builtin_amdgcn_s_setprio(0);
        float sv[2][4];
        float tmax[4] = {NEG_BIG, NEG_BIG, NEG_BIG, NEG_BIG};
        #pragma unroll
        for (int n = 0; n < 2; n++) {
            #pragma unroll
            for (int r = 0; r < 4; r++) {
                int qq = quad * 4 + r;
                int kc = n * 16 + m16;
                float av = Afs[wave][qq][qq - kc + 31];
                float bv = Bfs[wave][kc][kc - qq + 15];
                float x = (accS[n][r] + av + bv) * inv_scale;
                x = mkk[s][kc] ? x : NEG_BIG;
                sv[n][r] = x;
                tmax[r] = fmaxf(tmax[r], x);
            }
        }
        float alpha[4], psum[4];
        #pragma unroll
        for (int r = 0; r < 4; r++) {
            float tm = tmax[r];
            tm = fmaxf(tm, __shfl_xor(tm, 1));
            tm = fmaxf(tm, __shfl_xor(tm, 2));
            tm = fmaxf(tm, __shfl_xor(tm, 4));
            tm = fmaxf(tm, __shfl_xor(tm, 8));
            float mo = mreg[r];
            float mn = fmaxf(mo, tm);
            alpha[r] = __expf(mo - mn);
            mreg[r] = mn;
        }
        #pragma unroll
        for (int r = 0; r < 4; r++) psum[r] = 0.f;
        #pragma unroll
        for (int n = 0; n < 2; n++) {
            #pragma unroll
            for (int r = 0; r < 4; r++) {
                float p = (sv[n][r] > -1.5e38f) ? __expf(sv[n][r] - mreg[r]) : 0.0f;
                unsigned short pb = f2b(p);
                Pls[wave][quad * 4 + r][n * 16 + m16] = pb;
                psum[r] += b2f(pb);
            }
        }
        #pragma unroll
        for (int r = 0; r < 4; r++) {
            float ps = psum[r];
            ps += __shfl_xor(ps, 1);
            ps += __shfl_xor(ps, 2);
            ps += __shfl_xor(ps, 4);
            ps += __shfl_xor(ps, 8);
            lreg[r] = lreg[r] * alpha[r] + ps;
        }
        #pragma unroll
        for (int nt = 0; nt < 4; nt++)
            #pragma unroll
            for (int r = 0; r < 4; r++) accO[nt][r] *= alpha[r];
        {
            __builtin_amdgcn_s_setprio(1);
            bf16x8 pf = *(const bf16x8*)&Pls[wave][m16][quad * 8];
            #pragma unroll
            for (int nt = 0; nt < 4; nt++) {
                int d = nt * 16 + m16;
                int kq = (quad ^ ((d >> 3) & 3)) * 8;
                bf16x8 vf = *(const bf16x8*)&Vt[s][d][kq];
                accO[nt] = MFMA16(pf, vf, accO[nt]);
            }
            __builtin_amdgcn_s_setprio(0);
        }
    };

    bf16x8 pkfA[3][2], pqfA[3][2], pkfB[3][2], pqfB[3][2];
    loadPQ(s, pkfA, pqfA);                        // ph=0 window
    #pragma unroll
    for (int pp = 0; pp < 4; pp++) {
        {   // even phase: uses A set, prefetches B set
            int ph = 2 * pp;
            __syncthreads();
            stageKV(ph);
            __syncthreads();
            if (ph < 7) loadPQ(2 * (ph + 1) + s, pkfB, pqfB);
            computePhase(pkfA, pqfA);
        }
        {   // odd phase: uses B set, prefetches A set
            int ph = 2 * pp + 1;
            __syncthreads();
            stageKV(ph);
            __syncthreads();
            if (ph < 7) loadPQ(2 * (ph + 1) + s, pkfA, pqfA);
            computePhase(pkfB, pqfB);
        }
    }

    __syncthreads();
    float* mo = &Bfs[0][0][0];
    if (s == 1) {
        #pragma unroll
        for (int nt = 0; nt < 4; nt++)
            #pragma unroll
            for (int r = 0; r < 4; r++)
                mo[u * 1056 + (quad * 4 + r) * 66 + nt * 16 + m16] = accO[nt][r];
        if (m16 == 0) {
            #pragma unroll
            for (int r = 0; r < 4; r++) {
                mergeML[u][0][quad * 4 + r] = mreg[r];
                mergeML[u][1][quad * 4 + r] = lreg[r];
            }
        }
    }
    __syncthreads();
    if (s == 0) {
        #pragma unroll
        for (int r = 0; r < 4; r++) {
            int row = quad * 4 + r;
            float m1 = mergeML[u][0][row], l1 = mergeML[u][1][row];
            float m0 = mreg[r], l0 = lreg[r];
            float mt = fmaxf(m0, m1);
            float a0 = __expf(m0 - mt), a1 = __expf(m1 - mt);
            float lt = l0 * a0 + l1 * a1;
            float inv = lt > 0.0f ? 1.0f / lt : 0.0f;
            inv *= (float)am[b * SEQ + q0 + u * 16 + row];
            #pragma unroll
            for (int nt = 0; nt < 4; nt++) {
                float o1 = mo[u * 1056 + row * 66 + nt * 16 + m16];
                float val = (accO[nt][r] * a0 + o1 * a1) * inv;
                ctx[(size_t)(b * SEQ + q0 + u * 16 + row) * HID + hh * HEAD + nt * 16 + m16] = f2b(val);
            }
        }
    }
}

// ---------------- output copy / classifier (fp32 out) ----------------
__global__ void copy_f_kernel(const float* __restrict__ in, float* __restrict__ out, int n) {
    int i = blockIdx.x * 256 + threadIdx.x;
    if (i < n) out[i] = in[i];
}
__global__ void cls_kernel(const float* __restrict__ h, const float* __restrict__ cls_w,
                           const float* __restrict__ cls_b, float* __restrict__ out) {
    int t = blockIdx.x, v = threadIdx.x;
    if (v < VOCAB) {
        const float* hr = h + (size_t)t * HID;
        const float* wr = cls_w + (size_t)v * HID;
        float acc = cls_b[v];
        for (int d = 0; d < HID; d += 4) {
            float4 hv = *(const float4*)(hr + d);
            float4 wv = *(const float4*)(wr + d);
            acc += hv.x * wv.x + hv.y * wv.y + hv.z * wv.z + hv.w * wv.w;
        }
        out[t * VOCAB + v] = acc;
    }
}

extern "C" void kernel_launch(void* const* d_in, const int* in_sizes, int n_in,
                              void* d_out, int out_size, void* d_ws, size_t ws_size,
                              hipStream_t stream) {
    const int* x     = (const int*)d_in[0];
    const int* am    = (const int*)d_in[1];
    const float* word_emb = (const float*)d_in[2];
    const float* emb_g    = (const float*)d_in[3];
    const float* emb_b    = (const float*)d_in[4];
    const float* rel_emb  = (const float*)d_in[5];
    const float* Wq  = (const float*)d_in[6];  const float* bq  = (const float*)d_in[7];
    const float* Wk  = (const float*)d_in[8];  const float* bk  = (const float*)d_in[9];
    const float* Wv  = (const float*)d_in[10]; const float* bv  = (const float*)d_in[11];
    const float* Wpk = (const float*)d_in[12]; const float* bpk = (const float*)d_in[13];
    const float* Wpq = (const float*)d_in[14]; const float* bpq = (const float*)d_in[15];
    const float* Wo  = (const float*)d_in[16]; const float* bo  = (const float*)d_in[17];
    const float* ln1g = (const float*)d_in[18]; const float* ln1b = (const float*)d_in[19];
    const float* W1  = (const float*)d_in[20]; const float* b1  = (const float*)d_in[21];
    const float* W2  = (const float*)d_in[22]; const float* b2  = (const float*)d_in[23];
    const float* ln2g = (const float*)d_in[24]; const float* ln2b = (const float*)d_in[25];
    const float* cls_w = (const float*)d_in[26]; const float* cls_b = (const float*)d_in[27];

    char* wsb = (char*)d_ws;
    const size_t NEED_BIG = 107u << 20;   // 23 MB activations + 84 MB bf16 weights

    if (ws_size >= NEED_BIG) {
        // ---- big-workspace path: preconverted transposed bf16 weights ----
        float* h  = (float*)wsb;                                      // 4 MB
        float* t1 = (float*)(wsb + (4u << 20));                       // 4 MB (split-K part 0)
        float* t2 = (float*)(wsb + (8u << 20));                       // 4 MB (split-K part 1)
        unsigned short* qb   = (unsigned short*)(wsb + (12u << 20));  // 2 MB
        unsigned short* kb   = (unsigned short*)(wsb + (14u << 20));  // 2 MB
        unsigned short* vb   = (unsigned short*)(wsb + (16u << 20));  // 2 MB
        unsigned short* pkb  = (unsigned short*)(wsb + (18u << 20));  // 1 MB
        unsigned short* pqb  = (unsigned short*)(wsb + (19u << 20));  // 1 MB
        unsigned short* relb = (unsigned short*)(wsb + (20u << 20));  // 1 MB
        unsigned short* hb   = (unsigned short*)(wsb + (21u << 20));  // 2 MB
        unsigned short* ctx  = hb;   // alias: hb dead between attn and add_ln1
        unsigned short* ffb  = qb;   // alias: qb..pqb (8 MB) dead by FF1
        unsigned short* Wqt  = (unsigned short*)(wsb + (23u << 20));  // 6x6 MB: q,k,v,pk,pq,o
        unsigned short* W1t  = (unsigned short*)(wsb + (59u << 20));  // 24 MB
        unsigned short* W2t  = (unsigned short*)(wsb + (83u << 20));  // 24 MB

        const size_t M512 = (size_t)HID * HID;   // elements per 512x512 matrix
        float* out_f = (float*)d_out;

        tcvt6_kernel<<<dim3(16, 16, 72), dim3(32, 8), 0, stream>>>(Wq, Wk, Wv, Wpk, Wpq, Wo, Wqt);
        tcvt_kernel<<<dim3(64, 16, 12), dim3(32, 8), 0, stream>>>(W1, W1t, HID, FFDIM);
        tcvt_kernel<<<dim3(16, 64, 12), dim3(32, 8), 0, stream>>>(W2, W2t, FFDIM, HID);
        cvt_rel_kernel<<<dim3(SPAN2 * HID / 1024), dim3(256), 0, stream>>>(rel_emb, relb);
        embed_ln_kernel<<<dim3(TOK / 4), dim3(256), 0, stream>>>(x, am, word_emb, emb_g, emb_b, h, hb);

        for (int l = 0; l < NLAYER; l++) {
            qkvp_gemm<<<dim3(512), dim3(256), 0, stream>>>(
                hb, relb,
                Wqt + (size_t)(0 * NLAYER + l) * M512, Wqt + (size_t)(1 * NLAYER + l) * M512,
                Wqt + (size_t)(2 * NLAYER + l) * M512, Wqt + (size_t)(3 * NLAYER + l) * M512,
                Wqt + (size_t)(4 * NLAYER + l) * M512,
                bq + l * HID, bk + l * HID, bv + l * HID, bpk + l * HID, bpq + l * HID,
                qb, kb, vb, pkb, pqb);

            attn_kernel<<<dim3(512), dim3(256), 0, stream>>>(
                qb, kb, vb, pkb, pqb, am, ctx);

            // Wo: 64x64 tiles, split-K2 -> 512 WGs (2 blocks/CU)
            gemm_bt<false, false, 2><<<dim3(HID / 64, TOK / 64, 2), dim3(256), 0, stream>>>(
                ctx, Wqt + (size_t)(5 * NLAYER + l) * M512, bo + l * HID, t1, HID, HID);
            add_ln2_kernel<<<dim3(TOK / 4), dim3(256), 0, stream>>>(
                t1, t2, ln1g + l * HID, ln1b + l * HID, h, h, hb);

            gemm_bt2<true, true, 1><<<dim3(FFDIM / 64, TOK / 128, 1), dim3(256), 0, stream>>>(
                hb, W1t + (size_t)l * HID * FFDIM, b1 + l * FFDIM, ffb, FFDIM, HID);
            // FF2: 64x64 tiles, split-K2 -> 512 WGs (2 blocks/CU)
            gemm_bt<false, false, 2><<<dim3(HID / 64, TOK / 64, 2), dim3(256), 0, stream>>>(
                ffb, W2t + (size_t)l * HID * FFDIM, b2 + l * HID, t1, HID, FFDIM);
            // last layer writes LN output directly into d_out (drops copy_f)
            add_ln2_kernel<<<dim3(TOK / 4), dim3(256), 0, stream>>>(
                t1, t2, ln2g + l * HID, ln2b + l * HID, h, (l == NLAYER - 1) ? out_f : h, hb);
        }

        cls_kernel<<<dim3(TOK), dim3(32), 0, stream>>>(out_f, cls_w, cls_b, out_f + TOK * HID);
        return;
    }

    // ---- fallback path: baseline 19 MB layout, inline fp32->bf16 weight conversion ----
    const size_t NEEDED = 19u << 20;
    if (ws_size < NEEDED) return;
    float* h  = (float*)wsb;                                     // 4 MB
    float* t1 = (float*)(wsb + (4u << 20));                      // 4 MB
    unsigned short* qb   = (unsigned short*)(wsb + (8u << 20));  // 2 MB
    unsigned short* kb   = qb  + (1u << 20);                     // 2 MB
    unsigned short* vb   = kb  + (1u << 20);                     // 2 MB
    unsigned short* pkb  = vb  + (1u << 20);                     // 1 MB
    unsigned short* pqb  = pkb + (1u << 19);                     // 1 MB
    unsigned short* relb = (unsigned short*)(wsb + (16u << 20)); // 1 MB
    unsigned short* hb   = (unsigned short*)(wsb + (17u << 20)); // 2 MB
    unsigned short* ctx  = hb;   // alias: hb dead between V-GEMM and add_ln1
    unsigned short* ffb  = qb;   // alias: q..pq dead by FF1

    cvt_rel_kernel<<<dim3(SPAN2 * HID / 1024), dim3(256), 0, stream>>>(rel_emb, relb);
    embed_ln_kernel<<<dim3(TOK / 4), dim3(256), 0, stream>>>(x, am, word_emb, emb_g, emb_b, h, hb);

    for (int l = 0; l < NLAYER; l++) {
        const float* Wq_l = Wq + (size_t)l * HID * HID;
        const float* Wk_l = Wk + (size_t)l * HID * HID;
        const float* Wv_l = Wv + (size_t)l * HID * HID;
        const float* Wo_l = Wo + (size_t)l * HID * HID;
        const float* Wpk_l = Wpk + (size_t)l * HID * HID;
        const float* Wpq_l = Wpq + (size_t)l * HID * HID;
        const float* W1_l = W1 + (size_t)l * HID * FFDIM;
        const float* W2_l = W2 + (size_t)l * FFDIM * HID;

        mfma_gemm<true,  false><<<dim3(HID/64, TOK/64),   dim3(256), 0, stream>>>(hb,   Wq_l,  bq + l*HID,  qb,  HID, HID);
        mfma_gemm<true,  false><<<dim3(HID/64, TOK/64),   dim3(256), 0, stream>>>(hb,   Wk_l,  bk + l*HID,  kb,  HID, HID);
        mfma_gemm<true,  false><<<dim3(HID/64, TOK/64),   dim3(256), 0, stream>>>(hb,   Wv_l,  bv + l*HID,  vb,  HID, HID);
        mfma_gemm<true,  false><<<dim3(HID/64, SPAN2/64), dim3(256), 0, stream>>>(relb, Wpk_l, bpk + l*HID, pkb, HID, HID);
        mfma_gemm<true,  false><<<dim3(HID/64, SPAN2/64), dim3(256), 0, stream>>>(relb, Wpq_l, bpq + l*HID, pqb, HID, HID);

        attn_kernel<<<dim3(512), dim3(256), 0, stream>>>(qb, kb, vb, pkb, pqb, am, ctx);

        mfma_gemm<false, false><<<dim3(HID/64, TOK/64),   dim3(256), 0, stream>>>(ctx,  Wo_l,  bo + l*HID,  t1,  HID, HID);
        add_ln_kernel<<<dim3(TOK / 4), dim3(256), 0, stream>>>(t1, ln1g + l*HID, ln1b + l*HID, h, hb);

        mfma_gemm<true,  true ><<<dim3(FFDIM/64, TOK/64), dim3(256), 0, stream>>>(hb,   W1_l,  b1 + l*FFDIM, ffb, FFDIM, HID);
        mfma_gemm<false, false><<<dim3(HID/64, TOK/64),   dim3(256), 0, stream>>>(ffb,  W2_l,  b2 + l*HID,  t1,  HID, FFDIM);
        add_ln_kernel<<<dim3(TOK / 4), dim3(256), 0, stream>>>(t1, ln2g + l*HID, ln2b + l*HID, h, hb);
    }

    float* out_f = (float*)d_out;
    copy_f_kernel<<<dim3(TOK*HID/256), dim3(256), 0, stream>>>(h, out_f, TOK*HID);
    cls_kernel<<<dim3(TOK), dim3(32), 0, stream>>>(h, cls_w, cls_b, out_f + TOK*HID);
}